// Round 2
// baseline (991.664 us; speedup 1.0000x reference)
//
#include <hip/hip_runtime.h>

typedef unsigned short u16;
typedef __attribute__((ext_vector_type(8))) short bf16x8s;
typedef __attribute__((ext_vector_type(4))) float f32x4;

#define DEV static __device__ __forceinline__

DEV float b2f(u16 v) { return __uint_as_float(((unsigned)v) << 16); }
DEV u16 f2b(float f) {
  unsigned u = __float_as_uint(f);
  unsigned r = (u + 0x7fffu + ((u >> 16) & 1u)) >> 16;
  return (u16)r;
}

// ---------------- elementwise converts ----------------
__global__ __launch_bounds__(256) void k_f2b(const float* __restrict__ in,
                                             u16* __restrict__ o, long n4) {
  long i = (long)blockIdx.x * 256 + threadIdx.x;
  if (i >= n4) return;
  float4 v = *(const float4*)(in + i * 4);
  u16* d = o + i * 4;
  d[0] = f2b(v.x); d[1] = f2b(v.y); d[2] = f2b(v.z); d[3] = f2b(v.w);
}

// W[k][N] (fp32) -> Wt[n][512] bf16  (K fixed = 512)
__global__ __launch_bounds__(256) void k_wt(const float* __restrict__ W,
                                            u16* __restrict__ Wt, int N) {
  int e = blockIdx.x * 256 + threadIdx.x;  // e < N*512
  int nn = e >> 9, kk = e & 511;
  Wt[e] = f2b(W[(long)kk * N + nn]);
}

// ---------------- bf16 NT GEMM: C = A[M,K] @ B[N,K]^T ----------------
// MODE 0: q-proj (scale 0.125, write q[b,h,n,dh])
// MODE 1: kv-proj (write k[b,h,nz,dh] and vt[b,h,dh,nz])
// MODE 2: out-proj (+x + bias, fp32 out)
// MODE 3: batched bf16 store (ldc)
// MODE 4: batched fp32 store (ldc)
template <int MODE>
__global__ __launch_bounds__(256) void k_gemm_nt(
    const u16* __restrict__ A, const u16* __restrict__ Bm, void* __restrict__ C0,
    void* __restrict__ C1, const float* __restrict__ xres,
    const float* __restrict__ bias, int K, long sA, long sB, long sC, int ldc) {
  const int bz = blockIdx.z;
  A += (long)bz * sA;
  Bm += (long)bz * sB;
  const int m0 = blockIdx.y << 6, n0 = blockIdx.x << 6;
  const int t = threadIdx.x, lane = t & 63, w = t >> 6;
  const int wm = (w >> 1) << 5, wn = (w & 1) << 5;
  const int fr = lane & 15, fk = (lane >> 4) << 3;
  __shared__ u16 As[64][40];
  __shared__ u16 Bs[64][40];
  f32x4 acc[2][2] = {};
  const int sr = t >> 2, sc = (t & 3) << 3;
  for (int k0 = 0; k0 < K; k0 += 32) {
    *(bf16x8s*)&As[sr][sc] = *(const bf16x8s*)&A[(long)(m0 + sr) * K + k0 + sc];
    *(bf16x8s*)&Bs[sr][sc] = *(const bf16x8s*)&Bm[(long)(n0 + sr) * K + k0 + sc];
    __syncthreads();
    bf16x8s a0 = *(const bf16x8s*)&As[wm + fr][fk];
    bf16x8s a1 = *(const bf16x8s*)&As[wm + 16 + fr][fk];
    bf16x8s b0 = *(const bf16x8s*)&Bs[wn + fr][fk];
    bf16x8s b1 = *(const bf16x8s*)&Bs[wn + 16 + fr][fk];
    acc[0][0] = __builtin_amdgcn_mfma_f32_16x16x32_bf16(a0, b0, acc[0][0], 0, 0, 0);
    acc[0][1] = __builtin_amdgcn_mfma_f32_16x16x32_bf16(a0, b1, acc[0][1], 0, 0, 0);
    acc[1][0] = __builtin_amdgcn_mfma_f32_16x16x32_bf16(a1, b0, acc[1][0], 0, 0, 0);
    acc[1][1] = __builtin_amdgcn_mfma_f32_16x16x32_bf16(a1, b1, acc[1][1], 0, 0, 0);
    __syncthreads();
  }
  const int crow = (lane >> 4) << 2;
#pragma unroll
  for (int fi = 0; fi < 2; ++fi)
#pragma unroll
    for (int fj = 0; fj < 2; ++fj)
#pragma unroll
      for (int r = 0; r < 4; ++r) {
        int row = m0 + wm + fi * 16 + crow + r;
        int col = n0 + wn + fj * 16 + fr;
        float v = acc[fi][fj][r];
        if (MODE == 0) {
          int b = row >> 13, n = row & 8191, h = col >> 6, dh = col & 63;
          ((u16*)C0)[((((long)(b * 8 + h)) << 13) + n) * 64 + dh] = f2b(v * 0.125f);
        } else if (MODE == 1) {
          int b = row >> 12, nz = row & 4095;
          if (col < 512) {
            int h = col >> 6, dh = col & 63;
            ((u16*)C0)[((((long)(b * 8 + h)) << 12) + nz) * 64 + dh] = f2b(v);
          } else {
            int c2 = col - 512, h = c2 >> 6, dh = c2 & 63;
            ((u16*)C1)[((((long)(b * 8 + h) * 64 + dh)) << 12) + nz] = f2b(v);
          }
        } else if (MODE == 2) {
          long idx = ((long)row << 9) + col;
          ((float*)C0)[idx] = v + xres[idx] + bias[col];
        } else if (MODE == 3) {
          ((u16*)C0)[(long)bz * sC + (long)row * ldc + col] = f2b(v);
        } else {
          ((float*)C0)[(long)bz * sC + (long)row * ldc + col] = v;
        }
      }
}

// ---------------- fp32 NN GEMM (pinv): C = cdiag*I + csc * A @ (bdiag*I + bsc*B)
__global__ __launch_bounds__(256) void k_gemm_nn_f32(
    const float* __restrict__ A, const float* __restrict__ B, void* __restrict__ C,
    int Nc, int K, long sA, long sB, long sC, float bdiag, float bsc, float cdiag,
    float csc, int outbf) {
  const int bz = blockIdx.z;
  A += (long)bz * sA;
  B += (long)bz * sB;
  const int m0 = blockIdx.y << 6, n0 = blockIdx.x << 6;
  const int t = threadIdx.x;
  const int ty = t >> 4, tx = t & 15;
  __shared__ float Atr[32][68];
  __shared__ float Bsh[32][68];
  float acc[4][4] = {};
  const int ar = t >> 2, ac = (t & 3) << 3;
  const int br = t >> 3, bc = (t & 7) << 3;
  for (int k0 = 0; k0 < K; k0 += 32) {
    float4 a0 = *(const float4*)&A[(long)(m0 + ar) * K + k0 + ac];
    float4 a1 = *(const float4*)&A[(long)(m0 + ar) * K + k0 + ac + 4];
    Atr[ac + 0][ar] = a0.x; Atr[ac + 1][ar] = a0.y;
    Atr[ac + 2][ar] = a0.z; Atr[ac + 3][ar] = a0.w;
    Atr[ac + 4][ar] = a1.x; Atr[ac + 5][ar] = a1.y;
    Atr[ac + 6][ar] = a1.z; Atr[ac + 7][ar] = a1.w;
    float4 b0 = *(const float4*)&B[(long)(k0 + br) * Nc + n0 + bc];
    float4 b1 = *(const float4*)&B[(long)(k0 + br) * Nc + n0 + bc + 4];
    float tv[8] = {b0.x, b0.y, b0.z, b0.w, b1.x, b1.y, b1.z, b1.w};
    int kg = k0 + br;
#pragma unroll
    for (int j = 0; j < 8; ++j) {
      int cg = n0 + bc + j;
      Bsh[br][bc + j] = bsc * tv[j] + (kg == cg ? bdiag : 0.f);
    }
    __syncthreads();
#pragma unroll
    for (int kk = 0; kk < 32; ++kk) {
      float4 a4 = *(const float4*)&Atr[kk][ty << 2];
      float4 b4 = *(const float4*)&Bsh[kk][tx << 2];
      float av[4] = {a4.x, a4.y, a4.z, a4.w};
      float bv[4] = {b4.x, b4.y, b4.z, b4.w};
#pragma unroll
      for (int i = 0; i < 4; ++i)
#pragma unroll
        for (int j = 0; j < 4; ++j) acc[i][j] += av[i] * bv[j];
    }
    __syncthreads();
  }
#pragma unroll
  for (int i = 0; i < 4; ++i)
#pragma unroll
    for (int j = 0; j < 4; ++j) {
      int row = m0 + (ty << 2) + i;
      int col = n0 + (tx << 2) + j;
      float v = csc * acc[i][j] + ((row == col) ? cdiag : 0.f);
      if (outbf)
        ((u16*)C)[(long)bz * sC + (long)row * Nc + col] = f2b(v);
      else
        ((float*)C)[(long)bz * sC + (long)row * Nc + col] = v;
    }
}

// ---------------- landmarks ----------------
__global__ __launch_bounds__(256) void k_landmark(const u16* __restrict__ src,
                                                  float* __restrict__ df,
                                                  u16* __restrict__ db, int ntok,
                                                  int l, float inv) {
  int pidx = blockIdx.x * 4 + (threadIdx.x >> 6);
  int d = threadIdx.x & 63;
  int bh = pidx >> 8, m = pidx & 255;
  const u16* s = src + ((long)bh * ntok + (long)m * l) * 64 + d;
  float sum = 0.f;
  for (int j = 0; j < l; ++j) sum += b2f(s[j * 64]);
  sum *= inv;
  long o = ((long)bh * 256 + m) * 64 + d;
  df[o] = sum;
  db[o] = f2b(sum);
}

// ---------------- sim2 + softmax (fp32) ----------------
__global__ __launch_bounds__(256) void k_sim2_softmax(const float* __restrict__ qlf,
                                                      const float* __restrict__ klf,
                                                      float* __restrict__ attn2) {
  int m = blockIdx.x, bh = blockIdx.y;
  int j = threadIdx.x, lane = j & 63, w = j >> 6;
  const float* qr = qlf + ((long)bh * 256 + m) * 64;
  const float* kr = klf + ((long)bh * 256 + j) * 64;
  float s = 0.f;
#pragma unroll
  for (int d = 0; d < 64; ++d) s += qr[d] * kr[d];
  float mx = s;
  for (int o = 1; o < 64; o <<= 1) mx = fmaxf(mx, __shfl_xor(mx, o, 64));
  __shared__ float r1[4], r2[4];
  if (lane == 0) r1[w] = mx;
  __syncthreads();
  mx = fmaxf(fmaxf(r1[0], r1[1]), fmaxf(r1[2], r1[3]));
  float e = __expf(s - mx);
  float su = e;
  for (int o = 1; o < 64; o <<= 1) su += __shfl_xor(su, o, 64);
  if (lane == 0) r2[w] = su;
  __syncthreads();
  su = r2[0] + r2[1] + r2[2] + r2[3];
  attn2[(((long)bh * 256 + m) << 8) + j] = e / su;
}

__global__ __launch_bounds__(256) void k_colmax(const float* __restrict__ attn2,
                                                unsigned* __restrict__ cmax) {
  int bh = blockIdx.x, j = threadIdx.x, lane = j & 63, w = j >> 6;
  const float* p = attn2 + ((long)bh << 16) + j;
  float s = 0.f;
  for (int m = 0; m < 256; ++m) s += p[m * 256];
  float mx = s;
  for (int o = 1; o < 64; o <<= 1) mx = fmaxf(mx, __shfl_xor(mx, o, 64));
  __shared__ float r1[4];
  if (lane == 0) r1[w] = mx;
  __syncthreads();
  if (j == 0) {
    mx = fmaxf(fmaxf(r1[0], r1[1]), fmaxf(r1[2], r1[3]));
    atomicMax(cmax, __float_as_uint(mx));
  }
}

__global__ __launch_bounds__(256) void k_init_zt(const float* __restrict__ attn2,
                                                 float* __restrict__ zt,
                                                 const unsigned* __restrict__ cmax) {
  long e = (long)blockIdx.x * 256 + threadIdx.x;  // 2M total
  float inv = 1.f / __uint_as_float(*cmax);
  int bh = (int)(e >> 16), rem = (int)(e & 65535), i = rem >> 8, jj = rem & 255;
  zt[e] = attn2[((long)bh << 16) + jj * 256 + i] * inv;
}

// ---------------- softmax over 4096-long rows (bf16 in place) ----------------
__global__ __launch_bounds__(256) void k_softmax_row4096(u16* __restrict__ S) {
  long row = blockIdx.x;
  u16* p = S + row * 4096 + threadIdx.x;
  int lane = threadIdx.x & 63, w = threadIdx.x >> 6;
  float v[16];
  float mx = -3.4e38f;
#pragma unroll
  for (int i = 0; i < 16; ++i) { v[i] = b2f(p[i * 256]); mx = fmaxf(mx, v[i]); }
  for (int o = 1; o < 64; o <<= 1) mx = fmaxf(mx, __shfl_xor(mx, o, 64));
  __shared__ float r1[4], r2[4];
  if (lane == 0) r1[w] = mx;
  __syncthreads();
  mx = fmaxf(fmaxf(r1[0], r1[1]), fmaxf(r1[2], r1[3]));
  float su = 0.f;
#pragma unroll
  for (int i = 0; i < 16; ++i) { v[i] = __expf(v[i] - mx); su += v[i]; }
  for (int o = 1; o < 64; o <<= 1) su += __shfl_xor(su, o, 64);
  if (lane == 0) r2[w] = su;
  __syncthreads();
  su = r2[0] + r2[1] + r2[2] + r2[3];
  float inv = 1.f / su;
#pragma unroll
  for (int i = 0; i < 16; ++i) p[i * 256] = f2b(v[i] * inv);
}

// ---------------- fused sim1: O = softmax(q @ k_land^T) @ T2 ----------------
__global__ __launch_bounds__(256) void k_fused_attn1(const u16* __restrict__ q,
                                                     const u16* __restrict__ klb,
                                                     const u16* __restrict__ t2b,
                                                     u16* __restrict__ O) {
  const int bh = blockIdx.y, n0 = blockIdx.x << 6;
  const int bb = bh >> 3, hh = bh & 7;
  const int t = threadIdx.x, lane = t & 63, w = t >> 6;
  const int fr = lane & 15, g = lane >> 4, fk = g << 3;
  __shared__ char lds[65536];  // [0,32K)=k_land swz (later aliased by P), [32K,64K)=T2^T swz
  {
    const u16* src = klb + (long)bh * 16384;
#pragma unroll
    for (int i = 0; i < 8; ++i) {
      int c = t + (i << 8);
      int byte = c << 4;
      int sw = byte ^ (((byte >> 7) & 7) << 4);
      *(bf16x8s*)(lds + sw) = *(const bf16x8s*)(src + (c << 3));
    }
    const u16* src2 = t2b + (long)bh * 16384;
#pragma unroll
    for (int i = 0; i < 64; ++i) {
      int e = t + (i << 8);
      int k = e >> 6, dh = e & 63;
      int byte = (dh << 9) + (k << 1);
      int sw = byte ^ ((dh & 7) << 4);
      *(u16*)(lds + 32768 + sw) = src2[e];
    }
  }
  __syncthreads();

  const u16* qrow = q + ((long)bh * 8192 + n0 + (w << 4) + fr) * 64;
  bf16x8s a0 = *(const bf16x8s*)(qrow + fk);
  bf16x8s a1 = *(const bf16x8s*)(qrow + 32 + fk);

  f32x4 s[16];
#pragma unroll
  for (int c = 0; c < 16; ++c) {
    int j = (c << 4) + fr;
    int base = (j << 7) + (fk << 1);
    int swm = (j & 7) << 4;
    bf16x8s b0 = *(const bf16x8s*)(lds + (base ^ swm));
    bf16x8s b1 = *(const bf16x8s*)(lds + ((base + 64) ^ swm));
    f32x4 zz = {};
    zz = __builtin_amdgcn_mfma_f32_16x16x32_bf16(a0, b0, zz, 0, 0, 0);
    zz = __builtin_amdgcn_mfma_f32_16x16x32_bf16(a1, b1, zz, 0, 0, 0);
    s[c] = zz;
  }
  float mr[4], li[4];
#pragma unroll
  for (int r = 0; r < 4; ++r) {
    float m = s[0][r];
#pragma unroll
    for (int c = 1; c < 16; ++c) m = fmaxf(m, s[c][r]);
    m = fmaxf(m, __shfl_xor(m, 1, 64));
    m = fmaxf(m, __shfl_xor(m, 2, 64));
    m = fmaxf(m, __shfl_xor(m, 4, 64));
    m = fmaxf(m, __shfl_xor(m, 8, 64));
    mr[r] = m;
  }
#pragma unroll
  for (int r = 0; r < 4; ++r) {
    float l = 0.f;
#pragma unroll
    for (int c = 0; c < 16; ++c) {
      float e = __expf(s[c][r] - mr[r]);
      s[c][r] = e;
      l += e;
    }
    l += __shfl_xor(l, 1, 64);
    l += __shfl_xor(l, 2, 64);
    l += __shfl_xor(l, 4, 64);
    l += __shfl_xor(l, 8, 64);
    li[r] = 1.f / l;
  }
  __syncthreads();  // everyone done reading k_land; its LDS now reused as P staging

  char* plw = lds + (w << 10);  // 1KB per wave: P[16][32] bf16, swizzled
  f32x4 o4[4] = {};
#pragma unroll
  for (int pair = 0; pair < 8; ++pair) {
#pragma unroll
    for (int cc = 0; cc < 2; ++cc) {
      int c = (pair << 1) + cc;
#pragma unroll
      for (int r = 0; r < 4; ++r) {
        int row = (g << 2) + r;
        int byte = (row << 6) + (((cc << 4) + fr) << 1);
        int sw = byte ^ ((row & 7) << 4);
        *(u16*)(plw + sw) = f2b(s[c][r] * li[r]);
      }
    }
    asm volatile("s_waitcnt lgkmcnt(0)" ::: "memory");
    __builtin_amdgcn_sched_barrier(0);
    int abyte = (fr << 6) + (fk << 1);
    bf16x8s ap = *(const bf16x8s*)(plw + (abyte ^ ((fr & 7) << 4)));
#pragma unroll
    for (int d = 0; d < 4; ++d) {
      int dh = (d << 4) + fr;
      int tb = (dh << 9) + (((pair << 5) + fk) << 1);
      bf16x8s bv = *(const bf16x8s*)(lds + 32768 + (tb ^ ((dh & 7) << 4)));
      o4[d] = __builtin_amdgcn_mfma_f32_16x16x32_bf16(ap, bv, o4[d], 0, 0, 0);
    }
    asm volatile("s_waitcnt lgkmcnt(0)" ::: "memory");
    __builtin_amdgcn_sched_barrier(0);
  }
  u16* ob = O + (((long)bb * 8192 + n0 + (w << 4)) << 9) + (hh << 6);
#pragma unroll
  for (int d = 0; d < 4; ++d)
#pragma unroll
    for (int r = 0; r < 4; ++r) {
      int row = (g << 2) + r;
      int col = (d << 4) + fr;
      ob[((long)row << 9) + col] = f2b(o4[d][r]);
    }
}

// ---------------- host ----------------
extern "C" void kernel_launch(void* const* d_in, const int* in_sizes, int n_in,
                              void* d_out, int out_size, void* d_ws, size_t ws_size,
                              hipStream_t stream) {
  const float* x = (const float*)d_in[0];
  const float* z = (const float*)d_in[1];
  const float* Wq = (const float*)d_in[2];
  const float* Wkv = (const float*)d_in[3];
  const float* Wo = (const float*)d_in[4];
  const float* bo = (const float*)d_in[5];
  float* out = (float*)d_out;

  char* base = (char*)d_ws;
  size_t off = 0;
  auto alloc = [&](size_t bytes) -> void* {
    void* r = base + off;
    off = (off + bytes + 255) & ~(size_t)255;
    return r;
  };
  // ---- live-range-aware layout (total ~195 MB; previous 280 MB overflowed ws) ----
  u16* qb = (u16*)alloc(33554432);    // q bf16 [b,h,n,dh]           live: qproj -> attn1
  u16* kb = (u16*)alloc(16777216);    // k bf16 [b,h,nz,dh]          live: kvproj -> sim3
  u16* vtb = (u16*)alloc(16777216);   // v^T bf16 [b,h,dh,nz]        live: kvproj -> T1
  u16* S3 = (u16*)alloc(67108864);    // sim3 logits/probs (64MB)    live: sim3 -> T1
  float* attn2 = (float*)alloc(8388608);
  u16* xb = (u16*)alloc(33554432);    // x bf16; DEAD after qproj -> reused as Ob
  u16* zb = (u16*)alloc(16777216);    // z bf16; dead after kvproj
  u16* wqt = (u16*)alloc(524288);
  u16* wkvt = (u16*)alloc(1048576);
  u16* wot = (u16*)alloc(524288);
  float* qlf = (float*)alloc(2097152);
  u16* qlb = (u16*)alloc(1048576);
  float* klf = (float*)alloc(2097152);
  u16* klb = (u16*)alloc(1048576);
  float* T1 = (float*)alloc(2097152);
  u16* T2b = (u16*)alloc(1048576);
  unsigned* cmax = (unsigned*)alloc(256);
  // aliases over dead regions:
  float* zta = (float*)S3;            // pinv temps alias S3 (S3 dead after T1 gemm)
  float* ztb = zta + 2097152;
  float* az  = ztb + 2097152;
  float* ta  = az + 2097152;
  float* tc  = ta + 2097152;
  u16* Ob = xb;                       // attn1 output aliases xb (dead after qproj)

  hipMemsetAsync(cmax, 0, 4, stream);
  k_f2b<<<16384, 256, 0, stream>>>(x, xb, 4194304);
  k_f2b<<<8192, 256, 0, stream>>>(z, zb, 2097152);
  k_wt<<<1024, 256, 0, stream>>>(Wq, wqt, 512);
  k_wt<<<2048, 256, 0, stream>>>(Wkv, wkvt, 1024);
  k_wt<<<1024, 256, 0, stream>>>(Wo, wot, 512);

  k_gemm_nt<0><<<dim3(8, 512, 1), 256, 0, stream>>>(xb, wqt, qb, nullptr, nullptr,
                                                    nullptr, 512, 0, 0, 0, 0);
  k_gemm_nt<1><<<dim3(16, 256, 1), 256, 0, stream>>>(zb, wkvt, kb, vtb, nullptr,
                                                     nullptr, 512, 0, 0, 0, 0);
  k_landmark<<<2048, 256, 0, stream>>>(qb, qlf, qlb, 8192, 32, 1.f / 32.f);
  k_landmark<<<2048, 256, 0, stream>>>(kb, klf, klb, 4096, 16, 1.f / 16.f);
  k_sim2_softmax<<<dim3(256, 32), 256, 0, stream>>>(qlf, klf, attn2);
  k_colmax<<<32, 256, 0, stream>>>(attn2, cmax);

  // sim3 logits -> softmax -> T1 = attn3 @ v   (must finish BEFORE pinv temps alias S3)
  k_gemm_nt<3><<<dim3(64, 4, 32), 256, 0, stream>>>(
      qlb, kb, S3, nullptr, nullptr, nullptr, 64, 16384, 262144, 1048576, 4096);
  k_softmax_row4096<<<8192, 256, 0, stream>>>(S3);
  k_gemm_nt<4><<<dim3(1, 4, 32), 256, 0, stream>>>(
      S3, vtb, T1, nullptr, nullptr, nullptr, 4096, 1048576, 262144, 16384, 64);

  // Newton-Schulz pinv (fp32); zta..tc alias S3 region (S3 now dead)
  k_init_zt<<<8192, 256, 0, stream>>>(attn2, zta, cmax);
  auto nn = [&](const float* A, const float* Bp, void* C, int Nc, int K, long sA,
                long sB, long sC, float bdiag, float bsc, float cdiag, float csc,
                int outbf) {
    k_gemm_nn_f32<<<dim3(Nc / 64, 4, 32), 256, 0, stream>>>(
        A, Bp, C, Nc, K, sA, sB, sC, bdiag, bsc, cdiag, csc, outbf);
  };
  float* cur = zta;
  float* nxt = ztb;
  for (int it = 0; it < 6; ++it) {
    nn(attn2, cur, az, 256, 256, 65536, 65536, 65536, 0.f, 1.f, 0.f, 1.f, 0);
    nn(az, az, ta, 256, 256, 65536, 65536, 65536, 7.f, -1.f, 15.f, -1.f, 0);
    nn(az, ta, tc, 256, 256, 65536, 65536, 65536, 0.f, 1.f, 13.f, -1.f, 0);
    nn(cur, tc, nxt, 256, 256, 65536, 65536, 65536, 0.f, 1.f, 0.f, 0.25f, 0);
    float* tmp = cur; cur = nxt; nxt = tmp;
  }
  // T2 = attn2_inv @ T1  (bf16 out)
  nn(cur, T1, T2b, 64, 256, 65536, 16384, 16384, 0.f, 1.f, 0.f, 1.f, 1);

  k_fused_attn1<<<dim3(128, 32), 256, 0, stream>>>(qb, klb, T2b, Ob);
  k_gemm_nt<2><<<dim3(8, 512, 1), 256, 0, stream>>>(Ob, wot, out, nullptr, x, bo,
                                                    512, 0, 0, 0, 512);
}

// Round 3
// 897.271 us; speedup vs baseline: 1.1052x; 1.1052x over previous
//
#include <hip/hip_runtime.h>

typedef unsigned short u16;
typedef __attribute__((ext_vector_type(8))) short bf16x8s;
typedef __attribute__((ext_vector_type(4))) float f32x4;

#define DEV static __device__ __forceinline__

DEV float b2f(u16 v) { return __uint_as_float(((unsigned)v) << 16); }
DEV u16 f2b(float f) {
  unsigned u = __float_as_uint(f);
  unsigned r = (u + 0x7fffu + ((u >> 16) & 1u)) >> 16;
  return (u16)r;
}

// ---------------- elementwise converts ----------------
__global__ __launch_bounds__(256) void k_f2b(const float* __restrict__ in,
                                             u16* __restrict__ o, long n4) {
  long i = (long)blockIdx.x * 256 + threadIdx.x;
  if (i >= n4) return;
  float4 v = *(const float4*)(in + i * 4);
  u16* d = o + i * 4;
  d[0] = f2b(v.x); d[1] = f2b(v.y); d[2] = f2b(v.z); d[3] = f2b(v.w);
}

// W[k][N] (fp32) -> Wt[n][512] bf16  (K fixed = 512)
__global__ __launch_bounds__(256) void k_wt(const float* __restrict__ W,
                                            u16* __restrict__ Wt, int N) {
  int e = blockIdx.x * 256 + threadIdx.x;  // e < N*512
  int nn = e >> 9, kk = e & 511;
  Wt[e] = f2b(W[(long)kk * N + nn]);
}

// ---------------- bf16 NT GEMM: C = A[M,K] @ B[N,K]^T ----------------
// MODE 0: q-proj (scale 0.125, write q[b,h,n,dh])
// MODE 1: kv-proj (write k[b,h,nz,dh] and vt[b,h,dh,nz])
// MODE 2: out-proj (+x + bias, fp32 out)
// MODE 3: batched bf16 store (ldc)
// MODE 5: T1^T split-bf16 store: C0=hi, C1=lo, [bz][64][256]
template <int MODE>
__global__ __launch_bounds__(256) void k_gemm_nt(
    const u16* __restrict__ A, const u16* __restrict__ Bm, void* __restrict__ C0,
    void* __restrict__ C1, const float* __restrict__ xres,
    const float* __restrict__ bias, int K, long sA, long sB, long sC, int ldc) {
  const int bz = blockIdx.z;
  A += (long)bz * sA;
  Bm += (long)bz * sB;
  // bijective XCD-chunked swizzle (m204): contiguous linear-id band per XCD ->
  // A-tile re-reads across n-blocks become same-XCD L2 hits.
  const int nwg = gridDim.x * gridDim.y;
  const int orig = blockIdx.y * gridDim.x + blockIdx.x;
  const int qq = nwg >> 3, rr = nwg & 7;
  const int xcd = orig & 7, loc = orig >> 3;
  const int swz = (xcd < rr ? xcd * (qq + 1) : rr * (qq + 1) + (xcd - rr) * qq) + loc;
  const int m0 = (swz / gridDim.x) << 6, n0 = (swz % gridDim.x) << 6;
  const int t = threadIdx.x, lane = t & 63, w = t >> 6;
  const int wm = (w >> 1) << 5, wn = (w & 1) << 5;
  const int fr = lane & 15, fk = (lane >> 4) << 3;
  __shared__ u16 As[64][40];
  __shared__ u16 Bs[64][40];
  f32x4 acc[2][2] = {};
  const int sr = t >> 2, sc = (t & 3) << 3;
  for (int k0 = 0; k0 < K; k0 += 32) {
    *(bf16x8s*)&As[sr][sc] = *(const bf16x8s*)&A[(long)(m0 + sr) * K + k0 + sc];
    *(bf16x8s*)&Bs[sr][sc] = *(const bf16x8s*)&Bm[(long)(n0 + sr) * K + k0 + sc];
    __syncthreads();
    bf16x8s a0 = *(const bf16x8s*)&As[wm + fr][fk];
    bf16x8s a1 = *(const bf16x8s*)&As[wm + 16 + fr][fk];
    bf16x8s b0 = *(const bf16x8s*)&Bs[wn + fr][fk];
    bf16x8s b1 = *(const bf16x8s*)&Bs[wn + 16 + fr][fk];
    acc[0][0] = __builtin_amdgcn_mfma_f32_16x16x32_bf16(a0, b0, acc[0][0], 0, 0, 0);
    acc[0][1] = __builtin_amdgcn_mfma_f32_16x16x32_bf16(a0, b1, acc[0][1], 0, 0, 0);
    acc[1][0] = __builtin_amdgcn_mfma_f32_16x16x32_bf16(a1, b0, acc[1][0], 0, 0, 0);
    acc[1][1] = __builtin_amdgcn_mfma_f32_16x16x32_bf16(a1, b1, acc[1][1], 0, 0, 0);
    __syncthreads();
  }
  const int crow = (lane >> 4) << 2;
#pragma unroll
  for (int fi = 0; fi < 2; ++fi)
#pragma unroll
    for (int fj = 0; fj < 2; ++fj)
#pragma unroll
      for (int r = 0; r < 4; ++r) {
        int row = m0 + wm + fi * 16 + crow + r;
        int col = n0 + wn + fj * 16 + fr;
        float v = acc[fi][fj][r];
        if (MODE == 0) {
          int b = row >> 13, n = row & 8191, h = col >> 6, dh = col & 63;
          ((u16*)C0)[((((long)(b * 8 + h)) << 13) + n) * 64 + dh] = f2b(v * 0.125f);
        } else if (MODE == 1) {
          int b = row >> 12, nz = row & 4095;
          if (col < 512) {
            int h = col >> 6, dh = col & 63;
            ((u16*)C0)[((((long)(b * 8 + h)) << 12) + nz) * 64 + dh] = f2b(v);
          } else {
            int c2 = col - 512, h = c2 >> 6, dh = c2 & 63;
            ((u16*)C1)[((((long)(b * 8 + h) * 64 + dh)) << 12) + nz] = f2b(v);
          }
        } else if (MODE == 2) {
          long idx = ((long)row << 9) + col;
          ((float*)C0)[idx] = v + xres[idx] + bias[col];
        } else if (MODE == 3) {
          ((u16*)C0)[(long)bz * sC + (long)row * ldc + col] = f2b(v);
        } else if (MODE == 5) {
          long idx = ((long)bz << 14) + ((long)col << 8) + row;  // [bz][64][256]
          u16 h = f2b(v);
          ((u16*)C0)[idx] = h;
          ((u16*)C1)[idx] = f2b(v - b2f(h));
        }
      }
}

// ---------------- split-bf16 MFMA NN GEMM (pinv chain) ----------------
// C[i][j] = sab*(A@B)[i][j] + sa*A[i][j] + cdiag*(i==j)
// A: [bz][256][256] as (Ahi,Alo) row-major. B: [bz][Nc? no: K=256][Nc] logical,
// stored transposed (Bthi,Btlo) = [bz][Nc][256] (k contiguous).
// Outputs (any may be null): CN (hi,lo) normal [256][Nc]; CT (hi,lo) transposed
// [Nc][256]. If CNlo==null, CNhi gets single-bf16 (plain) values.
__global__ __launch_bounds__(256) void k_nn_mfma(
    const u16* __restrict__ Ahi, const u16* __restrict__ Alo,
    const u16* __restrict__ Bthi, const u16* __restrict__ Btlo,
    u16* __restrict__ CNhi, u16* __restrict__ CNlo,
    u16* __restrict__ CThi, u16* __restrict__ CTlo,
    int Nc, float sab, float sa, float cdiag) {
  const int bz = blockIdx.z;
  const long offA = (long)bz << 16;
  const long offB = (long)bz * ((long)Nc << 8);
  const int m0 = blockIdx.y << 6, n0 = blockIdx.x << 6;
  const int t = threadIdx.x, lane = t & 63, w = t >> 6;
  const int wm = (w >> 1) << 5, wn = (w & 1) << 5;
  const int fr = lane & 15, fk = (lane >> 4) << 3;
  __shared__ char lds[32768];  // Ahi|Alo|Bhi|Blo tiles, each [64][64] u16 (8KB), XOR-swizzled
  f32x4 acc[2][2] = {};
  const int sr = t >> 2, sc = (t & 3) << 4;       // staging: row 0..63, col base {0,16,32,48}
  const int wby = sr * 128 + sc * 2;              // byte offset of (sr, sc)
  const int wsw = (sr & 7) << 4;
  const int frsw = (fr & 7) << 4;
  for (int k0 = 0; k0 < 256; k0 += 64) {
    const long ab = offA + (long)(m0 + sr) * 256 + k0 + sc;
    const long bb = offB + (long)(n0 + sr) * 256 + k0 + sc;
    bf16x8s ah0 = *(const bf16x8s*)(Ahi + ab);
    bf16x8s ah1 = *(const bf16x8s*)(Ahi + ab + 8);
    bf16x8s al0 = *(const bf16x8s*)(Alo + ab);
    bf16x8s al1 = *(const bf16x8s*)(Alo + ab + 8);
    bf16x8s bh0 = *(const bf16x8s*)(Bthi + bb);
    bf16x8s bh1 = *(const bf16x8s*)(Bthi + bb + 8);
    bf16x8s bl0 = *(const bf16x8s*)(Btlo + bb);
    bf16x8s bl1 = *(const bf16x8s*)(Btlo + bb + 8);
    __syncthreads();
    *(bf16x8s*)(lds + (wby ^ wsw)) = ah0;
    *(bf16x8s*)(lds + ((wby + 16) ^ wsw)) = ah1;
    *(bf16x8s*)(lds + 8192 + (wby ^ wsw)) = al0;
    *(bf16x8s*)(lds + 8192 + ((wby + 16) ^ wsw)) = al1;
    *(bf16x8s*)(lds + 16384 + (wby ^ wsw)) = bh0;
    *(bf16x8s*)(lds + 16384 + ((wby + 16) ^ wsw)) = bh1;
    *(bf16x8s*)(lds + 24576 + (wby ^ wsw)) = bl0;
    *(bf16x8s*)(lds + 24576 + ((wby + 16) ^ wsw)) = bl1;
    __syncthreads();
#pragma unroll
    for (int ks = 0; ks < 64; ks += 32) {
      const int kb = (ks + fk) << 1;
      const int ra0 = (wm + fr) * 128 + kb, ra1 = (wm + 16 + fr) * 128 + kb;
      const int rb0 = (wn + fr) * 128 + kb, rb1 = (wn + 16 + fr) * 128 + kb;
      bf16x8s fah0 = *(const bf16x8s*)(lds + (ra0 ^ frsw));
      bf16x8s fah1 = *(const bf16x8s*)(lds + (ra1 ^ frsw));
      bf16x8s fal0 = *(const bf16x8s*)(lds + 8192 + (ra0 ^ frsw));
      bf16x8s fal1 = *(const bf16x8s*)(lds + 8192 + (ra1 ^ frsw));
      bf16x8s fbh0 = *(const bf16x8s*)(lds + 16384 + (rb0 ^ frsw));
      bf16x8s fbh1 = *(const bf16x8s*)(lds + 16384 + (rb1 ^ frsw));
      bf16x8s fbl0 = *(const bf16x8s*)(lds + 24576 + (rb0 ^ frsw));
      bf16x8s fbl1 = *(const bf16x8s*)(lds + 24576 + (rb1 ^ frsw));
      acc[0][0] = __builtin_amdgcn_mfma_f32_16x16x32_bf16(fah0, fbh0, acc[0][0], 0, 0, 0);
      acc[0][0] = __builtin_amdgcn_mfma_f32_16x16x32_bf16(fah0, fbl0, acc[0][0], 0, 0, 0);
      acc[0][0] = __builtin_amdgcn_mfma_f32_16x16x32_bf16(fal0, fbh0, acc[0][0], 0, 0, 0);
      acc[0][1] = __builtin_amdgcn_mfma_f32_16x16x32_bf16(fah0, fbh1, acc[0][1], 0, 0, 0);
      acc[0][1] = __builtin_amdgcn_mfma_f32_16x16x32_bf16(fah0, fbl1, acc[0][1], 0, 0, 0);
      acc[0][1] = __builtin_amdgcn_mfma_f32_16x16x32_bf16(fal0, fbh1, acc[0][1], 0, 0, 0);
      acc[1][0] = __builtin_amdgcn_mfma_f32_16x16x32_bf16(fah1, fbh0, acc[1][0], 0, 0, 0);
      acc[1][0] = __builtin_amdgcn_mfma_f32_16x16x32_bf16(fah1, fbl0, acc[1][0], 0, 0, 0);
      acc[1][0] = __builtin_amdgcn_mfma_f32_16x16x32_bf16(fal1, fbh0, acc[1][0], 0, 0, 0);
      acc[1][1] = __builtin_amdgcn_mfma_f32_16x16x32_bf16(fah1, fbh1, acc[1][1], 0, 0, 0);
      acc[1][1] = __builtin_amdgcn_mfma_f32_16x16x32_bf16(fah1, fbl1, acc[1][1], 0, 0, 0);
      acc[1][1] = __builtin_amdgcn_mfma_f32_16x16x32_bf16(fal1, fbh1, acc[1][1], 0, 0, 0);
    }
  }
  const int crow = (lane >> 4) << 2;
  const long offC = (long)bz * ((long)Nc << 8);
#pragma unroll
  for (int i = 0; i < 2; ++i)
#pragma unroll
    for (int j = 0; j < 2; ++j)
#pragma unroll
      for (int r = 0; r < 4; ++r) {
        int row = m0 + wm + i * 16 + crow + r;
        int col = n0 + wn + j * 16 + fr;
        float v = sab * acc[i][j][r];
        if (sa != 0.f) {
          long ai = offA + ((long)row << 8) + col;
          v += sa * (b2f(Ahi[ai]) + b2f(Alo[ai]));
        }
        if (row == col) v += cdiag;
        if (CNhi) {
          long ci = offC + (long)row * Nc + col;
          u16 h = f2b(v);
          if (CNlo) { CNhi[ci] = h; CNlo[ci] = f2b(v - b2f(h)); }
          else CNhi[ci] = h;
        }
        if (CThi) {
          long ti = offC + ((long)col << 8) + row;
          u16 h = f2b(v);
          CThi[ti] = h;
          CTlo[ti] = f2b(v - b2f(h));
        }
      }
}

// ---------------- landmarks ----------------
__global__ __launch_bounds__(256) void k_landmark(const u16* __restrict__ src,
                                                  float* __restrict__ df,
                                                  u16* __restrict__ db, int ntok,
                                                  int l, float inv) {
  int pidx = blockIdx.x * 4 + (threadIdx.x >> 6);
  int d = threadIdx.x & 63;
  int bh = pidx >> 8, m = pidx & 255;
  const u16* s = src + ((long)bh * ntok + (long)m * l) * 64 + d;
  float sum = 0.f;
  for (int j = 0; j < l; ++j) sum += b2f(s[j * 64]);
  sum *= inv;
  long o = ((long)bh * 256 + m) * 64 + d;
  df[o] = sum;
  db[o] = f2b(sum);
}

// ---------------- sim2 + softmax (fp32) ----------------
__global__ __launch_bounds__(256) void k_sim2_softmax(const float* __restrict__ qlf,
                                                      const float* __restrict__ klf,
                                                      float* __restrict__ attn2) {
  int m = blockIdx.x, bh = blockIdx.y;
  int j = threadIdx.x, lane = j & 63, w = j >> 6;
  const float* qr = qlf + ((long)bh * 256 + m) * 64;
  const float* kr = klf + ((long)bh * 256 + j) * 64;
  float s = 0.f;
#pragma unroll
  for (int d = 0; d < 64; ++d) s += qr[d] * kr[d];
  float mx = s;
  for (int o = 1; o < 64; o <<= 1) mx = fmaxf(mx, __shfl_xor(mx, o, 64));
  __shared__ float r1[4], r2[4];
  if (lane == 0) r1[w] = mx;
  __syncthreads();
  mx = fmaxf(fmaxf(r1[0], r1[1]), fmaxf(r1[2], r1[3]));
  float e = __expf(s - mx);
  float su = e;
  for (int o = 1; o < 64; o <<= 1) su += __shfl_xor(su, o, 64);
  if (lane == 0) r2[w] = su;
  __syncthreads();
  su = r2[0] + r2[1] + r2[2] + r2[3];
  attn2[(((long)bh * 256 + m) << 8) + j] = e / su;
}

__global__ __launch_bounds__(256) void k_colmax(const float* __restrict__ attn2,
                                                unsigned* __restrict__ cmax) {
  int bh = blockIdx.x, j = threadIdx.x, lane = j & 63, w = j >> 6;
  const float* p = attn2 + ((long)bh << 16) + j;
  float s = 0.f;
  for (int m = 0; m < 256; ++m) s += p[m * 256];
  float mx = s;
  for (int o = 1; o < 64; o <<= 1) mx = fmaxf(mx, __shfl_xor(mx, o, 64));
  __shared__ float r1[4];
  if (lane == 0) r1[w] = mx;
  __syncthreads();
  if (j == 0) {
    mx = fmaxf(fmaxf(r1[0], r1[1]), fmaxf(r1[2], r1[3]));
    atomicMax(cmax, __float_as_uint(mx));
  }
}

// ---------------- pinv operand prep ----------------
// From fp32 attn2 (per bh 256x256) and cmax build:
//   aN  (hi,lo) = split(attn2)            [A-operand, normal layout]
//   zN  (hi,lo) = split(attn2^T * s)      [zt0 normal]
//   zT  (hi,lo) = split(attn2 * s)        [zt0 transposed layout]
__global__ __launch_bounds__(256) void k_prep_pinv(
    const float* __restrict__ attn2, const unsigned* __restrict__ cmax,
    u16* __restrict__ aNhi, u16* __restrict__ aNlo,
    u16* __restrict__ zNhi, u16* __restrict__ zNlo,
    u16* __restrict__ zThi, u16* __restrict__ zTlo) {
  const int bz = blockIdx.z, i0 = blockIdx.y << 6, j0 = blockIdx.x << 6;
  const float s = 1.f / __uint_as_float(*cmax);
  const float* base = attn2 + ((long)bz << 16);
  __shared__ float mt[64][65];
  const int r = threadIdx.x >> 2, cb = (threadIdx.x & 3) << 4;
#pragma unroll
  for (int c4 = 0; c4 < 16; c4 += 4) {
    float4 v = *(const float4*)&base[(long)(j0 + r) * 256 + i0 + cb + c4];
    mt[r][cb + c4] = v.x; mt[r][cb + c4 + 1] = v.y;
    mt[r][cb + c4 + 2] = v.z; mt[r][cb + c4 + 3] = v.w;
  }
  __syncthreads();
  const int i = i0 + r;
#pragma unroll
  for (int c4 = 0; c4 < 16; c4 += 4) {
    float4 v = *(const float4*)&base[(long)i * 256 + j0 + cb + c4];
    float vv[4] = {v.x, v.y, v.z, v.w};
#pragma unroll
    for (int e = 0; e < 4; ++e) {
      int j = j0 + cb + c4 + e;
      long idx = ((long)bz << 16) + ((long)i << 8) + j;
      float a = vv[e];
      u16 h = f2b(a);
      aNhi[idx] = h; aNlo[idx] = f2b(a - b2f(h));
      float zt = a * s;
      u16 zh = f2b(zt);
      zThi[idx] = zh; zTlo[idx] = f2b(zt - b2f(zh));
      float zn = mt[cb + c4 + e][r] * s;
      u16 nh = f2b(zn);
      zNhi[idx] = nh; zNlo[idx] = f2b(zn - b2f(nh));
    }
  }
}

// ---------------- softmax over 4096-long rows (bf16 in place) ----------------
__global__ __launch_bounds__(256) void k_softmax_row4096(u16* __restrict__ S) {
  long row = blockIdx.x;
  u16* p = S + row * 4096 + threadIdx.x;
  int lane = threadIdx.x & 63, w = threadIdx.x >> 6;
  float v[16];
  float mx = -3.4e38f;
#pragma unroll
  for (int i = 0; i < 16; ++i) { v[i] = b2f(p[i * 256]); mx = fmaxf(mx, v[i]); }
  for (int o = 1; o < 64; o <<= 1) mx = fmaxf(mx, __shfl_xor(mx, o, 64));
  __shared__ float r1[4], r2[4];
  if (lane == 0) r1[w] = mx;
  __syncthreads();
  mx = fmaxf(fmaxf(r1[0], r1[1]), fmaxf(r1[2], r1[3]));
  float su = 0.f;
#pragma unroll
  for (int i = 0; i < 16; ++i) { v[i] = __expf(v[i] - mx); su += v[i]; }
  for (int o = 1; o < 64; o <<= 1) su += __shfl_xor(su, o, 64);
  if (lane == 0) r2[w] = su;
  __syncthreads();
  su = r2[0] + r2[1] + r2[2] + r2[3];
  float inv = 1.f / su;
#pragma unroll
  for (int i = 0; i < 16; ++i) p[i * 256] = f2b(v[i] * inv);
}

// ---------------- fused sim1: O = softmax(q @ k_land^T) @ T2 ----------------
__global__ __launch_bounds__(256) void k_fused_attn1(const u16* __restrict__ q,
                                                     const u16* __restrict__ klb,
                                                     const u16* __restrict__ t2b,
                                                     u16* __restrict__ O) {
  const int bh = blockIdx.y, n0 = blockIdx.x << 6;
  const int bb = bh >> 3, hh = bh & 7;
  const int t = threadIdx.x, lane = t & 63, w = t >> 6;
  const int fr = lane & 15, g = lane >> 4, fk = g << 3;
  __shared__ char lds[65536];  // [0,32K)=k_land swz (later aliased by P), [32K,64K)=T2^T swz
  {
    const u16* src = klb + (long)bh * 16384;
#pragma unroll
    for (int i = 0; i < 8; ++i) {
      int c = t + (i << 8);
      int byte = c << 4;
      int sw = byte ^ (((byte >> 7) & 7) << 4);
      *(bf16x8s*)(lds + sw) = *(const bf16x8s*)(src + (c << 3));
    }
    const u16* src2 = t2b + (long)bh * 16384;
#pragma unroll
    for (int i = 0; i < 64; ++i) {
      int e = t + (i << 8);
      int k = e >> 6, dh = e & 63;
      int byte = (dh << 9) + (k << 1);
      int sw = byte ^ ((dh & 7) << 4);
      *(u16*)(lds + 32768 + sw) = src2[e];
    }
  }
  __syncthreads();

  const u16* qrow = q + ((long)bh * 8192 + n0 + (w << 4) + fr) * 64;
  bf16x8s a0 = *(const bf16x8s*)(qrow + fk);
  bf16x8s a1 = *(const bf16x8s*)(qrow + 32 + fk);

  f32x4 s[16];
#pragma unroll
  for (int c = 0; c < 16; ++c) {
    int j = (c << 4) + fr;
    int base = (j << 7) + (fk << 1);
    int swm = (j & 7) << 4;
    bf16x8s b0 = *(const bf16x8s*)(lds + (base ^ swm));
    bf16x8s b1 = *(const bf16x8s*)(lds + ((base + 64) ^ swm));
    f32x4 zz = {};
    zz = __builtin_amdgcn_mfma_f32_16x16x32_bf16(a0, b0, zz, 0, 0, 0);
    zz = __builtin_amdgcn_mfma_f32_16x16x32_bf16(a1, b1, zz, 0, 0, 0);
    s[c] = zz;
  }
  float mr[4], li[4];
#pragma unroll
  for (int r = 0; r < 4; ++r) {
    float m = s[0][r];
#pragma unroll
    for (int c = 1; c < 16; ++c) m = fmaxf(m, s[c][r]);
    m = fmaxf(m, __shfl_xor(m, 1, 64));
    m = fmaxf(m, __shfl_xor(m, 2, 64));
    m = fmaxf(m, __shfl_xor(m, 4, 64));
    m = fmaxf(m, __shfl_xor(m, 8, 64));
    mr[r] = m;
  }
#pragma unroll
  for (int r = 0; r < 4; ++r) {
    float l = 0.f;
#pragma unroll
    for (int c = 0; c < 16; ++c) {
      float e = __expf(s[c][r] - mr[r]);
      s[c][r] = e;
      l += e;
    }
    l += __shfl_xor(l, 1, 64);
    l += __shfl_xor(l, 2, 64);
    l += __shfl_xor(l, 4, 64);
    l += __shfl_xor(l, 8, 64);
    li[r] = 1.f / l;
  }
  __syncthreads();  // everyone done reading k_land; its LDS now reused as P staging

  char* plw = lds + (w << 10);  // 1KB per wave: P[16][32] bf16, swizzled
  f32x4 o4[4] = {};
#pragma unroll
  for (int pair = 0; pair < 8; ++pair) {
#pragma unroll
    for (int cc = 0; cc < 2; ++cc) {
      int c = (pair << 1) + cc;
#pragma unroll
      for (int r = 0; r < 4; ++r) {
        int row = (g << 2) + r;
        int byte = (row << 6) + (((cc << 4) + fr) << 1);
        int sw = byte ^ ((row & 7) << 4);
        *(u16*)(plw + sw) = f2b(s[c][r] * li[r]);
      }
    }
    asm volatile("s_waitcnt lgkmcnt(0)" ::: "memory");
    __builtin_amdgcn_sched_barrier(0);
    int abyte = (fr << 6) + (fk << 1);
    bf16x8s ap = *(const bf16x8s*)(plw + (abyte ^ ((fr & 7) << 4)));
#pragma unroll
    for (int d = 0; d < 4; ++d) {
      int dh = (d << 4) + fr;
      int tb = (dh << 9) + (((pair << 5) + fk) << 1);
      bf16x8s bv = *(const bf16x8s*)(lds + 32768 + (tb ^ ((dh & 7) << 4)));
      o4[d] = __builtin_amdgcn_mfma_f32_16x16x32_bf16(ap, bv, o4[d], 0, 0, 0);
    }
    asm volatile("s_waitcnt lgkmcnt(0)" ::: "memory");
    __builtin_amdgcn_sched_barrier(0);
  }
  u16* ob = O + (((long)bb * 8192 + n0 + (w << 4)) << 9) + (hh << 6);
#pragma unroll
  for (int d = 0; d < 4; ++d)
#pragma unroll
    for (int r = 0; r < 4; ++r) {
      int row = (g << 2) + r;
      int col = (d << 4) + fr;
      ob[((long)row << 9) + col] = f2b(o4[d][r]);
    }
}

// ---------------- host ----------------
extern "C" void kernel_launch(void* const* d_in, const int* in_sizes, int n_in,
                              void* d_out, int out_size, void* d_ws, size_t ws_size,
                              hipStream_t stream) {
  const float* x = (const float*)d_in[0];
  const float* z = (const float*)d_in[1];
  const float* Wq = (const float*)d_in[2];
  const float* Wkv = (const float*)d_in[3];
  const float* Wo = (const float*)d_in[4];
  const float* bo = (const float*)d_in[5];
  float* out = (float*)d_out;

  char* base = (char*)d_ws;
  size_t off = 0;
  auto alloc = [&](size_t bytes) -> void* {
    void* r = base + off;
    off = (off + bytes + 255) & ~(size_t)255;
    return r;
  };
  // ---- live-range-aware layout (~195 MB) ----
  u16* qb = (u16*)alloc(33554432);    // q bf16 [b,h,n,dh]           live: qproj -> attn1
  u16* kb = (u16*)alloc(16777216);    // k bf16 [b,h,nz,dh]          live: kvproj -> sim3
  u16* vtb = (u16*)alloc(16777216);   // v^T bf16 [b,h,dh,nz]        live: kvproj -> T1
  u16* S3 = (u16*)alloc(67108864);    // sim3 probs (64MB); dead after T1 -> pinv state
  float* attn2 = (float*)alloc(8388608);
  u16* xb = (u16*)alloc(33554432);    // x bf16; dead after qproj -> reused as Ob
  u16* zb = (u16*)alloc(16777216);    // z bf16; dead after kvproj -> attn2 split
  u16* wqt = (u16*)alloc(524288);
  u16* wkvt = (u16*)alloc(1048576);
  u16* wot = (u16*)alloc(524288);
  float* qlf = (float*)alloc(2097152);
  u16* qlb = (u16*)alloc(1048576);
  float* klf = (float*)alloc(2097152);
  u16* klb = (u16*)alloc(1048576);
  u16* T1t = (u16*)alloc(2097152);    // T1^T split: hi [32][64][256], then lo
  u16* T2b = (u16*)alloc(1048576);
  unsigned* cmax = (unsigned*)alloc(256);
  // pinv state aliased over dead S3 (16 components x 4MB = 64MB exactly)
  const long MC = 2097152;  // elements per component
  u16* P = S3;
  u16 *ztA_Nhi = P,         *ztA_Nlo = P + MC,     *ztA_Thi = P + 2 * MC,  *ztA_Tlo = P + 3 * MC;
  u16 *ztB_Nhi = P + 4 * MC, *ztB_Nlo = P + 5 * MC, *ztB_Thi = P + 6 * MC, *ztB_Tlo = P + 7 * MC;
  u16 *az_Nhi = P + 8 * MC,  *az_Nlo = P + 9 * MC,  *az_Thi = P + 10 * MC, *az_Tlo = P + 11 * MC;
  u16 *taThi = P + 12 * MC,  *taTlo = P + 13 * MC;
  u16 *tcThi = P + 14 * MC,  *tcTlo = P + 15 * MC;
  // attn2 split over dead zb (2 x 4MB)
  u16 *aNhi = zb, *aNlo = zb + MC;
  u16* T1thi = T1t;
  u16* T1tlo = T1t + 524288;
  u16* Ob = xb;

  hipMemsetAsync(cmax, 0, 4, stream);
  k_f2b<<<16384, 256, 0, stream>>>(x, xb, 4194304);
  k_f2b<<<8192, 256, 0, stream>>>(z, zb, 2097152);
  k_wt<<<1024, 256, 0, stream>>>(Wq, wqt, 512);
  k_wt<<<2048, 256, 0, stream>>>(Wkv, wkvt, 1024);
  k_wt<<<1024, 256, 0, stream>>>(Wo, wot, 512);

  k_gemm_nt<0><<<dim3(8, 512, 1), 256, 0, stream>>>(xb, wqt, qb, nullptr, nullptr,
                                                    nullptr, 512, 0, 0, 0, 0);
  k_gemm_nt<1><<<dim3(16, 256, 1), 256, 0, stream>>>(zb, wkvt, kb, vtb, nullptr,
                                                     nullptr, 512, 0, 0, 0, 0);
  k_landmark<<<2048, 256, 0, stream>>>(qb, qlf, qlb, 8192, 32, 1.f / 32.f);
  k_landmark<<<2048, 256, 0, stream>>>(kb, klf, klb, 4096, 16, 1.f / 16.f);
  k_sim2_softmax<<<dim3(256, 32), 256, 0, stream>>>(qlf, klf, attn2);
  k_colmax<<<32, 256, 0, stream>>>(attn2, cmax);

  // sim3 logits -> softmax -> T1^T (split bf16). Must finish BEFORE pinv aliases S3.
  k_gemm_nt<3><<<dim3(64, 4, 32), 256, 0, stream>>>(
      qlb, kb, S3, nullptr, nullptr, nullptr, 64, 16384, 262144, 1048576, 4096);
  k_softmax_row4096<<<8192, 256, 0, stream>>>(S3);
  k_gemm_nt<5><<<dim3(1, 4, 32), 256, 0, stream>>>(
      S3, vtb, T1thi, T1tlo, nullptr, nullptr, 4096, 1048576, 262144, 0, 0);

  // zb now dead (kvproj done) -> attn2 split; S3 dead -> pinv state
  k_prep_pinv<<<dim3(4, 4, 32), 256, 0, stream>>>(attn2, cmax, aNhi, aNlo,
                                                  ztA_Nhi, ztA_Nlo, ztA_Thi, ztA_Tlo);

  // Newton-Schulz: az = a@zt; ta = az@az - 7az + 15I; tc = -az@ta + 13I; znew = 0.25 zt@tc
  dim3 g256(4, 4, 32);
  u16 *cN0 = ztA_Nhi, *cN1 = ztA_Nlo, *cT0 = ztA_Thi, *cT1 = ztA_Tlo;
  u16 *nN0 = ztB_Nhi, *nN1 = ztB_Nlo, *nT0 = ztB_Thi, *nT1 = ztB_Tlo;
  for (int it = 0; it < 6; ++it) {
    bool last = (it == 5);
    k_nn_mfma<<<g256, 256, 0, stream>>>(aNhi, aNlo, cT0, cT1, az_Nhi, az_Nlo,
                                        az_Thi, az_Tlo, 256, 1.f, 0.f, 0.f);
    k_nn_mfma<<<g256, 256, 0, stream>>>(az_Nhi, az_Nlo, az_Thi, az_Tlo, nullptr,
                                        nullptr, taThi, taTlo, 256, 1.f, -7.f, 15.f);
    k_nn_mfma<<<g256, 256, 0, stream>>>(az_Nhi, az_Nlo, taThi, taTlo, nullptr,
                                        nullptr, tcThi, tcTlo, 256, -1.f, 0.f, 13.f);
    k_nn_mfma<<<g256, 256, 0, stream>>>(cN0, cN1, tcThi, tcTlo, nN0, nN1,
                                        last ? nullptr : nT0, last ? nullptr : nT1,
                                        256, 0.25f, 0.f, 0.f);
    u16* t0;
    t0 = cN0; cN0 = nN0; nN0 = t0;  t0 = cN1; cN1 = nN1; nN1 = t0;
    t0 = cT0; cT0 = nT0; nT0 = t0;  t0 = cT1; cT1 = nT1; nT1 = t0;
  }
  // T2 = pinv @ T1 (plain bf16 out, [bh][256][64])
  k_nn_mfma<<<dim3(1, 4, 32), 256, 0, stream>>>(cN0, cN1, T1thi, T1tlo, T2b,
                                                nullptr, nullptr, nullptr, 64,
                                                1.f, 0.f, 0.f);

  k_fused_attn1<<<dim3(128, 32), 256, 0, stream>>>(qb, klb, T2b, Ob);
  k_gemm_nt<2><<<dim3(8, 512, 1), 256, 0, stream>>>(Ob, wot, out, nullptr, x, bo,
                                                    512, 0, 0, 0, 512);
}

// Round 4
// 802.162 us; speedup vs baseline: 1.2362x; 1.1186x over previous
//
#include <hip/hip_runtime.h>

typedef unsigned short u16;
typedef __attribute__((ext_vector_type(8))) short bf16x8s;
typedef __attribute__((ext_vector_type(4))) float f32x4;

#define DEV static __device__ __forceinline__

DEV float b2f(u16 v) { return __uint_as_float(((unsigned)v) << 16); }
DEV u16 f2b(float f) {
  unsigned u = __float_as_uint(f);
  unsigned r = (u + 0x7fffu + ((u >> 16) & 1u)) >> 16;
  return (u16)r;
}

// async global->LDS, 16B per lane; lds base must be wave-uniform (HW adds lane*16)
#define GLL(gp, lp)                                                            \
  __builtin_amdgcn_global_load_lds(                                            \
      (const __attribute__((address_space(1))) unsigned int*)(gp),             \
      (__attribute__((address_space(3))) unsigned int*)(lp), 16, 0, 0)

// ---------------- elementwise converts ----------------
__global__ __launch_bounds__(256) void k_f2b(const float* __restrict__ in,
                                             u16* __restrict__ o, long n4) {
  long i = (long)blockIdx.x * 256 + threadIdx.x;
  if (i >= n4) return;
  float4 v = *(const float4*)(in + i * 4);
  u16* d = o + i * 4;
  d[0] = f2b(v.x); d[1] = f2b(v.y); d[2] = f2b(v.z); d[3] = f2b(v.w);
}

// W[k][N] (fp32) -> Wt[n][512] bf16  (K fixed = 512)
__global__ __launch_bounds__(256) void k_wt(const float* __restrict__ W,
                                            u16* __restrict__ Wt, int N) {
  int e = blockIdx.x * 256 + threadIdx.x;  // e < N*512
  int nn = e >> 9, kk = e & 511;
  Wt[e] = f2b(W[(long)kk * N + nn]);
}

// ---------------- 128x128 bf16 NT GEMM (BK=64, global_load_lds, swizzled) ----
// C = A[M,K] @ B[N,K]^T ; K = 512
// MODE 0: q-proj (scale 0.125 -> q[b,h,n,dh]) M=32768 N=512
// MODE 1: kv-proj (k[b,h,nz,dh]; vt[b,h,dh,nz]) M=16384 N=1024
// MODE 2: out-proj (+x + bias, fp32 out)        M=32768 N=512
template <int MODE>
__global__ __launch_bounds__(256, 2) void k_gemm128(
    const u16* __restrict__ A, const u16* __restrict__ Bm, void* __restrict__ C0,
    void* __restrict__ C1, const float* __restrict__ xres,
    const float* __restrict__ bias, int K) {
  // bijective XCD-chunked swizzle
  const int nwg = gridDim.x * gridDim.y;
  const int orig = blockIdx.y * gridDim.x + blockIdx.x;
  const int qq = nwg >> 3, rr = nwg & 7;
  const int xcd = orig & 7, loc = orig >> 3;
  const int swz = (xcd < rr ? xcd * (qq + 1) : rr * (qq + 1) + (xcd - rr) * qq) + loc;
  const int m0 = (swz / gridDim.x) << 7, n0 = (swz % gridDim.x) << 7;
  const int t = threadIdx.x, lane = t & 63, w = t >> 6;
  const int wm = (w >> 1) << 6, wn = (w & 1) << 6;
  const int fr = lane & 15, g = lane >> 4;
  __shared__ u16 As[8192];  // [128 rows][64 k] bf16, 128B rows, XOR-swizzled
  __shared__ u16 Bs[8192];
  f32x4 acc[4][4] = {};
  const int srow = t >> 3, scs = t & 7;  // staging: this thread's seg (issue i adds 32 rows)
  for (int k0 = 0; k0 < K; k0 += 64) {
    __syncthreads();  // previous tile's readers done
#pragma unroll
    for (int i = 0; i < 4; ++i) {
      int row = srow + (i << 5), cs = scs;
      GLL(A + (long)(m0 + row) * K + k0 + ((cs ^ (row & 7)) << 3),
          &As[(i << 11) + (w << 9)]);
      GLL(Bm + (long)(n0 + row) * K + k0 + ((cs ^ (row & 7)) << 3),
          &Bs[(i << 11) + (w << 9)]);
    }
    __syncthreads();  // vmcnt(0) drained by compiler before barrier
#pragma unroll
    for (int ks = 0; ks < 2; ++ks) {
      bf16x8s af[4], bf[4];
#pragma unroll
      for (int fi = 0; fi < 4; ++fi) {
        int row = wm + fi * 16 + fr;
        af[fi] = *(const bf16x8s*)((const char*)As + row * 128 +
                                   (((ks * 4 + g) ^ (row & 7)) << 4));
      }
#pragma unroll
      for (int fj = 0; fj < 4; ++fj) {
        int row = wn + fj * 16 + fr;
        bf[fj] = *(const bf16x8s*)((const char*)Bs + row * 128 +
                                   (((ks * 4 + g) ^ (row & 7)) << 4));
      }
#pragma unroll
      for (int fi = 0; fi < 4; ++fi)
#pragma unroll
        for (int fj = 0; fj < 4; ++fj)
          acc[fi][fj] =
              __builtin_amdgcn_mfma_f32_16x16x32_bf16(af[fi], bf[fj], acc[fi][fj], 0, 0, 0);
    }
  }
  const int crow = g << 2;
#pragma unroll
  for (int fi = 0; fi < 4; ++fi)
#pragma unroll
    for (int fj = 0; fj < 4; ++fj)
#pragma unroll
      for (int r = 0; r < 4; ++r) {
        int row = m0 + wm + fi * 16 + crow + r;
        int col = n0 + wn + fj * 16 + fr;
        float v = acc[fi][fj][r];
        if (MODE == 0) {
          int b = row >> 13, n = row & 8191, h = col >> 6, dh = col & 63;
          ((u16*)C0)[((((long)(b * 8 + h)) << 13) + n) * 64 + dh] = f2b(v * 0.125f);
        } else if (MODE == 1) {
          int b = row >> 12, nz = row & 4095;
          if (col < 512) {
            int h = col >> 6, dh = col & 63;
            ((u16*)C0)[((((long)(b * 8 + h)) << 12) + nz) * 64 + dh] = f2b(v);
          } else {
            int c2 = col - 512, h = c2 >> 6, dh = c2 & 63;
            ((u16*)C1)[((((long)(b * 8 + h) * 64 + dh)) << 12) + nz] = f2b(v);
          }
        } else if (MODE == 2) {
          long idx = ((long)row << 9) + col;
          ((float*)C0)[idx] = v + xres[idx] + bias[col];
        }
      }
}

// ---------------- flash T1: T1 = softmax(q_land @ k^T) @ v  (per bh) --------
// writes T1^T split bf16: [bh][64 dh][256 m] hi / lo
__global__ __launch_bounds__(256, 2) void k_flashT1(
    const u16* __restrict__ qlb, const u16* __restrict__ kb,
    const u16* __restrict__ vtb, u16* __restrict__ T1thi,
    u16* __restrict__ T1tlo) {
  // 128 blocks; map so 16 consecutive logical blocks (4 bh) share an XCD
  int bid = blockIdx.x;
  int logical = (bid & 7) * 16 + (bid >> 3);
  int bh = logical >> 2, rb = logical & 3;
  const int t = threadIdx.x, lane = t & 63, w = t >> 6;
  const int fr = lane & 15, g = lane >> 4;
  __shared__ char lds[69632];  // K [0,32K) ; V^T [32K,64K) ; P [64K,68K)
  const u16* qrow = qlb + ((long)bh * 256 + rb * 64 + w * 16 + fr) * 64;
  bf16x8s qa0 = *(const bf16x8s*)(qrow + g * 8);
  bf16x8s qa1 = *(const bf16x8s*)(qrow + 32 + g * 8);
  f32x4 o[4] = {};
  float m[4] = {-3e38f, -3e38f, -3e38f, -3e38f};
  float l[4] = {};
  const long kbase = (long)bh * 262144;
  for (int c0 = 0; c0 < 4096; c0 += 256) {
    __syncthreads();  // previous chunk fully consumed
    // stage K chunk [256 keys][64 dh] (128B rows, swizzled)
#pragma unroll
    for (int i = 0; i < 8; ++i) {
      int seg = (i << 8) + t, row = seg >> 3, cs = seg & 7;
      GLL(kb + kbase + (long)(c0 + row) * 64 + ((cs ^ (row & 7)) << 3),
          lds + (i << 12) + (w << 10));
    }
    // stage V^T chunk [64 dh][256 keys] (512B rows, low-3-bit swizzle)
#pragma unroll
    for (int i = 0; i < 8; ++i) {
      int seg = (i << 8) + t, row = seg >> 5, cs = seg & 31;
      GLL(vtb + kbase + (long)row * 4096 + c0 + ((cs ^ (row & 7)) << 3),
          lds + 32768 + (i << 12) + (w << 10));
    }
    __syncthreads();
    // QK^T: S[16 rows][256 keys] per wave
    f32x4 s[16];
#pragma unroll
    for (int c = 0; c < 16; ++c) {
      int j = c * 16 + fr;
      bf16x8s b0 = *(const bf16x8s*)(lds + j * 128 + ((g ^ (j & 7)) << 4));
      bf16x8s b1 = *(const bf16x8s*)(lds + j * 128 + (((4 + g) ^ (j & 7)) << 4));
      f32x4 zz = {};
      zz = __builtin_amdgcn_mfma_f32_16x16x32_bf16(qa0, b0, zz, 0, 0, 0);
      zz = __builtin_amdgcn_mfma_f32_16x16x32_bf16(qa1, b1, zz, 0, 0, 0);
      s[c] = zz;
    }
    // online softmax update
    float sc[4];
#pragma unroll
    for (int r = 0; r < 4; ++r) {
      float pm = s[0][r];
#pragma unroll
      for (int c = 1; c < 16; ++c) pm = fmaxf(pm, s[c][r]);
      pm = fmaxf(pm, __shfl_xor(pm, 1, 64));
      pm = fmaxf(pm, __shfl_xor(pm, 2, 64));
      pm = fmaxf(pm, __shfl_xor(pm, 4, 64));
      pm = fmaxf(pm, __shfl_xor(pm, 8, 64));
      float mn = fmaxf(m[r], pm);
      sc[r] = __expf(m[r] - mn);
      m[r] = mn;
    }
#pragma unroll
    for (int r = 0; r < 4; ++r) {
      float su = 0.f;
#pragma unroll
      for (int c = 0; c < 16; ++c) {
        float e = __expf(s[c][r] - m[r]);
        s[c][r] = e;
        su += e;
      }
      su += __shfl_xor(su, 1, 64);
      su += __shfl_xor(su, 2, 64);
      su += __shfl_xor(su, 4, 64);
      su += __shfl_xor(su, 8, 64);
      l[r] = l[r] * sc[r] + su;
    }
#pragma unroll
    for (int d = 0; d < 4; ++d)
#pragma unroll
      for (int r = 0; r < 4; ++r) o[d][r] *= sc[r];
    // PV: 8 key-slices of 32, per-wave P staging
    char* plw = lds + 65536 + (w << 10);
#pragma unroll
    for (int ss = 0; ss < 8; ++ss) {
#pragma unroll
      for (int cc = 0; cc < 2; ++cc) {
        int c = ss * 2 + cc;
#pragma unroll
        for (int r = 0; r < 4; ++r) {
          int row = (g << 2) + r;
          int byte = (row << 6) + (((cc << 4) + fr) << 1);
          *(u16*)(plw + (byte ^ ((row & 7) << 4))) = f2b(s[c][r]);
        }
      }
      asm volatile("s_waitcnt lgkmcnt(0)" ::: "memory");
      __builtin_amdgcn_sched_barrier(0);
      int abyte = (fr << 6) + (g << 4);
      bf16x8s ap = *(const bf16x8s*)(plw + (abyte ^ ((fr & 7) << 4)));
#pragma unroll
      for (int d = 0; d < 4; ++d) {
        int dh = (d << 4) + fr;
        bf16x8s bv = *(const bf16x8s*)(lds + 32768 + dh * 512 +
                                       (((ss * 4 + g) ^ (dh & 7)) << 4));
        o[d] = __builtin_amdgcn_mfma_f32_16x16x32_bf16(ap, bv, o[d], 0, 0, 0);
      }
      asm volatile("s_waitcnt lgkmcnt(0)" ::: "memory");
      __builtin_amdgcn_sched_barrier(0);
    }
  }
  long base = (long)bh * 16384;
#pragma unroll
  for (int d = 0; d < 4; ++d)
#pragma unroll
    for (int r = 0; r < 4; ++r) {
      int mrow = rb * 64 + w * 16 + (g << 2) + r;
      int dh = (d << 4) + fr;
      float v = o[d][r] / l[r];
      u16 h = f2b(v);
      T1thi[base + dh * 256 + mrow] = h;
      T1tlo[base + dh * 256 + mrow] = f2b(v - b2f(h));
    }
}

// ---------------- split-bf16 MFMA NN GEMM (pinv chain) ----------------
__global__ __launch_bounds__(256) void k_nn_mfma(
    const u16* __restrict__ Ahi, const u16* __restrict__ Alo,
    const u16* __restrict__ Bthi, const u16* __restrict__ Btlo,
    u16* __restrict__ CNhi, u16* __restrict__ CNlo,
    u16* __restrict__ CThi, u16* __restrict__ CTlo,
    int Nc, float sab, float sa, float cdiag) {
  const int bz = blockIdx.z;
  const long offA = (long)bz << 16;
  const long offB = (long)bz * ((long)Nc << 8);
  const int m0 = blockIdx.y << 6, n0 = blockIdx.x << 6;
  const int t = threadIdx.x, lane = t & 63, w = t >> 6;
  const int wm = (w >> 1) << 5, wn = (w & 1) << 5;
  const int fr = lane & 15, fk = (lane >> 4) << 3;
  __shared__ char lds[32768];
  f32x4 acc[2][2] = {};
  const int sr = t >> 2, sc = (t & 3) << 4;
  const int wby = sr * 128 + sc * 2;
  const int wsw = (sr & 7) << 4;
  const int frsw = (fr & 7) << 4;
  for (int k0 = 0; k0 < 256; k0 += 64) {
    const long ab = offA + (long)(m0 + sr) * 256 + k0 + sc;
    const long bb = offB + (long)(n0 + sr) * 256 + k0 + sc;
    bf16x8s ah0 = *(const bf16x8s*)(Ahi + ab);
    bf16x8s ah1 = *(const bf16x8s*)(Ahi + ab + 8);
    bf16x8s al0 = *(const bf16x8s*)(Alo + ab);
    bf16x8s al1 = *(const bf16x8s*)(Alo + ab + 8);
    bf16x8s bh0 = *(const bf16x8s*)(Bthi + bb);
    bf16x8s bh1 = *(const bf16x8s*)(Bthi + bb + 8);
    bf16x8s bl0 = *(const bf16x8s*)(Btlo + bb);
    bf16x8s bl1 = *(const bf16x8s*)(Btlo + bb + 8);
    __syncthreads();
    *(bf16x8s*)(lds + (wby ^ wsw)) = ah0;
    *(bf16x8s*)(lds + ((wby + 16) ^ wsw)) = ah1;
    *(bf16x8s*)(lds + 8192 + (wby ^ wsw)) = al0;
    *(bf16x8s*)(lds + 8192 + ((wby + 16) ^ wsw)) = al1;
    *(bf16x8s*)(lds + 16384 + (wby ^ wsw)) = bh0;
    *(bf16x8s*)(lds + 16384 + ((wby + 16) ^ wsw)) = bh1;
    *(bf16x8s*)(lds + 24576 + (wby ^ wsw)) = bl0;
    *(bf16x8s*)(lds + 24576 + ((wby + 16) ^ wsw)) = bl1;
    __syncthreads();
#pragma unroll
    for (int ks = 0; ks < 64; ks += 32) {
      const int kb = (ks + fk) << 1;
      const int ra0 = (wm + fr) * 128 + kb, ra1 = (wm + 16 + fr) * 128 + kb;
      const int rb0 = (wn + fr) * 128 + kb, rb1 = (wn + 16 + fr) * 128 + kb;
      bf16x8s fah0 = *(const bf16x8s*)(lds + (ra0 ^ frsw));
      bf16x8s fah1 = *(const bf16x8s*)(lds + (ra1 ^ frsw));
      bf16x8s fal0 = *(const bf16x8s*)(lds + 8192 + (ra0 ^ frsw));
      bf16x8s fal1 = *(const bf16x8s*)(lds + 8192 + (ra1 ^ frsw));
      bf16x8s fbh0 = *(const bf16x8s*)(lds + 16384 + (rb0 ^ frsw));
      bf16x8s fbh1 = *(const bf16x8s*)(lds + 16384 + (rb1 ^ frsw));
      bf16x8s fbl0 = *(const bf16x8s*)(lds + 24576 + (rb0 ^ frsw));
      bf16x8s fbl1 = *(const bf16x8s*)(lds + 24576 + (rb1 ^ frsw));
      acc[0][0] = __builtin_amdgcn_mfma_f32_16x16x32_bf16(fah0, fbh0, acc[0][0], 0, 0, 0);
      acc[0][0] = __builtin_amdgcn_mfma_f32_16x16x32_bf16(fah0, fbl0, acc[0][0], 0, 0, 0);
      acc[0][0] = __builtin_amdgcn_mfma_f32_16x16x32_bf16(fal0, fbh0, acc[0][0], 0, 0, 0);
      acc[0][1] = __builtin_amdgcn_mfma_f32_16x16x32_bf16(fah0, fbh1, acc[0][1], 0, 0, 0);
      acc[0][1] = __builtin_amdgcn_mfma_f32_16x16x32_bf16(fah0, fbl1, acc[0][1], 0, 0, 0);
      acc[0][1] = __builtin_amdgcn_mfma_f32_16x16x32_bf16(fal0, fbh1, acc[0][1], 0, 0, 0);
      acc[1][0] = __builtin_amdgcn_mfma_f32_16x16x32_bf16(fah1, fbh0, acc[1][0], 0, 0, 0);
      acc[1][0] = __builtin_amdgcn_mfma_f32_16x16x32_bf16(fah1, fbl0, acc[1][0], 0, 0, 0);
      acc[1][0] = __builtin_amdgcn_mfma_f32_16x16x32_bf16(fal1, fbh0, acc[1][0], 0, 0, 0);
      acc[1][1] = __builtin_amdgcn_mfma_f32_16x16x32_bf16(fah1, fbh1, acc[1][1], 0, 0, 0);
      acc[1][1] = __builtin_amdgcn_mfma_f32_16x16x32_bf16(fah1, fbl1, acc[1][1], 0, 0, 0);
      acc[1][1] = __builtin_amdgcn_mfma_f32_16x16x32_bf16(fal1, fbh1, acc[1][1], 0, 0, 0);
    }
  }
  const int crow = (lane >> 4) << 2;
  const long offC = (long)bz * ((long)Nc << 8);
#pragma unroll
  for (int i = 0; i < 2; ++i)
#pragma unroll
    for (int j = 0; j < 2; ++j)
#pragma unroll
      for (int r = 0; r < 4; ++r) {
        int row = m0 + wm + i * 16 + crow + r;
        int col = n0 + wn + j * 16 + fr;
        float v = sab * acc[i][j][r];
        if (sa != 0.f) {
          long ai = offA + ((long)row << 8) + col;
          v += sa * (b2f(Ahi[ai]) + b2f(Alo[ai]));
        }
        if (row == col) v += cdiag;
        if (CNhi) {
          long ci = offC + (long)row * Nc + col;
          u16 h = f2b(v);
          if (CNlo) { CNhi[ci] = h; CNlo[ci] = f2b(v - b2f(h)); }
          else CNhi[ci] = h;
        }
        if (CThi) {
          long ti = offC + ((long)col << 8) + row;
          u16 h = f2b(v);
          CThi[ti] = h;
          CTlo[ti] = f2b(v - b2f(h));
        }
      }
}

// ---------------- landmarks ----------------
__global__ __launch_bounds__(256) void k_landmark(const u16* __restrict__ src,
                                                  float* __restrict__ df,
                                                  u16* __restrict__ db, int ntok,
                                                  int l, float inv) {
  int pidx = blockIdx.x * 4 + (threadIdx.x >> 6);
  int d = threadIdx.x & 63;
  int bh = pidx >> 8, m = pidx & 255;
  const u16* s = src + ((long)bh * ntok + (long)m * l) * 64 + d;
  float sum = 0.f;
  for (int j = 0; j < l; ++j) sum += b2f(s[j * 64]);
  sum *= inv;
  long o = ((long)bh * 256 + m) * 64 + d;
  df[o] = sum;
  db[o] = f2b(sum);
}

// ---------------- sim2 + softmax (fp32) ----------------
__global__ __launch_bounds__(256) void k_sim2_softmax(const float* __restrict__ qlf,
                                                      const float* __restrict__ klf,
                                                      float* __restrict__ attn2) {
  int m = blockIdx.x, bh = blockIdx.y;
  int j = threadIdx.x, lane = j & 63, w = j >> 6;
  const float* qr = qlf + ((long)bh * 256 + m) * 64;
  const float* kr = klf + ((long)bh * 256 + j) * 64;
  float s = 0.f;
#pragma unroll
  for (int d = 0; d < 64; ++d) s += qr[d] * kr[d];
  float mx = s;
  for (int o = 1; o < 64; o <<= 1) mx = fmaxf(mx, __shfl_xor(mx, o, 64));
  __shared__ float r1[4], r2[4];
  if (lane == 0) r1[w] = mx;
  __syncthreads();
  mx = fmaxf(fmaxf(r1[0], r1[1]), fmaxf(r1[2], r1[3]));
  float e = __expf(s - mx);
  float su = e;
  for (int o = 1; o < 64; o <<= 1) su += __shfl_xor(su, o, 64);
  if (lane == 0) r2[w] = su;
  __syncthreads();
  su = r2[0] + r2[1] + r2[2] + r2[3];
  attn2[(((long)bh * 256 + m) << 8) + j] = e / su;
}

__global__ __launch_bounds__(256) void k_colmax(const float* __restrict__ attn2,
                                                unsigned* __restrict__ cmax) {
  int bh = blockIdx.x, j = threadIdx.x, lane = j & 63, w = j >> 6;
  const float* p = attn2 + ((long)bh << 16) + j;
  float s = 0.f;
  for (int m = 0; m < 256; ++m) s += p[m * 256];
  float mx = s;
  for (int o = 1; o < 64; o <<= 1) mx = fmaxf(mx, __shfl_xor(mx, o, 64));
  __shared__ float r1[4];
  if (lane == 0) r1[w] = mx;
  __syncthreads();
  if (j == 0) {
    mx = fmaxf(fmaxf(r1[0], r1[1]), fmaxf(r1[2], r1[3]));
    atomicMax(cmax, __float_as_uint(mx));
  }
}

// ---------------- pinv operand prep ----------------
__global__ __launch_bounds__(256) void k_prep_pinv(
    const float* __restrict__ attn2, const unsigned* __restrict__ cmax,
    u16* __restrict__ aNhi, u16* __restrict__ aNlo,
    u16* __restrict__ zNhi, u16* __restrict__ zNlo,
    u16* __restrict__ zThi, u16* __restrict__ zTlo) {
  const int bz = blockIdx.z, i0 = blockIdx.y << 6, j0 = blockIdx.x << 6;
  const float s = 1.f / __uint_as_float(*cmax);
  const float* base = attn2 + ((long)bz << 16);
  __shared__ float mt[64][65];
  const int r = threadIdx.x >> 2, cb = (threadIdx.x & 3) << 4;
#pragma unroll
  for (int c4 = 0; c4 < 16; c4 += 4) {
    float4 v = *(const float4*)&base[(long)(j0 + r) * 256 + i0 + cb + c4];
    mt[r][cb + c4] = v.x; mt[r][cb + c4 + 1] = v.y;
    mt[r][cb + c4 + 2] = v.z; mt[r][cb + c4 + 3] = v.w;
  }
  __syncthreads();
  const int i = i0 + r;
#pragma unroll
  for (int c4 = 0; c4 < 16; c4 += 4) {
    float4 v = *(const float4*)&base[(long)i * 256 + j0 + cb + c4];
    float vv[4] = {v.x, v.y, v.z, v.w};
#pragma unroll
    for (int e = 0; e < 4; ++e) {
      int j = j0 + cb + c4 + e;
      long idx = ((long)bz << 16) + ((long)i << 8) + j;
      float a = vv[e];
      u16 h = f2b(a);
      aNhi[idx] = h; aNlo[idx] = f2b(a - b2f(h));
      float zt = a * s;
      u16 zh = f2b(zt);
      zThi[idx] = zh; zTlo[idx] = f2b(zt - b2f(zh));
      float zn = mt[cb + c4 + e][r] * s;
      u16 nh = f2b(zn);
      zNhi[idx] = nh; zNlo[idx] = f2b(zn - b2f(nh));
    }
  }
}

// ---------------- fused sim1: O = softmax(q @ k_land^T) @ T2 ----------------
__global__ __launch_bounds__(256) void k_fused_attn1(const u16* __restrict__ q,
                                                     const u16* __restrict__ klb,
                                                     const u16* __restrict__ t2b,
                                                     u16* __restrict__ O) {
  const int bh = blockIdx.y, n0 = blockIdx.x << 6;
  const int bb = bh >> 3, hh = bh & 7;
  const int t = threadIdx.x, lane = t & 63, w = t >> 6;
  const int fr = lane & 15, g = lane >> 4, fk = g << 3;
  __shared__ char lds[65536];
  {
    const u16* src = klb + (long)bh * 16384;
#pragma unroll
    for (int i = 0; i < 8; ++i) {
      int c = t + (i << 8);
      int byte = c << 4;
      int sw = byte ^ (((byte >> 7) & 7) << 4);
      *(bf16x8s*)(lds + sw) = *(const bf16x8s*)(src + (c << 3));
    }
    const u16* src2 = t2b + (long)bh * 16384;
#pragma unroll
    for (int i = 0; i < 64; ++i) {
      int e = t + (i << 8);
      int k = e >> 6, dh = e & 63;
      int byte = (dh << 9) + (k << 1);
      int sw = byte ^ ((dh & 7) << 4);
      *(u16*)(lds + 32768 + sw) = src2[e];
    }
  }
  __syncthreads();

  const u16* qrow = q + ((long)bh * 8192 + n0 + (w << 4) + fr) * 64;
  bf16x8s a0 = *(const bf16x8s*)(qrow + fk);
  bf16x8s a1 = *(const bf16x8s*)(qrow + 32 + fk);

  f32x4 s[16];
#pragma unroll
  for (int c = 0; c < 16; ++c) {
    int j = (c << 4) + fr;
    int base = (j << 7) + (fk << 1);
    int swm = (j & 7) << 4;
    bf16x8s b0 = *(const bf16x8s*)(lds + (base ^ swm));
    bf16x8s b1 = *(const bf16x8s*)(lds + ((base + 64) ^ swm));
    f32x4 zz = {};
    zz = __builtin_amdgcn_mfma_f32_16x16x32_bf16(a0, b0, zz, 0, 0, 0);
    zz = __builtin_amdgcn_mfma_f32_16x16x32_bf16(a1, b1, zz, 0, 0, 0);
    s[c] = zz;
  }
  float mr[4], li[4];
#pragma unroll
  for (int r = 0; r < 4; ++r) {
    float m = s[0][r];
#pragma unroll
    for (int c = 1; c < 16; ++c) m = fmaxf(m, s[c][r]);
    m = fmaxf(m, __shfl_xor(m, 1, 64));
    m = fmaxf(m, __shfl_xor(m, 2, 64));
    m = fmaxf(m, __shfl_xor(m, 4, 64));
    m = fmaxf(m, __shfl_xor(m, 8, 64));
    mr[r] = m;
  }
#pragma unroll
  for (int r = 0; r < 4; ++r) {
    float l = 0.f;
#pragma unroll
    for (int c = 0; c < 16; ++c) {
      float e = __expf(s[c][r] - mr[r]);
      s[c][r] = e;
      l += e;
    }
    l += __shfl_xor(l, 1, 64);
    l += __shfl_xor(l, 2, 64);
    l += __shfl_xor(l, 4, 64);
    l += __shfl_xor(l, 8, 64);
    li[r] = 1.f / l;
  }
  __syncthreads();

  char* plw = lds + (w << 10);
  f32x4 o4[4] = {};
#pragma unroll
  for (int pair = 0; pair < 8; ++pair) {
#pragma unroll
    for (int cc = 0; cc < 2; ++cc) {
      int c = (pair << 1) + cc;
#pragma unroll
      for (int r = 0; r < 4; ++r) {
        int row = (g << 2) + r;
        int byte = (row << 6) + (((cc << 4) + fr) << 1);
        int sw = byte ^ ((row & 7) << 4);
        *(u16*)(plw + sw) = f2b(s[c][r] * li[r]);
      }
    }
    asm volatile("s_waitcnt lgkmcnt(0)" ::: "memory");
    __builtin_amdgcn_sched_barrier(0);
    int abyte = (fr << 6) + (fk << 1);
    bf16x8s ap = *(const bf16x8s*)(plw + (abyte ^ ((fr & 7) << 4)));
#pragma unroll
    for (int d = 0; d < 4; ++d) {
      int dh = (d << 4) + fr;
      int tb = (dh << 9) + (((pair << 5) + fk) << 1);
      bf16x8s bv = *(const bf16x8s*)(lds + 32768 + (tb ^ ((dh & 7) << 4)));
      o4[d] = __builtin_amdgcn_mfma_f32_16x16x32_bf16(ap, bv, o4[d], 0, 0, 0);
    }
    asm volatile("s_waitcnt lgkmcnt(0)" ::: "memory");
    __builtin_amdgcn_sched_barrier(0);
  }
  u16* ob = O + (((long)bb * 8192 + n0 + (w << 4)) << 9) + (hh << 6);
#pragma unroll
  for (int d = 0; d < 4; ++d)
#pragma unroll
    for (int r = 0; r < 4; ++r) {
      int row = (g << 2) + r;
      int col = (d << 4) + fr;
      ob[((long)row << 9) + col] = f2b(o4[d][r]);
    }
}

// ---------------- host ----------------
extern "C" void kernel_launch(void* const* d_in, const int* in_sizes, int n_in,
                              void* d_out, int out_size, void* d_ws, size_t ws_size,
                              hipStream_t stream) {
  const float* x = (const float*)d_in[0];
  const float* z = (const float*)d_in[1];
  const float* Wq = (const float*)d_in[2];
  const float* Wkv = (const float*)d_in[3];
  const float* Wo = (const float*)d_in[4];
  const float* bo = (const float*)d_in[5];
  float* out = (float*)d_out;

  char* base = (char*)d_ws;
  size_t off = 0;
  auto alloc = [&](size_t bytes) -> void* {
    void* r = base + off;
    off = (off + bytes + 255) & ~(size_t)255;
    return r;
  };
  u16* qb = (u16*)alloc(33554432);
  u16* kb = (u16*)alloc(16777216);
  u16* vtb = (u16*)alloc(16777216);
  u16* PS = (u16*)alloc(67108864);    // pinv state (16 x 4MB)
  float* attn2 = (float*)alloc(8388608);
  u16* xb = (u16*)alloc(33554432);    // dead after qproj -> Ob
  u16* zb = (u16*)alloc(16777216);    // dead after kvproj -> attn2 split
  u16* wqt = (u16*)alloc(524288);
  u16* wkvt = (u16*)alloc(1048576);
  u16* wot = (u16*)alloc(524288);
  float* qlf = (float*)alloc(2097152);
  u16* qlb = (u16*)alloc(1048576);
  float* klf = (float*)alloc(2097152);
  u16* klb = (u16*)alloc(1048576);
  u16* T1t = (u16*)alloc(2097152);
  u16* T2b = (u16*)alloc(1048576);
  unsigned* cmax = (unsigned*)alloc(256);
  const long MC = 2097152;
  u16* P = PS;
  u16 *ztA_Nhi = P,          *ztA_Nlo = P + MC,      *ztA_Thi = P + 2 * MC,  *ztA_Tlo = P + 3 * MC;
  u16 *ztB_Nhi = P + 4 * MC,  *ztB_Nlo = P + 5 * MC,  *ztB_Thi = P + 6 * MC,  *ztB_Tlo = P + 7 * MC;
  u16 *az_Nhi = P + 8 * MC,   *az_Nlo = P + 9 * MC,   *az_Thi = P + 10 * MC,  *az_Tlo = P + 11 * MC;
  u16 *taThi = P + 12 * MC,   *taTlo = P + 13 * MC;
  u16 *tcThi = P + 14 * MC,   *tcTlo = P + 15 * MC;
  u16 *aNhi = zb, *aNlo = zb + MC;
  u16* T1thi = T1t;
  u16* T1tlo = T1t + 524288;
  u16* Ob = xb;

  hipMemsetAsync(cmax, 0, 4, stream);
  k_f2b<<<16384, 256, 0, stream>>>(x, xb, 4194304);
  k_f2b<<<8192, 256, 0, stream>>>(z, zb, 2097152);
  k_wt<<<1024, 256, 0, stream>>>(Wq, wqt, 512);
  k_wt<<<2048, 256, 0, stream>>>(Wkv, wkvt, 1024);
  k_wt<<<1024, 256, 0, stream>>>(Wo, wot, 512);

  k_gemm128<0><<<dim3(4, 256), 256, 0, stream>>>(xb, wqt, qb, nullptr, nullptr,
                                                 nullptr, 512);
  k_gemm128<1><<<dim3(8, 128), 256, 0, stream>>>(zb, wkvt, kb, vtb, nullptr,
                                                 nullptr, 512);
  k_landmark<<<2048, 256, 0, stream>>>(qb, qlf, qlb, 8192, 32, 1.f / 32.f);
  k_landmark<<<2048, 256, 0, stream>>>(kb, klf, klb, 4096, 16, 1.f / 16.f);
  k_sim2_softmax<<<dim3(256, 32), 256, 0, stream>>>(qlf, klf, attn2);
  k_colmax<<<32, 256, 0, stream>>>(attn2, cmax);

  // fused sim3 -> softmax -> T1 (flash)
  k_flashT1<<<128, 256, 0, stream>>>(qlb, kb, vtb, T1thi, T1tlo);

  // pinv prep (aN into dead zb; zt state into PS)
  k_prep_pinv<<<dim3(4, 4, 32), 256, 0, stream>>>(attn2, cmax, aNhi, aNlo,
                                                  ztA_Nhi, ztA_Nlo, ztA_Thi, ztA_Tlo);

  dim3 g256(4, 4, 32);
  u16 *cN0 = ztA_Nhi, *cN1 = ztA_Nlo, *cT0 = ztA_Thi, *cT1 = ztA_Tlo;
  u16 *nN0 = ztB_Nhi, *nN1 = ztB_Nlo, *nT0 = ztB_Thi, *nT1 = ztB_Tlo;
  for (int it = 0; it < 6; ++it) {
    bool last = (it == 5);
    k_nn_mfma<<<g256, 256, 0, stream>>>(aNhi, aNlo, cT0, cT1, az_Nhi, az_Nlo,
                                        az_Thi, az_Tlo, 256, 1.f, 0.f, 0.f);
    k_nn_mfma<<<g256, 256, 0, stream>>>(az_Nhi, az_Nlo, az_Thi, az_Tlo, nullptr,
                                        nullptr, taThi, taTlo, 256, 1.f, -7.f, 15.f);
    k_nn_mfma<<<g256, 256, 0, stream>>>(az_Nhi, az_Nlo, taThi, taTlo, nullptr,
                                        nullptr, tcThi, tcTlo, 256, -1.f, 0.f, 13.f);
    k_nn_mfma<<<g256, 256, 0, stream>>>(cN0, cN1, tcThi, tcTlo, nN0, nN1,
                                        last ? nullptr : nT0, last ? nullptr : nT1,
                                        256, 0.25f, 0.f, 0.f);
    u16* t0;
    t0 = cN0; cN0 = nN0; nN0 = t0;  t0 = cN1; cN1 = nN1; nN1 = t0;
    t0 = cT0; cT0 = nT0; nT0 = t0;  t0 = cT1; cT1 = nT1; nT1 = t0;
  }
  k_nn_mfma<<<dim3(1, 4, 32), 256, 0, stream>>>(cN0, cN1, T1thi, T1tlo, T2b,
                                                nullptr, nullptr, nullptr, 64,
                                                1.f, 0.f, 0.f);

  k_fused_attn1<<<dim3(128, 32), 256, 0, stream>>>(qb, klb, T2b, Ob);
  k_gemm128<2><<<dim3(4, 256), 256, 0, stream>>>(Ob, wot, out, nullptr, x, bo, 512);
}

// Round 5
// 788.174 us; speedup vs baseline: 1.2582x; 1.0177x over previous
//
#include <hip/hip_runtime.h>

typedef unsigned short u16;
typedef __attribute__((ext_vector_type(8))) short bf16x8s;
typedef __attribute__((ext_vector_type(4))) float f32x4;

#define DEV static __device__ __forceinline__

DEV float b2f(u16 v) { return __uint_as_float(((unsigned)v) << 16); }
DEV u16 f2b(float f) {
  unsigned u = __float_as_uint(f);
  unsigned r = (u + 0x7fffu + ((u >> 16) & 1u)) >> 16;
  return (u16)r;
}

// async global->LDS, 16B per lane; lds base must be wave-uniform (HW adds lane*16)
#define GLL(gp, lp)                                                            \
  __builtin_amdgcn_global_load_lds(                                            \
      (const __attribute__((address_space(1))) unsigned int*)(gp),             \
      (__attribute__((address_space(3))) unsigned int*)(lp), 16, 0, 0)

#define MFMA __builtin_amdgcn_mfma_f32_16x16x32_bf16

// ---------------- elementwise converts ----------------
__global__ __launch_bounds__(256) void k_f2b(const float* __restrict__ in,
                                             u16* __restrict__ o, long n4) {
  long i = (long)blockIdx.x * 256 + threadIdx.x;
  if (i >= n4) return;
  float4 v = *(const float4*)(in + i * 4);
  u16* d = o + i * 4;
  d[0] = f2b(v.x); d[1] = f2b(v.y); d[2] = f2b(v.z); d[3] = f2b(v.w);
}

// W[k][N] (fp32) -> Wt[n][512] bf16  (K fixed = 512)
__global__ __launch_bounds__(256) void k_wt(const float* __restrict__ W,
                                            u16* __restrict__ Wt, int N) {
  int e = blockIdx.x * 256 + threadIdx.x;  // e < N*512
  int nn = e >> 9, kk = e & 511;
  Wt[e] = f2b(W[(long)kk * N + nn]);
}

// ---------------- 128x128 bf16 NT GEMM (BK=64, global_load_lds, swizzled) ----
template <int MODE>
__global__ __launch_bounds__(256, 2) void k_gemm128(
    const u16* __restrict__ A, const u16* __restrict__ Bm, void* __restrict__ C0,
    void* __restrict__ C1, const float* __restrict__ xres,
    const float* __restrict__ bias, int K) {
  const int nwg = gridDim.x * gridDim.y;
  const int orig = blockIdx.y * gridDim.x + blockIdx.x;
  const int qq = nwg >> 3, rr = nwg & 7;
  const int xcd = orig & 7, loc = orig >> 3;
  const int swz = (xcd < rr ? xcd * (qq + 1) : rr * (qq + 1) + (xcd - rr) * qq) + loc;
  const int m0 = (swz / gridDim.x) << 7, n0 = (swz % gridDim.x) << 7;
  const int t = threadIdx.x, lane = t & 63, w = t >> 6;
  const int wm = (w >> 1) << 6, wn = (w & 1) << 6;
  const int fr = lane & 15, g = lane >> 4;
  __shared__ u16 As[8192];
  __shared__ u16 Bs[8192];
  f32x4 acc[4][4] = {};
  const int srow = t >> 3, scs = t & 7;
  for (int k0 = 0; k0 < K; k0 += 64) {
    __syncthreads();
#pragma unroll
    for (int i = 0; i < 4; ++i) {
      int row = srow + (i << 5), cs = scs;
      GLL(A + (long)(m0 + row) * K + k0 + ((cs ^ (row & 7)) << 3),
          &As[(i << 11) + (w << 9)]);
      GLL(Bm + (long)(n0 + row) * K + k0 + ((cs ^ (row & 7)) << 3),
          &Bs[(i << 11) + (w << 9)]);
    }
    __syncthreads();
#pragma unroll
    for (int ks = 0; ks < 2; ++ks) {
      bf16x8s af[4], bf[4];
#pragma unroll
      for (int fi = 0; fi < 4; ++fi) {
        int row = wm + fi * 16 + fr;
        af[fi] = *(const bf16x8s*)((const char*)As + row * 128 +
                                   (((ks * 4 + g) ^ (row & 7)) << 4));
      }
#pragma unroll
      for (int fj = 0; fj < 4; ++fj) {
        int row = wn + fj * 16 + fr;
        bf[fj] = *(const bf16x8s*)((const char*)Bs + row * 128 +
                                   (((ks * 4 + g) ^ (row & 7)) << 4));
      }
#pragma unroll
      for (int fi = 0; fi < 4; ++fi)
#pragma unroll
        for (int fj = 0; fj < 4; ++fj)
          acc[fi][fj] = MFMA(af[fi], bf[fj], acc[fi][fj], 0, 0, 0);
    }
  }
  const int crow = g << 2;
#pragma unroll
  for (int fi = 0; fi < 4; ++fi)
#pragma unroll
    for (int fj = 0; fj < 4; ++fj)
#pragma unroll
      for (int r = 0; r < 4; ++r) {
        int row = m0 + wm + fi * 16 + crow + r;
        int col = n0 + wn + fj * 16 + fr;
        float v = acc[fi][fj][r];
        if (MODE == 0) {
          int b = row >> 13, n = row & 8191, h = col >> 6, dh = col & 63;
          ((u16*)C0)[((((long)(b * 8 + h)) << 13) + n) * 64 + dh] = f2b(v * 0.125f);
        } else if (MODE == 1) {
          int b = row >> 12, nz = row & 4095;
          if (col < 512) {
            int h = col >> 6, dh = col & 63;
            ((u16*)C0)[((((long)(b * 8 + h)) << 12) + nz) * 64 + dh] = f2b(v);
          } else {
            int c2 = col - 512, h = c2 >> 6, dh = c2 & 63;
            ((u16*)C1)[((((long)(b * 8 + h) * 64 + dh)) << 12) + nz] = f2b(v);
          }
        } else if (MODE == 2) {
          long idx = ((long)row << 9) + col;
          ((float*)C0)[idx] = v + xres[idx] + bias[col];
        }
      }
}

// ---------------- flash T1: T1 = softmax(q_land @ k^T) @ v  (per bh) --------
// writes T1^T split bf16: [bh][64 dh][256 m] hi / lo
__global__ __launch_bounds__(256, 2) void k_flashT1(
    const u16* __restrict__ qlb, const u16* __restrict__ kb,
    const u16* __restrict__ vtb, u16* __restrict__ T1thi,
    u16* __restrict__ T1tlo) {
  int bid = blockIdx.x;
  int logical = (bid & 7) * 16 + (bid >> 3);
  int bh = logical >> 2, rb = logical & 3;
  const int t = threadIdx.x, lane = t & 63, w = t >> 6;
  const int fr = lane & 15, g = lane >> 4;
  __shared__ char lds[65536];  // [0,32K) K chunk (aliased by P after QK^T); [32K,64K) V^T
  const u16* qrow = qlb + ((long)bh * 256 + rb * 64 + w * 16 + fr) * 64;
  bf16x8s qa0 = *(const bf16x8s*)(qrow + g * 8);
  bf16x8s qa1 = *(const bf16x8s*)(qrow + 32 + g * 8);
  f32x4 o[4] = {};
  float m[4] = {-3e38f, -3e38f, -3e38f, -3e38f};
  float l[4] = {};
  const long kbase = (long)bh * 262144;
  for (int c0 = 0; c0 < 4096; c0 += 256) {
    __syncthreads();  // previous chunk's P and V fully consumed
#pragma unroll
    for (int i = 0; i < 8; ++i) {
      int seg = (i << 8) + t, row = seg >> 3, cs = seg & 7;
      GLL(kb + kbase + (long)(c0 + row) * 64 + ((cs ^ (row & 7)) << 3),
          lds + (i << 12) + (w << 10));
    }
#pragma unroll
    for (int i = 0; i < 8; ++i) {
      int seg = (i << 8) + t, row = seg >> 5, cs = seg & 31;
      GLL(vtb + kbase + (long)row * 4096 + c0 + ((cs ^ (row & 7)) << 3),
          lds + 32768 + (i << 12) + (w << 10));
    }
    __syncthreads();
    // QK^T
    f32x4 s[16];
#pragma unroll
    for (int c = 0; c < 16; ++c) {
      int j = c * 16 + fr;
      bf16x8s b0 = *(const bf16x8s*)(lds + j * 128 + ((g ^ (j & 7)) << 4));
      bf16x8s b1 = *(const bf16x8s*)(lds + j * 128 + (((4 + g) ^ (j & 7)) << 4));
      f32x4 zz = {};
      zz = MFMA(qa0, b0, zz, 0, 0, 0);
      zz = MFMA(qa1, b1, zz, 0, 0, 0);
      s[c] = zz;
    }
    // online softmax
    float sc[4];
#pragma unroll
    for (int r = 0; r < 4; ++r) {
      float pm = s[0][r];
#pragma unroll
      for (int c = 1; c < 16; ++c) pm = fmaxf(pm, s[c][r]);
      pm = fmaxf(pm, __shfl_xor(pm, 1, 64));
      pm = fmaxf(pm, __shfl_xor(pm, 2, 64));
      pm = fmaxf(pm, __shfl_xor(pm, 4, 64));
      pm = fmaxf(pm, __shfl_xor(pm, 8, 64));
      float mn = fmaxf(m[r], pm);
      sc[r] = __expf(m[r] - mn);
      m[r] = mn;
    }
#pragma unroll
    for (int r = 0; r < 4; ++r) {
      float su = 0.f;
#pragma unroll
      for (int c = 0; c < 16; ++c) {
        float e = __expf(s[c][r] - m[r]);
        s[c][r] = e;
        su += e;
      }
      su += __shfl_xor(su, 1, 64);
      su += __shfl_xor(su, 2, 64);
      su += __shfl_xor(su, 4, 64);
      su += __shfl_xor(su, 8, 64);
      l[r] = l[r] * sc[r] + su;
    }
#pragma unroll
    for (int d = 0; d < 4; ++d)
#pragma unroll
      for (int r = 0; r < 4; ++r) o[d][r] *= sc[r];
    __syncthreads();  // all waves done reading K; reuse region as P[64][256]
#pragma unroll
    for (int c = 0; c < 16; ++c)
#pragma unroll
      for (int r = 0; r < 4; ++r) {
        int row = (w << 4) + (g << 2) + r;
        int byin = (c << 5) + (fr << 1);
        *(u16*)(lds + row * 512 + (byin ^ ((row & 7) << 4))) = f2b(s[c][r]);
      }
    asm volatile("s_waitcnt lgkmcnt(0)" ::: "memory");
    __builtin_amdgcn_sched_barrier(0);
    // PV (wave-local P rows; V untouched)
#pragma unroll
    for (int ss = 0; ss < 8; ++ss) {
      int prow = (w << 4) + fr;
      bf16x8s ap = *(const bf16x8s*)(lds + prow * 512 +
                                     (((ss * 64) + (g << 4)) ^ ((prow & 7) << 4)));
#pragma unroll
      for (int d = 0; d < 4; ++d) {
        int dh = (d << 4) + fr;
        bf16x8s bv = *(const bf16x8s*)(lds + 32768 + dh * 512 +
                                       (((ss * 4 + g) ^ (dh & 7)) << 4));
        o[d] = MFMA(ap, bv, o[d], 0, 0, 0);
      }
    }
  }
  long base = (long)bh * 16384;
#pragma unroll
  for (int d = 0; d < 4; ++d)
#pragma unroll
    for (int r = 0; r < 4; ++r) {
      int mrow = rb * 64 + w * 16 + (g << 2) + r;
      int dh = (d << 4) + fr;
      float v = o[d][r] / l[r];
      u16 h = f2b(v);
      T1thi[base + dh * 256 + mrow] = h;
      T1tlo[base + dh * 256 + mrow] = f2b(v - b2f(h));
    }
}

// ---------------- split-bf16 MFMA NN GEMM (pinv chain), GLL staging ---------
// C[i][j] = sab*(A@B)[i][j] + sa*A[i][j] + cdiag*(i==j)
__global__ __launch_bounds__(256) void k_nn_mfma(
    const u16* __restrict__ Ahi, const u16* __restrict__ Alo,
    const u16* __restrict__ Bthi, const u16* __restrict__ Btlo,
    u16* __restrict__ CNhi, u16* __restrict__ CNlo,
    u16* __restrict__ CThi, u16* __restrict__ CTlo,
    int Nc, float sab, float sa, float cdiag) {
  const int bz = blockIdx.z;
  const long offA = (long)bz << 16;
  const long offB = (long)bz * ((long)Nc << 8);
  const int m0 = blockIdx.y << 6, n0 = blockIdx.x << 6;
  const int t = threadIdx.x, lane = t & 63, w = t >> 6;
  const int wm = (w >> 1) << 5, wn = (w & 1) << 5;
  const int fr = lane & 15, g = lane >> 4;
  __shared__ u16 lds[16384];  // Ah|Al|Bh|Bl, each [64 rows][64 k] swz (8KB)
  u16* LAh = lds;
  u16* LAl = lds + 4096;
  u16* LBh = lds + 8192;
  u16* LBl = lds + 12288;
  f32x4 acc[2][2] = {};
  const int srow8 = lane >> 3, cs = lane & 7;
  for (int k0 = 0; k0 < 256; k0 += 64) {
    __syncthreads();
#pragma unroll
    for (int j = 0; j < 2; ++j) {
      int slab = w * 2 + j;
      int row = slab * 8 + srow8;
      long asrc = offA + (long)(m0 + row) * 256 + k0 + ((cs ^ (row & 7)) << 3);
      long bsrc = offB + (long)(n0 + row) * 256 + k0 + ((cs ^ (row & 7)) << 3);
      GLL(Ahi + asrc, LAh + slab * 512);
      GLL(Alo + asrc, LAl + slab * 512);
      GLL(Bthi + bsrc, LBh + slab * 512);
      GLL(Btlo + bsrc, LBl + slab * 512);
    }
    __syncthreads();
#pragma unroll
    for (int ks = 0; ks < 2; ++ks) {
      const int ra0 = wm + fr, ra1 = wm + 16 + fr;
      const int rb0 = wn + fr, rb1 = wn + 16 + fr;
#define RD(base, row) \
  (*(const bf16x8s*)((const char*)(base) + (row) * 128 + (((ks * 4 + g) ^ ((row) & 7)) << 4)))
      bf16x8s ah0 = RD(LAh, ra0), ah1 = RD(LAh, ra1);
      bf16x8s al0 = RD(LAl, ra0), al1 = RD(LAl, ra1);
      bf16x8s bh0 = RD(LBh, rb0), bh1 = RD(LBh, rb1);
      bf16x8s bl0 = RD(LBl, rb0), bl1 = RD(LBl, rb1);
#undef RD
      acc[0][0] = MFMA(ah0, bh0, acc[0][0], 0, 0, 0);
      acc[0][0] = MFMA(ah0, bl0, acc[0][0], 0, 0, 0);
      acc[0][0] = MFMA(al0, bh0, acc[0][0], 0, 0, 0);
      acc[0][1] = MFMA(ah0, bh1, acc[0][1], 0, 0, 0);
      acc[0][1] = MFMA(ah0, bl1, acc[0][1], 0, 0, 0);
      acc[0][1] = MFMA(al0, bh1, acc[0][1], 0, 0, 0);
      acc[1][0] = MFMA(ah1, bh0, acc[1][0], 0, 0, 0);
      acc[1][0] = MFMA(ah1, bl0, acc[1][0], 0, 0, 0);
      acc[1][0] = MFMA(al1, bh0, acc[1][0], 0, 0, 0);
      acc[1][1] = MFMA(ah1, bh1, acc[1][1], 0, 0, 0);
      acc[1][1] = MFMA(ah1, bl1, acc[1][1], 0, 0, 0);
      acc[1][1] = MFMA(al1, bh1, acc[1][1], 0, 0, 0);
    }
  }
  const int crow = g << 2;
  const long offC = (long)bz * ((long)Nc << 8);
#pragma unroll
  for (int i = 0; i < 2; ++i)
#pragma unroll
    for (int j = 0; j < 2; ++j)
#pragma unroll
      for (int r = 0; r < 4; ++r) {
        int row = m0 + wm + i * 16 + crow + r;
        int col = n0 + wn + j * 16 + fr;
        float v = sab * acc[i][j][r];
        if (sa != 0.f) {
          long ai = offA + ((long)row << 8) + col;
          v += sa * (b2f(Ahi[ai]) + b2f(Alo[ai]));
        }
        if (row == col) v += cdiag;
        if (CNhi) {
          long ci = offC + (long)row * Nc + col;
          u16 h = f2b(v);
          if (CNlo) { CNhi[ci] = h; CNlo[ci] = f2b(v - b2f(h)); }
          else CNhi[ci] = h;
        }
        if (CThi) {
          long ti = offC + ((long)col << 8) + row;
          u16 h = f2b(v);
          CThi[ti] = h;
          if (CTlo) CTlo[ti] = f2b(v - b2f(h));
        }
      }
}

// ---------------- landmarks ----------------
__global__ __launch_bounds__(256) void k_landmark(const u16* __restrict__ src,
                                                  float* __restrict__ df,
                                                  u16* __restrict__ db, int ntok,
                                                  int l, float inv) {
  int pidx = blockIdx.x * 4 + (threadIdx.x >> 6);
  int d = threadIdx.x & 63;
  int bh = pidx >> 8, m = pidx & 255;
  const u16* s = src + ((long)bh * ntok + (long)m * l) * 64 + d;
  float sum = 0.f;
  for (int j = 0; j < l; ++j) sum += b2f(s[j * 64]);
  sum *= inv;
  long o = ((long)bh * 256 + m) * 64 + d;
  df[o] = sum;
  db[o] = f2b(sum);
}

// ---------------- sim2 + softmax (fp32) ----------------
__global__ __launch_bounds__(256) void k_sim2_softmax(const float* __restrict__ qlf,
                                                      const float* __restrict__ klf,
                                                      float* __restrict__ attn2) {
  int m = blockIdx.x, bh = blockIdx.y;
  int j = threadIdx.x, lane = j & 63, w = j >> 6;
  const float* qr = qlf + ((long)bh * 256 + m) * 64;
  const float* kr = klf + ((long)bh * 256 + j) * 64;
  float s = 0.f;
#pragma unroll
  for (int d = 0; d < 64; ++d) s += qr[d] * kr[d];
  float mx = s;
  for (int o = 1; o < 64; o <<= 1) mx = fmaxf(mx, __shfl_xor(mx, o, 64));
  __shared__ float r1[4], r2[4];
  if (lane == 0) r1[w] = mx;
  __syncthreads();
  mx = fmaxf(fmaxf(r1[0], r1[1]), fmaxf(r1[2], r1[3]));
  float e = __expf(s - mx);
  float su = e;
  for (int o = 1; o < 64; o <<= 1) su += __shfl_xor(su, o, 64);
  if (lane == 0) r2[w] = su;
  __syncthreads();
  su = r2[0] + r2[1] + r2[2] + r2[3];
  attn2[(((long)bh * 256 + m) << 8) + j] = e / su;
}

__global__ __launch_bounds__(256) void k_colmax(const float* __restrict__ attn2,
                                                unsigned* __restrict__ cmax) {
  int bh = blockIdx.x, j = threadIdx.x, lane = j & 63, w = j >> 6;
  const float* p = attn2 + ((long)bh << 16) + j;
  float s = 0.f;
  for (int m = 0; m < 256; ++m) s += p[m * 256];
  float mx = s;
  for (int o = 1; o < 64; o <<= 1) mx = fmaxf(mx, __shfl_xor(mx, o, 64));
  __shared__ float r1[4];
  if (lane == 0) r1[w] = mx;
  __syncthreads();
  if (j == 0) {
    mx = fmaxf(fmaxf(r1[0], r1[1]), fmaxf(r1[2], r1[3]));
    atomicMax(cmax, __float_as_uint(mx));
  }
}

// ---------------- pinv operand prep ----------------
__global__ __launch_bounds__(256) void k_prep_pinv(
    const float* __restrict__ attn2, const unsigned* __restrict__ cmax,
    u16* __restrict__ aNhi, u16* __restrict__ aNlo,
    u16* __restrict__ zNhi, u16* __restrict__ zNlo,
    u16* __restrict__ zThi, u16* __restrict__ zTlo) {
  const int bz = blockIdx.z, i0 = blockIdx.y << 6, j0 = blockIdx.x << 6;
  const float s = 1.f / __uint_as_float(*cmax);
  const float* base = attn2 + ((long)bz << 16);
  __shared__ float mt[64][65];
  const int r = threadIdx.x >> 2, cb = (threadIdx.x & 3) << 4;
#pragma unroll
  for (int c4 = 0; c4 < 16; c4 += 4) {
    float4 v = *(const float4*)&base[(long)(j0 + r) * 256 + i0 + cb + c4];
    mt[r][cb + c4] = v.x; mt[r][cb + c4 + 1] = v.y;
    mt[r][cb + c4 + 2] = v.z; mt[r][cb + c4 + 3] = v.w;
  }
  __syncthreads();
  const int i = i0 + r;
#pragma unroll
  for (int c4 = 0; c4 < 16; c4 += 4) {
    float4 v = *(const float4*)&base[(long)i * 256 + j0 + cb + c4];
    float vv[4] = {v.x, v.y, v.z, v.w};
#pragma unroll
    for (int e = 0; e < 4; ++e) {
      int j = j0 + cb + c4 + e;
      long idx = ((long)bz << 16) + ((long)i << 8) + j;
      float a = vv[e];
      u16 h = f2b(a);
      aNhi[idx] = h; aNlo[idx] = f2b(a - b2f(h));
      float zt = a * s;
      u16 zh = f2b(zt);
      zThi[idx] = zh; zTlo[idx] = f2b(zt - b2f(zh));
      float zn = mt[cb + c4 + e][r] * s;
      u16 nh = f2b(zn);
      zNhi[idx] = nh; zNlo[idx] = f2b(zn - b2f(nh));
    }
  }
}

// ---------------- fused sim1: O = softmax(q @ k_land^T) @ T2 ----------------
// T2 supplied TRANSPOSED: t2t[bh][64 dh][256 m]
__global__ __launch_bounds__(256) void k_fused_attn1(const u16* __restrict__ q,
                                                     const u16* __restrict__ klb,
                                                     const u16* __restrict__ t2t,
                                                     u16* __restrict__ O) {
  const int bh = blockIdx.y, n0 = blockIdx.x << 6;
  const int bb = bh >> 3, hh = bh & 7;
  const int t = threadIdx.x, lane = t & 63, w = t >> 6;
  const int fr = lane & 15, g = lane >> 4;
  __shared__ char lds[65536];  // [0,32K) k_land (aliased by P); [32K,64K) T2^T
  {
    const u16* ks = klb + (long)bh * 16384;
    const u16* ts = t2t + (long)bh * 16384;
    int srow8 = lane >> 3, cs7 = lane & 7;
    int srow2 = lane >> 5, seg32 = lane & 31;
#pragma unroll
    for (int i = 0; i < 8; ++i) {
      int slab = w * 8 + i;
      int krow = slab * 8 + srow8;
      GLL(ks + krow * 64 + ((cs7 ^ (krow & 7)) << 3), lds + slab * 1024);
      int trow = slab * 2 + srow2;
      GLL(ts + trow * 256 + ((seg32 ^ (trow & 7)) << 3), lds + 32768 + slab * 1024);
    }
  }
  __syncthreads();
  const u16* qrow = q + ((long)bh * 8192 + n0 + (w << 4) + fr) * 64;
  bf16x8s qa0 = *(const bf16x8s*)(qrow + g * 8);
  bf16x8s qa1 = *(const bf16x8s*)(qrow + 32 + g * 8);
  f32x4 s[16];
#pragma unroll
  for (int c = 0; c < 16; ++c) {
    int j = (c << 4) + fr;
    bf16x8s b0 = *(const bf16x8s*)(lds + j * 128 + ((g ^ (j & 7)) << 4));
    bf16x8s b1 = *(const bf16x8s*)(lds + j * 128 + (((4 + g) ^ (j & 7)) << 4));
    f32x4 zz = {};
    zz = MFMA(qa0, b0, zz, 0, 0, 0);
    zz = MFMA(qa1, b1, zz, 0, 0, 0);
    s[c] = zz;
  }
  float li[4];
#pragma unroll
  for (int r = 0; r < 4; ++r) {
    float m = s[0][r];
#pragma unroll
    for (int c = 1; c < 16; ++c) m = fmaxf(m, s[c][r]);
    m = fmaxf(m, __shfl_xor(m, 1, 64));
    m = fmaxf(m, __shfl_xor(m, 2, 64));
    m = fmaxf(m, __shfl_xor(m, 4, 64));
    m = fmaxf(m, __shfl_xor(m, 8, 64));
    float l = 0.f;
#pragma unroll
    for (int c = 0; c < 16; ++c) {
      float e = __expf(s[c][r] - m);
      s[c][r] = e;
      l += e;
    }
    l += __shfl_xor(l, 1, 64);
    l += __shfl_xor(l, 2, 64);
    l += __shfl_xor(l, 4, 64);
    l += __shfl_xor(l, 8, 64);
    li[r] = 1.f / l;
  }
  __syncthreads();  // all waves done reading k_land; reuse region as P[64][256]
#pragma unroll
  for (int c = 0; c < 16; ++c)
#pragma unroll
    for (int r = 0; r < 4; ++r) {
      int row = (w << 4) + (g << 2) + r;
      int byin = (c << 5) + (fr << 1);
      *(u16*)(lds + row * 512 + (byin ^ ((row & 7) << 4))) = f2b(s[c][r]);
    }
  asm volatile("s_waitcnt lgkmcnt(0)" ::: "memory");
  __builtin_amdgcn_sched_barrier(0);
  f32x4 o4[4] = {};
#pragma unroll
  for (int ss = 0; ss < 8; ++ss) {
    int prow = (w << 4) + fr;
    bf16x8s ap = *(const bf16x8s*)(lds + prow * 512 +
                                   (((ss * 64) + (g << 4)) ^ ((prow & 7) << 4)));
#pragma unroll
    for (int d = 0; d < 4; ++d) {
      int dh = (d << 4) + fr;
      bf16x8s bv = *(const bf16x8s*)(lds + 32768 + dh * 512 +
                                     (((ss * 4 + g) ^ (dh & 7)) << 4));
      o4[d] = MFMA(ap, bv, o4[d], 0, 0, 0);
    }
  }
  u16* ob = O + (((long)bb * 8192 + n0 + (w << 4)) << 9) + (hh << 6);
#pragma unroll
  for (int d = 0; d < 4; ++d)
#pragma unroll
    for (int r = 0; r < 4; ++r) {
      int row = (g << 2) + r;
      int col = (d << 4) + fr;
      ob[((long)row << 9) + col] = f2b(o4[d][r] * li[r]);
    }
}

// ---------------- host ----------------
extern "C" void kernel_launch(void* const* d_in, const int* in_sizes, int n_in,
                              void* d_out, int out_size, void* d_ws, size_t ws_size,
                              hipStream_t stream) {
  const float* x = (const float*)d_in[0];
  const float* z = (const float*)d_in[1];
  const float* Wq = (const float*)d_in[2];
  const float* Wkv = (const float*)d_in[3];
  const float* Wo = (const float*)d_in[4];
  const float* bo = (const float*)d_in[5];
  float* out = (float*)d_out;

  char* base = (char*)d_ws;
  size_t off = 0;
  auto alloc = [&](size_t bytes) -> void* {
    void* r = base + off;
    off = (off + bytes + 255) & ~(size_t)255;
    return r;
  };
  u16* qb = (u16*)alloc(33554432);
  u16* kb = (u16*)alloc(16777216);
  u16* vtb = (u16*)alloc(16777216);
  u16* PS = (u16*)alloc(67108864);    // pinv state (16 x 4MB)
  float* attn2 = (float*)alloc(8388608);
  u16* xb = (u16*)alloc(33554432);    // dead after qproj -> Ob
  u16* zb = (u16*)alloc(16777216);    // dead after kvproj -> attn2 split
  u16* wqt = (u16*)alloc(524288);
  u16* wkvt = (u16*)alloc(1048576);
  u16* wot = (u16*)alloc(524288);
  float* qlf = (float*)alloc(2097152);
  u16* qlb = (u16*)alloc(1048576);
  float* klf = (float*)alloc(2097152);
  u16* klb = (u16*)alloc(1048576);
  u16* T1t = (u16*)alloc(2097152);
  u16* T2t = (u16*)alloc(1048576);    // T2^T [bh][64 dh][256 m]
  unsigned* cmax = (unsigned*)alloc(256);
  const long MC = 2097152;
  u16* P = PS;
  u16 *ztA_Nhi = P,          *ztA_Nlo = P + MC,      *ztA_Thi = P + 2 * MC,  *ztA_Tlo = P + 3 * MC;
  u16 *ztB_Nhi = P + 4 * MC,  *ztB_Nlo = P + 5 * MC,  *ztB_Thi = P + 6 * MC,  *ztB_Tlo = P + 7 * MC;
  u16 *az_Nhi = P + 8 * MC,   *az_Nlo = P + 9 * MC,   *az_Thi = P + 10 * MC,  *az_Tlo = P + 11 * MC;
  u16 *taThi = P + 12 * MC,   *taTlo = P + 13 * MC;
  u16 *tcThi = P + 14 * MC,   *tcTlo = P + 15 * MC;
  u16 *aNhi = zb, *aNlo = zb + MC;
  u16* T1thi = T1t;
  u16* T1tlo = T1t + 524288;
  u16* Ob = xb;

  hipMemsetAsync(cmax, 0, 4, stream);
  k_f2b<<<16384, 256, 0, stream>>>(x, xb, 4194304);
  k_f2b<<<8192, 256, 0, stream>>>(z, zb, 2097152);
  k_wt<<<1024, 256, 0, stream>>>(Wq, wqt, 512);
  k_wt<<<2048, 256, 0, stream>>>(Wkv, wkvt, 1024);
  k_wt<<<1024, 256, 0, stream>>>(Wo, wot, 512);

  k_gemm128<0><<<dim3(4, 256), 256, 0, stream>>>(xb, wqt, qb, nullptr, nullptr,
                                                 nullptr, 512);
  k_gemm128<1><<<dim3(8, 128), 256, 0, stream>>>(zb, wkvt, kb, vtb, nullptr,
                                                 nullptr, 512);
  k_landmark<<<2048, 256, 0, stream>>>(qb, qlf, qlb, 8192, 32, 1.f / 32.f);
  k_landmark<<<2048, 256, 0, stream>>>(kb, klf, klb, 4096, 16, 1.f / 16.f);
  k_sim2_softmax<<<dim3(256, 32), 256, 0, stream>>>(qlf, klf, attn2);
  k_colmax<<<32, 256, 0, stream>>>(attn2, cmax);

  // fused sim3 -> softmax -> T1 (flash)
  k_flashT1<<<128, 256, 0, stream>>>(qlb, kb, vtb, T1thi, T1tlo);

  // pinv prep (aN into dead zb; zt state into PS)
  k_prep_pinv<<<dim3(4, 4, 32), 256, 0, stream>>>(attn2, cmax, aNhi, aNlo,
                                                  ztA_Nhi, ztA_Nlo, ztA_Thi, ztA_Tlo);

  dim3 g256(4, 4, 32);
  u16 *cN0 = ztA_Nhi, *cN1 = ztA_Nlo, *cT0 = ztA_Thi, *cT1 = ztA_Tlo;
  u16 *nN0 = ztB_Nhi, *nN1 = ztB_Nlo, *nT0 = ztB_Thi, *nT1 = ztB_Tlo;
  for (int it = 0; it < 6; ++it) {
    bool last = (it == 5);
    k_nn_mfma<<<g256, 256, 0, stream>>>(aNhi, aNlo, cT0, cT1, az_Nhi, az_Nlo,
                                        az_Thi, az_Tlo, 256, 1.f, 0.f, 0.f);
    k_nn_mfma<<<g256, 256, 0, stream>>>(az_Nhi, az_Nlo, az_Thi, az_Tlo, nullptr,
                                        nullptr, taThi, taTlo, 256, 1.f, -7.f, 15.f);
    k_nn_mfma<<<g256, 256, 0, stream>>>(az_Nhi, az_Nlo, taThi, taTlo, nullptr,
                                        nullptr, tcThi, tcTlo, 256, -1.f, 0.f, 13.f);
    k_nn_mfma<<<g256, 256, 0, stream>>>(cN0, cN1, tcThi, tcTlo, nN0, nN1,
                                        last ? nullptr : nT0, last ? nullptr : nT1,
                                        256, 0.25f, 0.f, 0.f);
    u16* t0;
    t0 = cN0; cN0 = nN0; nN0 = t0;  t0 = cN1; cN1 = nN1; nN1 = t0;
    t0 = cT0; cT0 = nT0; nT0 = t0;  t0 = cT1; cT1 = nT1; nT1 = t0;
  }
  // T2^T = (pinv @ T1)^T, plain bf16, [bh][64 dh][256 m] via CT store
  k_nn_mfma<<<dim3(1, 4, 32), 256, 0, stream>>>(cN0, cN1, T1thi, T1tlo, nullptr,
                                                nullptr, T2t, nullptr, 64,
                                                1.f, 0.f, 0.f);

  k_fused_attn1<<<dim3(128, 32), 256, 0, stream>>>(qb, klb, T2t, Ob);
  k_gemm128<2><<<dim3(4, 256), 256, 0, stream>>>(Ob, wot, out, nullptr, x, bo, 512);
}

// Round 6
// 752.090 us; speedup vs baseline: 1.3185x; 1.0480x over previous
//
#include <hip/hip_runtime.h>

typedef unsigned short u16;
typedef __attribute__((ext_vector_type(8))) short bf16x8s;
typedef __attribute__((ext_vector_type(4))) float f32x4;

#define DEV static __device__ __forceinline__

DEV float b2f(u16 v) { return __uint_as_float(((unsigned)v) << 16); }
DEV u16 f2b(float f) {
  unsigned u = __float_as_uint(f);
  unsigned r = (u + 0x7fffu + ((u >> 16) & 1u)) >> 16;
  return (u16)r;
}

// async global->LDS, 16B per lane; lds base must be wave-uniform (HW adds lane*16)
#define GLL(gp, lp)                                                            \
  __builtin_amdgcn_global_load_lds(                                            \
      (const __attribute__((address_space(1))) unsigned int*)(gp),             \
      (__attribute__((address_space(3))) unsigned int*)(lp), 16, 0, 0)

#define MFMA __builtin_amdgcn_mfma_f32_16x16x32_bf16

// ---------------- elementwise converts ----------------
__global__ __launch_bounds__(256) void k_f2b(const float* __restrict__ in,
                                             u16* __restrict__ o, long n4) {
  long i = (long)blockIdx.x * 256 + threadIdx.x;
  if (i >= n4) return;
  float4 v = *(const float4*)(in + i * 4);
  u16* d = o + i * 4;
  d[0] = f2b(v.x); d[1] = f2b(v.y); d[2] = f2b(v.z); d[3] = f2b(v.w);
}

// W[k][N] (fp32) -> Wt[n][512] bf16  (K fixed = 512)
__global__ __launch_bounds__(256) void k_wt(const float* __restrict__ W,
                                            u16* __restrict__ Wt, int N) {
  int e = blockIdx.x * 256 + threadIdx.x;  // e < N*512
  int nn = e >> 9, kk = e & 511;
  Wt[e] = f2b(W[(long)kk * N + nn]);
}

// ---------------- 128x128 bf16 NT GEMM (BK=64, global_load_lds, swizzled) ----
template <int MODE>
__global__ __launch_bounds__(256, 2) void k_gemm128(
    const u16* __restrict__ A, const u16* __restrict__ Bm, void* __restrict__ C0,
    void* __restrict__ C1, const float* __restrict__ xres,
    const float* __restrict__ bias, int K) {
  const int nwg = gridDim.x * gridDim.y;
  const int orig = blockIdx.y * gridDim.x + blockIdx.x;
  const int qq = nwg >> 3, rr = nwg & 7;
  const int xcd = orig & 7, loc = orig >> 3;
  const int swz = (xcd < rr ? xcd * (qq + 1) : rr * (qq + 1) + (xcd - rr) * qq) + loc;
  const int m0 = (swz / gridDim.x) << 7, n0 = (swz % gridDim.x) << 7;
  const int t = threadIdx.x, lane = t & 63, w = t >> 6;
  const int wm = (w >> 1) << 6, wn = (w & 1) << 6;
  const int fr = lane & 15, g = lane >> 4;
  __shared__ u16 As[8192];
  __shared__ u16 Bs[8192];
  f32x4 acc[4][4] = {};
  const int srow = t >> 3, scs = t & 7;
  for (int k0 = 0; k0 < K; k0 += 64) {
    __syncthreads();
#pragma unroll
    for (int i = 0; i < 4; ++i) {
      int row = srow + (i << 5), cs = scs;
      GLL(A + (long)(m0 + row) * K + k0 + ((cs ^ (row & 7)) << 3),
          &As[(i << 11) + (w << 9)]);
      GLL(Bm + (long)(n0 + row) * K + k0 + ((cs ^ (row & 7)) << 3),
          &Bs[(i << 11) + (w << 9)]);
    }
    __syncthreads();
#pragma unroll
    for (int ks = 0; ks < 2; ++ks) {
      bf16x8s af[4], bf[4];
#pragma unroll
      for (int fi = 0; fi < 4; ++fi) {
        int row = wm + fi * 16 + fr;
        af[fi] = *(const bf16x8s*)((const char*)As + row * 128 +
                                   (((ks * 4 + g) ^ (row & 7)) << 4));
      }
#pragma unroll
      for (int fj = 0; fj < 4; ++fj) {
        int row = wn + fj * 16 + fr;
        bf[fj] = *(const bf16x8s*)((const char*)Bs + row * 128 +
                                   (((ks * 4 + g) ^ (row & 7)) << 4));
      }
#pragma unroll
      for (int fi = 0; fi < 4; ++fi)
#pragma unroll
        for (int fj = 0; fj < 4; ++fj)
          acc[fi][fj] = MFMA(af[fi], bf[fj], acc[fi][fj], 0, 0, 0);
    }
  }
  const int crow = g << 2;
#pragma unroll
  for (int fi = 0; fi < 4; ++fi)
#pragma unroll
    for (int fj = 0; fj < 4; ++fj)
#pragma unroll
      for (int r = 0; r < 4; ++r) {
        int row = m0 + wm + fi * 16 + crow + r;
        int col = n0 + wn + fj * 16 + fr;
        float v = acc[fi][fj][r];
        if (MODE == 0) {
          int b = row >> 13, n = row & 8191, h = col >> 6, dh = col & 63;
          ((u16*)C0)[((((long)(b * 8 + h)) << 13) + n) * 64 + dh] = f2b(v * 0.125f);
        } else if (MODE == 1) {
          int b = row >> 12, nz = row & 4095;
          if (col < 512) {
            int h = col >> 6, dh = col & 63;
            ((u16*)C0)[((((long)(b * 8 + h)) << 12) + nz) * 64 + dh] = f2b(v);
          } else {
            int c2 = col - 512, h = c2 >> 6, dh = c2 & 63;
            ((u16*)C1)[((((long)(b * 8 + h) * 64 + dh)) << 12) + nz] = f2b(v);
          }
        } else if (MODE == 2) {
          long idx = ((long)row << 9) + col;
          ((float*)C0)[idx] = v + xres[idx] + bias[col];
        }
      }
}

// ---------------- landmarks: mean over groups -> split hi/lo bf16 -----------
__global__ __launch_bounds__(256) void k_landmark(const u16* __restrict__ src,
                                                  u16* __restrict__ hi,
                                                  u16* __restrict__ lo, int ntok,
                                                  int l, float inv) {
  int pidx = blockIdx.x * 4 + (threadIdx.x >> 6);
  int d = threadIdx.x & 63;
  int bh = pidx >> 8, m = pidx & 255;
  const u16* s = src + ((long)bh * ntok + (long)m * l) * 64 + d;
  float sum = 0.f;
  for (int j = 0; j < l; ++j) sum += b2f(s[j * 64]);
  sum *= inv;
  long o = ((long)bh * 256 + m) * 64 + d;
  u16 h = f2b(sum);
  hi[o] = h;
  lo[o] = f2b(sum - b2f(h));
}

// ---------------- sim2 + softmax via split-bf16 MFMA ------------------------
// attn2[bh][256][256] fp32 normalized + aN hi/lo split (bf16)
__global__ __launch_bounds__(256, 2) void k_sim2(
    const u16* __restrict__ qlh, const u16* __restrict__ qll,
    const u16* __restrict__ klh, const u16* __restrict__ kll,
    float* __restrict__ attn2, u16* __restrict__ aNhi, u16* __restrict__ aNlo) {
  const int rb = blockIdx.x, bh = blockIdx.y;
  const int t = threadIdx.x, lane = t & 63, w = t >> 6;
  const int fr = lane & 15, g = lane >> 4;
  __shared__ char lds[65536];  // [0,32K) k_land hi ; [32K,64K) k_land lo
  {
    const u16* kh = klh + (long)bh * 16384;
    const u16* kl = kll + (long)bh * 16384;
    int srow8 = lane >> 3, cs7 = lane & 7;
#pragma unroll
    for (int i = 0; i < 8; ++i) {
      int slab = w * 8 + i;
      int krow = slab * 8 + srow8;
      GLL(kh + krow * 64 + ((cs7 ^ (krow & 7)) << 3), lds + slab * 1024);
      GLL(kl + krow * 64 + ((cs7 ^ (krow & 7)) << 3), lds + 32768 + slab * 1024);
    }
  }
  long qoff = ((long)bh * 256 + rb * 64 + w * 16 + fr) * 64;
  bf16x8s qh0 = *(const bf16x8s*)(qlh + qoff + g * 8);
  bf16x8s qh1 = *(const bf16x8s*)(qlh + qoff + 32 + g * 8);
  bf16x8s ql0 = *(const bf16x8s*)(qll + qoff + g * 8);
  bf16x8s ql1 = *(const bf16x8s*)(qll + qoff + 32 + g * 8);
  __syncthreads();
  f32x4 s[16];
#pragma unroll
  for (int c = 0; c < 16; ++c) {
    int j = (c << 4) + fr;
    int o0 = j * 128 + ((g ^ (j & 7)) << 4);
    int o1 = j * 128 + (((4 + g) ^ (j & 7)) << 4);
    bf16x8s kh0 = *(const bf16x8s*)(lds + o0);
    bf16x8s kh1 = *(const bf16x8s*)(lds + o1);
    bf16x8s kl0 = *(const bf16x8s*)(lds + 32768 + o0);
    bf16x8s kl1 = *(const bf16x8s*)(lds + 32768 + o1);
    f32x4 zz = {};
    zz = MFMA(qh0, kh0, zz, 0, 0, 0);
    zz = MFMA(qh1, kh1, zz, 0, 0, 0);
    zz = MFMA(qh0, kl0, zz, 0, 0, 0);
    zz = MFMA(qh1, kl1, zz, 0, 0, 0);
    zz = MFMA(ql0, kh0, zz, 0, 0, 0);
    zz = MFMA(ql1, kh1, zz, 0, 0, 0);
    s[c] = zz;
  }
  float li[4];
#pragma unroll
  for (int r = 0; r < 4; ++r) {
    float m = s[0][r];
#pragma unroll
    for (int c = 1; c < 16; ++c) m = fmaxf(m, s[c][r]);
    m = fmaxf(m, __shfl_xor(m, 1, 64));
    m = fmaxf(m, __shfl_xor(m, 2, 64));
    m = fmaxf(m, __shfl_xor(m, 4, 64));
    m = fmaxf(m, __shfl_xor(m, 8, 64));
    float l = 0.f;
#pragma unroll
    for (int c = 0; c < 16; ++c) {
      float e = __expf(s[c][r] - m);
      s[c][r] = e;
      l += e;
    }
    l += __shfl_xor(l, 1, 64);
    l += __shfl_xor(l, 2, 64);
    l += __shfl_xor(l, 4, 64);
    l += __shfl_xor(l, 8, 64);
    li[r] = 1.f / l;
  }
#pragma unroll
  for (int c = 0; c < 16; ++c)
#pragma unroll
    for (int r = 0; r < 4; ++r) {
      int row = rb * 64 + w * 16 + (g << 2) + r;
      int col = (c << 4) + fr;
      long idx = ((long)bh << 16) + ((long)row << 8) + col;
      float p = s[c][r] * li[r];
      attn2[idx] = p;
      u16 h = f2b(p);
      aNhi[idx] = h;
      aNlo[idx] = f2b(p - b2f(h));
    }
}

__global__ __launch_bounds__(256) void k_colmax(const float* __restrict__ attn2,
                                                unsigned* __restrict__ cmax) {
  int bh = blockIdx.x, j = threadIdx.x, lane = j & 63, w = j >> 6;
  const float* p = attn2 + ((long)bh << 16) + j;
  float s = 0.f;
  for (int m = 0; m < 256; ++m) s += p[m * 256];
  float mx = s;
  for (int o = 1; o < 64; o <<= 1) mx = fmaxf(mx, __shfl_xor(mx, o, 64));
  __shared__ float r1[4];
  if (lane == 0) r1[w] = mx;
  __syncthreads();
  if (j == 0) {
    mx = fmaxf(fmaxf(r1[0], r1[1]), fmaxf(r1[2], r1[3]));
    atomicMax(cmax, __float_as_uint(mx));
  }
}

// ---------------- T1 split-KV partial: one (bh, rowblk, kchunk of 512) ------
// writes unnormalized o (fp32), per-row m,l
__global__ __launch_bounds__(256, 2) void k_t1part(
    const u16* __restrict__ qlb, const u16* __restrict__ kb,
    const u16* __restrict__ vtb, float* __restrict__ opart,
    float* __restrict__ pm_, float* __restrict__ pl_) {
  int orig = blockIdx.x;                       // 1024 = 32 bh * 8 kc * 4 rb
  int swz = (orig & 7) * 128 + (orig >> 3);    // bijective (1024 % 8 == 0)
  int bh = swz >> 5, kc = (swz >> 2) & 7, rb = swz & 3;
  const int t = threadIdx.x, lane = t & 63, w = t >> 6;
  const int fr = lane & 15, g = lane >> 4;
  __shared__ char lds[65536];  // [0,32K) K chunk (aliased by P); [32K,64K) V^T
  const u16* qrow = qlb + ((long)bh * 256 + rb * 64 + w * 16 + fr) * 64;
  bf16x8s qa0 = *(const bf16x8s*)(qrow + g * 8);
  bf16x8s qa1 = *(const bf16x8s*)(qrow + 32 + g * 8);
  f32x4 o[4] = {};
  float m[4] = {-3e38f, -3e38f, -3e38f, -3e38f};
  float l[4] = {};
  const long kbase = (long)bh * 262144;
#pragma unroll
  for (int cc = 0; cc < 2; ++cc) {
    int c0 = kc * 512 + cc * 256;
    __syncthreads();
#pragma unroll
    for (int i = 0; i < 8; ++i) {
      int seg = (i << 8) + t, row = seg >> 3, cs = seg & 7;
      GLL(kb + kbase + (long)(c0 + row) * 64 + ((cs ^ (row & 7)) << 3),
          lds + (i << 12) + (w << 10));
    }
#pragma unroll
    for (int i = 0; i < 8; ++i) {
      int seg = (i << 8) + t, row = seg >> 5, cs = seg & 31;
      GLL(vtb + kbase + (long)row * 4096 + c0 + ((cs ^ (row & 7)) << 3),
          lds + 32768 + (i << 12) + (w << 10));
    }
    __syncthreads();
    f32x4 s[16];
#pragma unroll
    for (int c = 0; c < 16; ++c) {
      int j = c * 16 + fr;
      bf16x8s b0 = *(const bf16x8s*)(lds + j * 128 + ((g ^ (j & 7)) << 4));
      bf16x8s b1 = *(const bf16x8s*)(lds + j * 128 + (((4 + g) ^ (j & 7)) << 4));
      f32x4 zz = {};
      zz = MFMA(qa0, b0, zz, 0, 0, 0);
      zz = MFMA(qa1, b1, zz, 0, 0, 0);
      s[c] = zz;
    }
    float sc[4];
#pragma unroll
    for (int r = 0; r < 4; ++r) {
      float pm = s[0][r];
#pragma unroll
      for (int c = 1; c < 16; ++c) pm = fmaxf(pm, s[c][r]);
      pm = fmaxf(pm, __shfl_xor(pm, 1, 64));
      pm = fmaxf(pm, __shfl_xor(pm, 2, 64));
      pm = fmaxf(pm, __shfl_xor(pm, 4, 64));
      pm = fmaxf(pm, __shfl_xor(pm, 8, 64));
      float mn = fmaxf(m[r], pm);
      sc[r] = __expf(m[r] - mn);
      m[r] = mn;
    }
#pragma unroll
    for (int r = 0; r < 4; ++r) {
      float su = 0.f;
#pragma unroll
      for (int c = 0; c < 16; ++c) {
        float e = __expf(s[c][r] - m[r]);
        s[c][r] = e;
        su += e;
      }
      su += __shfl_xor(su, 1, 64);
      su += __shfl_xor(su, 2, 64);
      su += __shfl_xor(su, 4, 64);
      su += __shfl_xor(su, 8, 64);
      l[r] = l[r] * sc[r] + su;
    }
#pragma unroll
    for (int d = 0; d < 4; ++d)
#pragma unroll
      for (int r = 0; r < 4; ++r) o[d][r] *= sc[r];
    __syncthreads();
#pragma unroll
    for (int c = 0; c < 16; ++c)
#pragma unroll
      for (int r = 0; r < 4; ++r) {
        int row = (w << 4) + (g << 2) + r;
        int byin = (c << 5) + (fr << 1);
        *(u16*)(lds + row * 512 + (byin ^ ((row & 7) << 4))) = f2b(s[c][r]);
      }
    asm volatile("s_waitcnt lgkmcnt(0)" ::: "memory");
    __builtin_amdgcn_sched_barrier(0);
#pragma unroll
    for (int ss = 0; ss < 8; ++ss) {
      int prow = (w << 4) + fr;
      bf16x8s ap = *(const bf16x8s*)(lds + prow * 512 +
                                     (((ss * 64) + (g << 4)) ^ ((prow & 7) << 4)));
#pragma unroll
      for (int d = 0; d < 4; ++d) {
        int dh = (d << 4) + fr;
        bf16x8s bv = *(const bf16x8s*)(lds + 32768 + dh * 512 +
                                       (((ss * 4 + g) ^ (dh & 7)) << 4));
        o[d] = MFMA(ap, bv, o[d], 0, 0, 0);
      }
    }
  }
  const long pbase = (long)(bh * 8 + kc) * 256;
#pragma unroll
  for (int d = 0; d < 4; ++d)
#pragma unroll
    for (int r = 0; r < 4; ++r) {
      int mrow = rb * 64 + w * 16 + (g << 2) + r;
      int dh = (d << 4) + fr;
      opart[(pbase + mrow) * 64 + dh] = o[d][r];
    }
  if (fr == 0) {
#pragma unroll
    for (int r = 0; r < 4; ++r) {
      int mrow = rb * 64 + w * 16 + (g << 2) + r;
      pm_[pbase + mrow] = m[r];
      pl_[pbase + mrow] = l[r];
    }
  }
}

// ---------------- merge 8 partials -> T1^T split bf16 -----------------------
__global__ __launch_bounds__(256) void k_t1merge(
    const float* __restrict__ opart, const float* __restrict__ pm_,
    const float* __restrict__ pl_, u16* __restrict__ T1thi,
    u16* __restrict__ T1tlo) {
  const int rb = blockIdx.x, bh = blockIdx.y;
  const int t = threadIdx.x;
#pragma unroll
  for (int rp = 0; rp < 4; ++rp) {
    int row = rb * 64 + rp * 16 + (t >> 4);
    int dh4 = (t & 15) << 2;
    float pmv[8], M = -3e38f;
#pragma unroll
    for (int i = 0; i < 8; ++i) {
      pmv[i] = pm_[(long)(bh * 8 + i) * 256 + row];
      M = fmaxf(M, pmv[i]);
    }
    float L = 0.f, wt[8];
#pragma unroll
    for (int i = 0; i < 8; ++i) {
      wt[i] = __expf(pmv[i] - M);
      L += pl_[(long)(bh * 8 + i) * 256 + row] * wt[i];
    }
    float4 acc = {0.f, 0.f, 0.f, 0.f};
#pragma unroll
    for (int i = 0; i < 8; ++i) {
      float4 v = *(const float4*)&opart[((long)(bh * 8 + i) * 256 + row) * 64 + dh4];
      acc.x += v.x * wt[i]; acc.y += v.y * wt[i];
      acc.z += v.z * wt[i]; acc.w += v.w * wt[i];
    }
    float invL = 1.f / L;
    float vv[4] = {acc.x * invL, acc.y * invL, acc.z * invL, acc.w * invL};
#pragma unroll
    for (int e = 0; e < 4; ++e) {
      int dh = dh4 + e;
      long idx = (long)bh * 16384 + (long)dh * 256 + row;
      u16 h = f2b(vv[e]);
      T1thi[idx] = h;
      T1tlo[idx] = f2b(vv[e] - b2f(h));
    }
  }
}

// ---------------- split-bf16 MFMA NN GEMM (pinv chain), GLL staging ---------
__global__ __launch_bounds__(256) void k_nn_mfma(
    const u16* __restrict__ Ahi, const u16* __restrict__ Alo,
    const u16* __restrict__ Bthi, const u16* __restrict__ Btlo,
    u16* __restrict__ CNhi, u16* __restrict__ CNlo,
    u16* __restrict__ CThi, u16* __restrict__ CTlo,
    int Nc, float sab, float sa, float cdiag) {
  const int bz = blockIdx.z;
  const long offA = (long)bz << 16;
  const long offB = (long)bz * ((long)Nc << 8);
  const int m0 = blockIdx.y << 6, n0 = blockIdx.x << 6;
  const int t = threadIdx.x, lane = t & 63, w = t >> 6;
  const int wm = (w >> 1) << 5, wn = (w & 1) << 5;
  const int fr = lane & 15, g = lane >> 4;
  __shared__ u16 lds[16384];
  u16* LAh = lds;
  u16* LAl = lds + 4096;
  u16* LBh = lds + 8192;
  u16* LBl = lds + 12288;
  f32x4 acc[2][2] = {};
  const int srow8 = lane >> 3, cs = lane & 7;
  for (int k0 = 0; k0 < 256; k0 += 64) {
    __syncthreads();
#pragma unroll
    for (int j = 0; j < 2; ++j) {
      int slab = w * 2 + j;
      int row = slab * 8 + srow8;
      long asrc = offA + (long)(m0 + row) * 256 + k0 + ((cs ^ (row & 7)) << 3);
      long bsrc = offB + (long)(n0 + row) * 256 + k0 + ((cs ^ (row & 7)) << 3);
      GLL(Ahi + asrc, LAh + slab * 512);
      GLL(Alo + asrc, LAl + slab * 512);
      GLL(Bthi + bsrc, LBh + slab * 512);
      GLL(Btlo + bsrc, LBl + slab * 512);
    }
    __syncthreads();
#pragma unroll
    for (int ks = 0; ks < 2; ++ks) {
      const int ra0 = wm + fr, ra1 = wm + 16 + fr;
      const int rb0 = wn + fr, rb1 = wn + 16 + fr;
#define RD(base, row) \
  (*(const bf16x8s*)((const char*)(base) + (row) * 128 + (((ks * 4 + g) ^ ((row) & 7)) << 4)))
      bf16x8s ah0 = RD(LAh, ra0), ah1 = RD(LAh, ra1);
      bf16x8s al0 = RD(LAl, ra0), al1 = RD(LAl, ra1);
      bf16x8s bh0 = RD(LBh, rb0), bh1 = RD(LBh, rb1);
      bf16x8s bl0 = RD(LBl, rb0), bl1 = RD(LBl, rb1);
#undef RD
      acc[0][0] = MFMA(ah0, bh0, acc[0][0], 0, 0, 0);
      acc[0][0] = MFMA(ah0, bl0, acc[0][0], 0, 0, 0);
      acc[0][0] = MFMA(al0, bh0, acc[0][0], 0, 0, 0);
      acc[0][1] = MFMA(ah0, bh1, acc[0][1], 0, 0, 0);
      acc[0][1] = MFMA(ah0, bl1, acc[0][1], 0, 0, 0);
      acc[0][1] = MFMA(al0, bh1, acc[0][1], 0, 0, 0);
      acc[1][0] = MFMA(ah1, bh0, acc[1][0], 0, 0, 0);
      acc[1][0] = MFMA(ah1, bl0, acc[1][0], 0, 0, 0);
      acc[1][0] = MFMA(al1, bh0, acc[1][0], 0, 0, 0);
      acc[1][1] = MFMA(ah1, bh1, acc[1][1], 0, 0, 0);
      acc[1][1] = MFMA(ah1, bl1, acc[1][1], 0, 0, 0);
      acc[1][1] = MFMA(al1, bh1, acc[1][1], 0, 0, 0);
    }
  }
  const int crow = g << 2;
  const long offC = (long)bz * ((long)Nc << 8);
#pragma unroll
  for (int i = 0; i < 2; ++i)
#pragma unroll
    for (int j = 0; j < 2; ++j)
#pragma unroll
      for (int r = 0; r < 4; ++r) {
        int row = m0 + wm + i * 16 + crow + r;
        int col = n0 + wn + j * 16 + fr;
        float v = sab * acc[i][j][r];
        if (sa != 0.f) {
          long ai = offA + ((long)row << 8) + col;
          v += sa * (b2f(Ahi[ai]) + b2f(Alo[ai]));
        }
        if (row == col) v += cdiag;
        if (CNhi) {
          long ci = offC + (long)row * Nc + col;
          u16 h = f2b(v);
          if (CNlo) { CNhi[ci] = h; CNlo[ci] = f2b(v - b2f(h)); }
          else CNhi[ci] = h;
        }
        if (CThi) {
          long ti = offC + ((long)col << 8) + row;
          u16 h = f2b(v);
          CThi[ti] = h;
          if (CTlo) CTlo[ti] = f2b(v - b2f(h));
        }
      }
}

// ---------------- pinv operand prep (z0 only; aN written by k_sim2) ---------
__global__ __launch_bounds__(256) void k_prep_pinv(
    const float* __restrict__ attn2, const unsigned* __restrict__ cmax,
    u16* __restrict__ zNhi, u16* __restrict__ zNlo,
    u16* __restrict__ zThi, u16* __restrict__ zTlo) {
  const int bz = blockIdx.z, i0 = blockIdx.y << 6, j0 = blockIdx.x << 6;
  const float s = 1.f / __uint_as_float(*cmax);
  const float* base = attn2 + ((long)bz << 16);
  __shared__ float mt[64][65];
  const int r = threadIdx.x >> 2, cb = (threadIdx.x & 3) << 4;
#pragma unroll
  for (int c4 = 0; c4 < 16; c4 += 4) {
    float4 v = *(const float4*)&base[(long)(j0 + r) * 256 + i0 + cb + c4];
    mt[r][cb + c4] = v.x; mt[r][cb + c4 + 1] = v.y;
    mt[r][cb + c4 + 2] = v.z; mt[r][cb + c4 + 3] = v.w;
  }
  __syncthreads();
  const int i = i0 + r;
#pragma unroll
  for (int c4 = 0; c4 < 16; c4 += 4) {
    float4 v = *(const float4*)&base[(long)i * 256 + j0 + cb + c4];
    float vv[4] = {v.x, v.y, v.z, v.w};
#pragma unroll
    for (int e = 0; e < 4; ++e) {
      int j = j0 + cb + c4 + e;
      long idx = ((long)bz << 16) + ((long)i << 8) + j;
      float zt = vv[e] * s;
      u16 zh = f2b(zt);
      zThi[idx] = zh; zTlo[idx] = f2b(zt - b2f(zh));
      float zn = mt[cb + c4 + e][r] * s;
      u16 nh = f2b(zn);
      zNhi[idx] = nh; zNlo[idx] = f2b(zn - b2f(nh));
    }
  }
}

// ---------------- fused sim1: O = softmax(q @ k_land^T) @ T2 ----------------
__global__ __launch_bounds__(256) void k_fused_attn1(const u16* __restrict__ q,
                                                     const u16* __restrict__ klb,
                                                     const u16* __restrict__ t2t,
                                                     u16* __restrict__ O) {
  const int bh = blockIdx.y, n0 = blockIdx.x << 6;
  const int bb = bh >> 3, hh = bh & 7;
  const int t = threadIdx.x, lane = t & 63, w = t >> 6;
  const int fr = lane & 15, g = lane >> 4;
  __shared__ char lds[65536];
  {
    const u16* ks = klb + (long)bh * 16384;
    const u16* ts = t2t + (long)bh * 16384;
    int srow8 = lane >> 3, cs7 = lane & 7;
    int srow2 = lane >> 5, seg32 = lane & 31;
#pragma unroll
    for (int i = 0; i < 8; ++i) {
      int slab = w * 8 + i;
      int krow = slab * 8 + srow8;
      GLL(ks + krow * 64 + ((cs7 ^ (krow & 7)) << 3), lds + slab * 1024);
      int trow = slab * 2 + srow2;
      GLL(ts + trow * 256 + ((seg32 ^ (trow & 7)) << 3), lds + 32768 + slab * 1024);
    }
  }
  __syncthreads();
  const u16* qrow = q + ((long)bh * 8192 + n0 + (w << 4) + fr) * 64;
  bf16x8s qa0 = *(const bf16x8s*)(qrow + g * 8);
  bf16x8s qa1 = *(const bf16x8s*)(qrow + 32 + g * 8);
  f32x4 s[16];
#pragma unroll
  for (int c = 0; c < 16; ++c) {
    int j = (c << 4) + fr;
    bf16x8s b0 = *(const bf16x8s*)(lds + j * 128 + ((g ^ (j & 7)) << 4));
    bf16x8s b1 = *(const bf16x8s*)(lds + j * 128 + (((4 + g) ^ (j & 7)) << 4));
    f32x4 zz = {};
    zz = MFMA(qa0, b0, zz, 0, 0, 0);
    zz = MFMA(qa1, b1, zz, 0, 0, 0);
    s[c] = zz;
  }
  float li[4];
#pragma unroll
  for (int r = 0; r < 4; ++r) {
    float m = s[0][r];
#pragma unroll
    for (int c = 1; c < 16; ++c) m = fmaxf(m, s[c][r]);
    m = fmaxf(m, __shfl_xor(m, 1, 64));
    m = fmaxf(m, __shfl_xor(m, 2, 64));
    m = fmaxf(m, __shfl_xor(m, 4, 64));
    m = fmaxf(m, __shfl_xor(m, 8, 64));
    float l = 0.f;
#pragma unroll
    for (int c = 0; c < 16; ++c) {
      float e = __expf(s[c][r] - m);
      s[c][r] = e;
      l += e;
    }
    l += __shfl_xor(l, 1, 64);
    l += __shfl_xor(l, 2, 64);
    l += __shfl_xor(l, 4, 64);
    l += __shfl_xor(l, 8, 64);
    li[r] = 1.f / l;
  }
  __syncthreads();  // all waves done reading k_land; reuse region as P[64][256]
#pragma unroll
  for (int c = 0; c < 16; ++c)
#pragma unroll
    for (int r = 0; r < 4; ++r) {
      int row = (w << 4) + (g << 2) + r;
      int byin = (c << 5) + (fr << 1);
      *(u16*)(lds + row * 512 + (byin ^ ((row & 7) << 4))) = f2b(s[c][r]);
    }
  asm volatile("s_waitcnt lgkmcnt(0)" ::: "memory");
  __builtin_amdgcn_sched_barrier(0);
  f32x4 o4[4] = {};
#pragma unroll
  for (int ss = 0; ss < 8; ++ss) {
    int prow = (w << 4) + fr;
    bf16x8s ap = *(const bf16x8s*)(lds + prow * 512 +
                                   (((ss * 64) + (g << 4)) ^ ((prow & 7) << 4)));
#pragma unroll
    for (int d = 0; d < 4; ++d) {
      int dh = (d << 4) + fr;
      bf16x8s bv = *(const bf16x8s*)(lds + 32768 + dh * 512 +
                                     (((ss * 4 + g) ^ (dh & 7)) << 4));
      o4[d] = MFMA(ap, bv, o4[d], 0, 0, 0);
    }
  }
  u16* ob = O + (((long)bb * 8192 + n0 + (w << 4)) << 9) + (hh << 6);
#pragma unroll
  for (int d = 0; d < 4; ++d)
#pragma unroll
    for (int r = 0; r < 4; ++r) {
      int row = (g << 2) + r;
      int col = (d << 4) + fr;
      ob[((long)row << 9) + col] = f2b(o4[d][r] * li[r]);
    }
}

// ---------------- host ----------------
extern "C" void kernel_launch(void* const* d_in, const int* in_sizes, int n_in,
                              void* d_out, int out_size, void* d_ws, size_t ws_size,
                              hipStream_t stream) {
  const float* x = (const float*)d_in[0];
  const float* z = (const float*)d_in[1];
  const float* Wq = (const float*)d_in[2];
  const float* Wkv = (const float*)d_in[3];
  const float* Wo = (const float*)d_in[4];
  const float* bo = (const float*)d_in[5];
  float* out = (float*)d_out;

  char* base = (char*)d_ws;
  size_t off = 0;
  auto alloc = [&](size_t bytes) -> void* {
    void* r = base + off;
    off = (off + bytes + 255) & ~(size_t)255;
    return r;
  };
  u16* qb = (u16*)alloc(33554432);
  u16* kb = (u16*)alloc(16777216);
  u16* vtb = (u16*)alloc(16777216);
  u16* PS = (u16*)alloc(67108864);    // T1 partials, then pinv state (16 x 4MB)
  float* attn2 = (float*)alloc(8388608);
  u16* xb = (u16*)alloc(33554432);    // dead after qproj -> Ob
  u16* zb = (u16*)alloc(16777216);    // dead after kvproj -> attn2 split aN
  u16* wqt = (u16*)alloc(524288);
  u16* wkvt = (u16*)alloc(1048576);
  u16* wot = (u16*)alloc(524288);
  u16* qlh = (u16*)alloc(1048576);
  u16* qll = (u16*)alloc(1048576);
  u16* klh = (u16*)alloc(1048576);
  u16* kll = (u16*)alloc(1048576);
  u16* T1t = (u16*)alloc(2097152);
  u16* T2t = (u16*)alloc(1048576);    // T2^T [bh][64 dh][256 m]
  unsigned* cmax = (unsigned*)alloc(256);
  const long MC = 2097152;
  u16* P = PS;
  u16 *ztA_Nhi = P,          *ztA_Nlo = P + MC,      *ztA_Thi = P + 2 * MC,  *ztA_Tlo = P + 3 * MC;
  u16 *ztB_Nhi = P + 4 * MC,  *ztB_Nlo = P + 5 * MC,  *ztB_Thi = P + 6 * MC,  *ztB_Tlo = P + 7 * MC;
  u16 *az_Nhi = P + 8 * MC,   *az_Nlo = P + 9 * MC,   *az_Thi = P + 10 * MC,  *az_Tlo = P + 11 * MC;
  u16 *taThi = P + 12 * MC,   *taTlo = P + 13 * MC;
  u16 *tcThi = P + 14 * MC,   *tcTlo = P + 15 * MC;
  u16 *aNhi = zb, *aNlo = zb + MC;
  // T1 partials alias PS (consumed by merge before prep overwrites PS)
  float* opart = (float*)PS;                 // 32*8*256*64 fp32 = 16.8MB
  float* pm_ = opart + 4194304;              // 256KB
  float* pl_ = pm_ + 65536;                  // 256KB
  u16* T1thi = T1t;
  u16* T1tlo = T1t + 524288;
  u16* Ob = xb;

  hipMemsetAsync(cmax, 0, 4, stream);
  k_f2b<<<16384, 256, 0, stream>>>(x, xb, 4194304);
  k_f2b<<<8192, 256, 0, stream>>>(z, zb, 2097152);
  k_wt<<<1024, 256, 0, stream>>>(Wq, wqt, 512);
  k_wt<<<2048, 256, 0, stream>>>(Wkv, wkvt, 1024);
  k_wt<<<1024, 256, 0, stream>>>(Wo, wot, 512);

  k_gemm128<0><<<dim3(4, 256), 256, 0, stream>>>(xb, wqt, qb, nullptr, nullptr,
                                                 nullptr, 512);
  k_gemm128<1><<<dim3(8, 128), 256, 0, stream>>>(zb, wkvt, kb, vtb, nullptr,
                                                 nullptr, 512);
  k_landmark<<<2048, 256, 0, stream>>>(qb, qlh, qll, 8192, 32, 1.f / 32.f);
  k_landmark<<<2048, 256, 0, stream>>>(kb, klh, kll, 4096, 16, 1.f / 16.f);

  // sim2 via split-bf16 MFMA (writes attn2 fp32 + aN split into dead zb)
  k_sim2<<<dim3(4, 32), 256, 0, stream>>>(qlh, qll, klh, kll, attn2, aNhi, aNlo);
  k_colmax<<<32, 256, 0, stream>>>(attn2, cmax);

  // T1 = softmax(q_land @ k^T) @ v : split-KV partials + merge
  k_t1part<<<1024, 256, 0, stream>>>(qlh, kb, vtb, opart, pm_, pl_);
  k_t1merge<<<dim3(4, 32), 256, 0, stream>>>(opart, pm_, pl_, T1thi, T1tlo);

  // pinv prep (zN/zT into PS; PS partials consumed by merge above)
  k_prep_pinv<<<dim3(4, 4, 32), 256, 0, stream>>>(attn2, cmax, ztA_Nhi, ztA_Nlo,
                                                  ztA_Thi, ztA_Tlo);

  dim3 g256(4, 4, 32);
  u16 *cN0 = ztA_Nhi, *cN1 = ztA_Nlo, *cT0 = ztA_Thi, *cT1 = ztA_Tlo;
  u16 *nN0 = ztB_Nhi, *nN1 = ztB_Nlo, *nT0 = ztB_Thi, *nT1 = ztB_Tlo;
  for (int it = 0; it < 6; ++it) {
    bool last = (it == 5);
    k_nn_mfma<<<g256, 256, 0, stream>>>(aNhi, aNlo, cT0, cT1, az_Nhi, az_Nlo,
                                        az_Thi, az_Tlo, 256, 1.f, 0.f, 0.f);
    k_nn_mfma<<<g256, 256, 0, stream>>>(az_Nhi, az_Nlo, az_Thi, az_Tlo, nullptr,
                                        nullptr, taThi, taTlo, 256, 1.f, -7.f, 15.f);
    k_nn_mfma<<<g256, 256, 0, stream>>>(az_Nhi, az_Nlo, taThi, taTlo, nullptr,
                                        nullptr, tcThi, tcTlo, 256, -1.f, 0.f, 13.f);
    k_nn_mfma<<<g256, 256, 0, stream>>>(cN0, cN1, tcThi, tcTlo, nN0, nN1,
                                        last ? nullptr : nT0, last ? nullptr : nT1,
                                        256, 0.25f, 0.f, 0.f);
    u16* t0;
    t0 = cN0; cN0 = nN0; nN0 = t0;  t0 = cN1; cN1 = nN1; nN1 = t0;
    t0 = cT0; cT0 = nT0; nT0 = t0;  t0 = cT1; cT1 = nT1; nT1 = t0;
  }
  // T2^T = (pinv @ T1)^T, plain bf16, [bh][64 dh][256 m] via CT store
  k_nn_mfma<<<dim3(1, 4, 32), 256, 0, stream>>>(cN0, cN1, T1thi, T1tlo, nullptr,
                                                nullptr, T2t, nullptr, 64,
                                                1.f, 0.f, 0.f);

  k_fused_attn1<<<dim3(128, 32), 256, 0, stream>>>(qb, klh, T2t, Ob);
  k_gemm128<2><<<dim3(4, 256), 256, 0, stream>>>(Ob, wot, out, nullptr, x, bo, 512);
}

// Round 7
// 664.354 us; speedup vs baseline: 1.4927x; 1.1321x over previous
//
#include <hip/hip_runtime.h>

typedef unsigned short u16;
typedef __attribute__((ext_vector_type(8))) short bf16x8s;
typedef __attribute__((ext_vector_type(4))) float f32x4;

#define DEV static __device__ __forceinline__

DEV float b2f(u16 v) { return __uint_as_float(((unsigned)v) << 16); }
DEV u16 f2b(float f) {
  unsigned u = __float_as_uint(f);
  unsigned r = (u + 0x7fffu + ((u >> 16) & 1u)) >> 16;
  return (u16)r;
}

// async global->LDS, 16B per lane; lds base must be wave-uniform (HW adds lane*16)
#define GLL(gp, lp)                                                            \
  __builtin_amdgcn_global_load_lds(                                            \
      (const __attribute__((address_space(1))) unsigned int*)(gp),             \
      (__attribute__((address_space(3))) unsigned int*)(lp), 16, 0, 0)

#define MFMA __builtin_amdgcn_mfma_f32_16x16x32_bf16

// ---------------- elementwise converts ----------------
__global__ __launch_bounds__(256) void k_f2b(const float* __restrict__ in,
                                             u16* __restrict__ o, long n4) {
  long i = (long)blockIdx.x * 256 + threadIdx.x;
  if (i >= n4) return;
  float4 v = *(const float4*)(in + i * 4);
  u16* d = o + i * 4;
  d[0] = f2b(v.x); d[1] = f2b(v.y); d[2] = f2b(v.z); d[3] = f2b(v.w);
}

// W[k][N] (fp32) -> Wt[n][512] bf16  (K fixed = 512)
__global__ __launch_bounds__(256) void k_wt(const float* __restrict__ W,
                                            u16* __restrict__ Wt, int N) {
  int e = blockIdx.x * 256 + threadIdx.x;  // e < N*512
  int nn = e >> 9, kk = e & 511;
  Wt[e] = f2b(W[(long)kk * N + nn]);
}

// ---------------- 128x128 bf16 NT GEMM (BK=64, global_load_lds, swizzled) ----
template <int MODE>
__global__ __launch_bounds__(256, 2) void k_gemm128(
    const u16* __restrict__ A, const u16* __restrict__ Bm, void* __restrict__ C0,
    void* __restrict__ C1, const float* __restrict__ xres,
    const float* __restrict__ bias, int K) {
  const int nwg = gridDim.x * gridDim.y;
  const int orig = blockIdx.y * gridDim.x + blockIdx.x;
  const int qq = nwg >> 3, rr = nwg & 7;
  const int xcd = orig & 7, loc = orig >> 3;
  const int swz = (xcd < rr ? xcd * (qq + 1) : rr * (qq + 1) + (xcd - rr) * qq) + loc;
  const int m0 = (swz / gridDim.x) << 7, n0 = (swz % gridDim.x) << 7;
  const int t = threadIdx.x, lane = t & 63, w = t >> 6;
  const int wm = (w >> 1) << 6, wn = (w & 1) << 6;
  const int fr = lane & 15, g = lane >> 4;
  __shared__ u16 As[8192];
  __shared__ u16 Bs[8192];
  f32x4 acc[4][4] = {};
  const int srow = t >> 3, scs = t & 7;
  for (int k0 = 0; k0 < K; k0 += 64) {
    __syncthreads();
#pragma unroll
    for (int i = 0; i < 4; ++i) {
      int row = srow + (i << 5), cs = scs;
      GLL(A + (long)(m0 + row) * K + k0 + ((cs ^ (row & 7)) << 3),
          &As[(i << 11) + (w << 9)]);
      GLL(Bm + (long)(n0 + row) * K + k0 + ((cs ^ (row & 7)) << 3),
          &Bs[(i << 11) + (w << 9)]);
    }
    __syncthreads();
#pragma unroll
    for (int ks = 0; ks < 2; ++ks) {
      bf16x8s af[4], bf[4];
#pragma unroll
      for (int fi = 0; fi < 4; ++fi) {
        int row = wm + fi * 16 + fr;
        af[fi] = *(const bf16x8s*)((const char*)As + row * 128 +
                                   (((ks * 4 + g) ^ (row & 7)) << 4));
      }
#pragma unroll
      for (int fj = 0; fj < 4; ++fj) {
        int row = wn + fj * 16 + fr;
        bf[fj] = *(const bf16x8s*)((const char*)Bs + row * 128 +
                                   (((ks * 4 + g) ^ (row & 7)) << 4));
      }
#pragma unroll
      for (int fi = 0; fi < 4; ++fi)
#pragma unroll
        for (int fj = 0; fj < 4; ++fj)
          acc[fi][fj] = MFMA(af[fi], bf[fj], acc[fi][fj], 0, 0, 0);
    }
  }
  const int crow = g << 2;
#pragma unroll
  for (int fi = 0; fi < 4; ++fi)
#pragma unroll
    for (int fj = 0; fj < 4; ++fj)
#pragma unroll
      for (int r = 0; r < 4; ++r) {
        int row = m0 + wm + fi * 16 + crow + r;
        int col = n0 + wn + fj * 16 + fr;
        float v = acc[fi][fj][r];
        if (MODE == 0) {
          int b = row >> 13, n = row & 8191, h = col >> 6, dh = col & 63;
          ((u16*)C0)[((((long)(b * 8 + h)) << 13) + n) * 64 + dh] = f2b(v * 0.125f);
        } else if (MODE == 1) {
          int b = row >> 12, nz = row & 4095;
          if (col < 512) {
            int h = col >> 6, dh = col & 63;
            ((u16*)C0)[((((long)(b * 8 + h)) << 12) + nz) * 64 + dh] = f2b(v);
          } else {
            int c2 = col - 512, h = c2 >> 6, dh = c2 & 63;
            ((u16*)C1)[((((long)(b * 8 + h) * 64 + dh)) << 12) + nz] = f2b(v);
          }
        } else if (MODE == 2) {
          long idx = ((long)row << 9) + col;
          ((float*)C0)[idx] = v + xres[idx] + bias[col];
        }
      }
}

// ---------------- landmarks: mean over groups -> split hi/lo bf16 -----------
__global__ __launch_bounds__(256) void k_landmark(const u16* __restrict__ src,
                                                  u16* __restrict__ hi,
                                                  u16* __restrict__ lo, int ntok,
                                                  int l, float inv) {
  int pidx = blockIdx.x * 4 + (threadIdx.x >> 6);
  int d = threadIdx.x & 63;
  int bh = pidx >> 8, m = pidx & 255;
  const u16* s = src + ((long)bh * ntok + (long)m * l) * 64 + d;
  float sum = 0.f;
  for (int j = 0; j < l; ++j) sum += b2f(s[j * 64]);
  sum *= inv;
  long o = ((long)bh * 256 + m) * 64 + d;
  u16 h = f2b(sum);
  hi[o] = h;
  lo[o] = f2b(sum - b2f(h));
}

// ---------------- sim2 + softmax via split-bf16 MFMA ------------------------
__global__ __launch_bounds__(256, 2) void k_sim2(
    const u16* __restrict__ qlh, const u16* __restrict__ qll,
    const u16* __restrict__ klh, const u16* __restrict__ kll,
    float* __restrict__ attn2, u16* __restrict__ aNhi, u16* __restrict__ aNlo) {
  const int rb = blockIdx.x, bh = blockIdx.y;
  const int t = threadIdx.x, lane = t & 63, w = t >> 6;
  const int fr = lane & 15, g = lane >> 4;
  __shared__ char lds[65536];  // [0,32K) k_land hi ; [32K,64K) k_land lo
  {
    const u16* kh = klh + (long)bh * 16384;
    const u16* kl = kll + (long)bh * 16384;
    int srow8 = lane >> 3, cs7 = lane & 7;
#pragma unroll
    for (int i = 0; i < 8; ++i) {
      int slab = w * 8 + i;
      int krow = slab * 8 + srow8;
      GLL(kh + krow * 64 + ((cs7 ^ (krow & 7)) << 3), lds + slab * 1024);
      GLL(kl + krow * 64 + ((cs7 ^ (krow & 7)) << 3), lds + 32768 + slab * 1024);
    }
  }
  long qoff = ((long)bh * 256 + rb * 64 + w * 16 + fr) * 64;
  bf16x8s qh0 = *(const bf16x8s*)(qlh + qoff + g * 8);
  bf16x8s qh1 = *(const bf16x8s*)(qlh + qoff + 32 + g * 8);
  bf16x8s ql0 = *(const bf16x8s*)(qll + qoff + g * 8);
  bf16x8s ql1 = *(const bf16x8s*)(qll + qoff + 32 + g * 8);
  __syncthreads();
  f32x4 s[16];
#pragma unroll
  for (int c = 0; c < 16; ++c) {
    int j = (c << 4) + fr;
    int o0 = j * 128 + ((g ^ (j & 7)) << 4);
    int o1 = j * 128 + (((4 + g) ^ (j & 7)) << 4);
    bf16x8s kh0 = *(const bf16x8s*)(lds + o0);
    bf16x8s kh1 = *(const bf16x8s*)(lds + o1);
    bf16x8s kl0 = *(const bf16x8s*)(lds + 32768 + o0);
    bf16x8s kl1 = *(const bf16x8s*)(lds + 32768 + o1);
    f32x4 zz = {};
    zz = MFMA(qh0, kh0, zz, 0, 0, 0);
    zz = MFMA(qh1, kh1, zz, 0, 0, 0);
    zz = MFMA(qh0, kl0, zz, 0, 0, 0);
    zz = MFMA(qh1, kl1, zz, 0, 0, 0);
    zz = MFMA(ql0, kh0, zz, 0, 0, 0);
    zz = MFMA(ql1, kh1, zz, 0, 0, 0);
    s[c] = zz;
  }
  float li[4];
#pragma unroll
  for (int r = 0; r < 4; ++r) {
    float m = s[0][r];
#pragma unroll
    for (int c = 1; c < 16; ++c) m = fmaxf(m, s[c][r]);
    m = fmaxf(m, __shfl_xor(m, 1, 64));
    m = fmaxf(m, __shfl_xor(m, 2, 64));
    m = fmaxf(m, __shfl_xor(m, 4, 64));
    m = fmaxf(m, __shfl_xor(m, 8, 64));
    float l = 0.f;
#pragma unroll
    for (int c = 0; c < 16; ++c) {
      float e = __expf(s[c][r] - m);
      s[c][r] = e;
      l += e;
    }
    l += __shfl_xor(l, 1, 64);
    l += __shfl_xor(l, 2, 64);
    l += __shfl_xor(l, 4, 64);
    l += __shfl_xor(l, 8, 64);
    li[r] = 1.f / l;
  }
#pragma unroll
  for (int c = 0; c < 16; ++c)
#pragma unroll
    for (int r = 0; r < 4; ++r) {
      int row = rb * 64 + w * 16 + (g << 2) + r;
      int col = (c << 4) + fr;
      long idx = ((long)bh << 16) + ((long)row << 8) + col;
      float p = s[c][r] * li[r];
      attn2[idx] = p;
      u16 h = f2b(p);
      aNhi[idx] = h;
      aNlo[idx] = f2b(p - b2f(h));
    }
}

__global__ __launch_bounds__(256) void k_colmax(const float* __restrict__ attn2,
                                                unsigned* __restrict__ cmax) {
  int bh = blockIdx.x, j = threadIdx.x, lane = j & 63, w = j >> 6;
  const float* p = attn2 + ((long)bh << 16) + j;
  float s = 0.f;
  for (int m = 0; m < 256; ++m) s += p[m * 256];
  float mx = s;
  for (int o = 1; o < 64; o <<= 1) mx = fmaxf(mx, __shfl_xor(mx, o, 64));
  __shared__ float r1[4];
  if (lane == 0) r1[w] = mx;
  __syncthreads();
  if (j == 0) {
    mx = fmaxf(fmaxf(r1[0], r1[1]), fmaxf(r1[2], r1[3]));
    atomicMax(cmax, __float_as_uint(mx));
  }
}

// ---------------- T1 split-KV partial: (bh, rb, kc of 1024 keys) ------------
// opart writes are LDS-transposed then float4-coalesced (fix 8x write amp)
__global__ __launch_bounds__(256, 2) void k_t1part(
    const u16* __restrict__ qlb, const u16* __restrict__ kb,
    const u16* __restrict__ vtb, float* __restrict__ opart,
    float* __restrict__ pm_, float* __restrict__ pl_) {
  int orig = blockIdx.x;  // 512 = 32 bh * 4 kc * 4 rb
  int xcd = orig & 7, idx = orig >> 3;
  int p = xcd * 16 + (idx >> 2);  // (bh,kc) pair; 4 rb of a pair share an XCD
  int rb = idx & 3;
  int bh = p >> 2, kc = p & 3;
  const int t = threadIdx.x, lane = t & 63, w = t >> 6;
  const int fr = lane & 15, g = lane >> 4;
  __shared__ char lds[65536];  // [0,32K) K chunk (aliased by P); [32K,64K) V^T
  const u16* qrow = qlb + ((long)bh * 256 + rb * 64 + w * 16 + fr) * 64;
  bf16x8s qa0 = *(const bf16x8s*)(qrow + g * 8);
  bf16x8s qa1 = *(const bf16x8s*)(qrow + 32 + g * 8);
  f32x4 o[4] = {};
  float m[4] = {-3e38f, -3e38f, -3e38f, -3e38f};
  float l[4] = {};
  const long kbase = (long)bh * 262144;
  for (int cc = 0; cc < 4; ++cc) {
    int c0 = kc * 1024 + cc * 256;
    __syncthreads();
#pragma unroll
    for (int i = 0; i < 8; ++i) {
      int seg = (i << 8) + t, row = seg >> 3, cs = seg & 7;
      GLL(kb + kbase + (long)(c0 + row) * 64 + ((cs ^ (row & 7)) << 3),
          lds + (i << 12) + (w << 10));
    }
#pragma unroll
    for (int i = 0; i < 8; ++i) {
      int seg = (i << 8) + t, row = seg >> 5, cs = seg & 31;
      GLL(vtb + kbase + (long)row * 4096 + c0 + ((cs ^ (row & 7)) << 3),
          lds + 32768 + (i << 12) + (w << 10));
    }
    __syncthreads();
    f32x4 s[16];
#pragma unroll
    for (int c = 0; c < 16; ++c) {
      int j = c * 16 + fr;
      bf16x8s b0 = *(const bf16x8s*)(lds + j * 128 + ((g ^ (j & 7)) << 4));
      bf16x8s b1 = *(const bf16x8s*)(lds + j * 128 + (((4 + g) ^ (j & 7)) << 4));
      f32x4 zz = {};
      zz = MFMA(qa0, b0, zz, 0, 0, 0);
      zz = MFMA(qa1, b1, zz, 0, 0, 0);
      s[c] = zz;
    }
    float sc[4];
#pragma unroll
    for (int r = 0; r < 4; ++r) {
      float pm = s[0][r];
#pragma unroll
      for (int c = 1; c < 16; ++c) pm = fmaxf(pm, s[c][r]);
      pm = fmaxf(pm, __shfl_xor(pm, 1, 64));
      pm = fmaxf(pm, __shfl_xor(pm, 2, 64));
      pm = fmaxf(pm, __shfl_xor(pm, 4, 64));
      pm = fmaxf(pm, __shfl_xor(pm, 8, 64));
      float mn = fmaxf(m[r], pm);
      sc[r] = __expf(m[r] - mn);
      m[r] = mn;
    }
#pragma unroll
    for (int r = 0; r < 4; ++r) {
      float su = 0.f;
#pragma unroll
      for (int c = 0; c < 16; ++c) {
        float e = __expf(s[c][r] - m[r]);
        s[c][r] = e;
        su += e;
      }
      su += __shfl_xor(su, 1, 64);
      su += __shfl_xor(su, 2, 64);
      su += __shfl_xor(su, 4, 64);
      su += __shfl_xor(su, 8, 64);
      l[r] = l[r] * sc[r] + su;
    }
#pragma unroll
    for (int d = 0; d < 4; ++d)
#pragma unroll
      for (int r = 0; r < 4; ++r) o[d][r] *= sc[r];
    __syncthreads();
#pragma unroll
    for (int c = 0; c < 16; ++c)
#pragma unroll
      for (int r = 0; r < 4; ++r) {
        int row = (w << 4) + (g << 2) + r;
        int byin = (c << 5) + (fr << 1);
        *(u16*)(lds + row * 512 + (byin ^ ((row & 7) << 4))) = f2b(s[c][r]);
      }
    asm volatile("s_waitcnt lgkmcnt(0)" ::: "memory");
    __builtin_amdgcn_sched_barrier(0);
#pragma unroll
    for (int ss = 0; ss < 8; ++ss) {
      int prow = (w << 4) + fr;
      bf16x8s ap = *(const bf16x8s*)(lds + prow * 512 +
                                     (((ss * 64) + (g << 4)) ^ ((prow & 7) << 4)));
#pragma unroll
      for (int d = 0; d < 4; ++d) {
        int dh = (d << 4) + fr;
        bf16x8s bv = *(const bf16x8s*)(lds + 32768 + dh * 512 +
                                       (((ss * 4 + g) ^ (dh & 7)) << 4));
        o[d] = MFMA(ap, bv, o[d], 0, 0, 0);
      }
    }
  }
  // LDS-transpose o then coalesced float4 writes (row stride 76: 16B-aligned + bank-spread)
  __syncthreads();
  float* lf = (float*)lds;
#pragma unroll
  for (int d = 0; d < 4; ++d)
#pragma unroll
    for (int r = 0; r < 4; ++r)
      lf[((w << 4) + (g << 2) + r) * 76 + (d << 4) + fr] = o[d][r];
  __syncthreads();
  const long pb = (long)(bh * 4 + kc) * 256 + rb * 64;
#pragma unroll
  for (int i = 0; i < 4; ++i) {
    int row = i * 16 + (t >> 4);
    int c4 = (t & 15) << 2;
    float4 v = *(const float4*)&lf[row * 76 + c4];
    *(float4*)&opart[(pb + row) * 64 + c4] = v;
  }
  if (fr == 0) {
#pragma unroll
    for (int r = 0; r < 4; ++r) {
      int lr = (w << 4) + (g << 2) + r;
      pm_[pb + lr] = m[r];
      pl_[pb + lr] = l[r];
    }
  }
}

// ---------------- merge 4 partials -> T1^T split bf16 -----------------------
__global__ __launch_bounds__(256) void k_t1merge(
    const float* __restrict__ opart, const float* __restrict__ pm_,
    const float* __restrict__ pl_, u16* __restrict__ T1thi,
    u16* __restrict__ T1tlo) {
  const int rb = blockIdx.x, bh = blockIdx.y;
  const int t = threadIdx.x;
#pragma unroll
  for (int rp = 0; rp < 4; ++rp) {
    int row = rb * 64 + rp * 16 + (t >> 4);
    int dh4 = (t & 15) << 2;
    float pmv[4], M = -3e38f;
#pragma unroll
    for (int i = 0; i < 4; ++i) {
      pmv[i] = pm_[(long)(bh * 4 + i) * 256 + row];
      M = fmaxf(M, pmv[i]);
    }
    float L = 0.f, wt[4];
#pragma unroll
    for (int i = 0; i < 4; ++i) {
      wt[i] = __expf(pmv[i] - M);
      L += pl_[(long)(bh * 4 + i) * 256 + row] * wt[i];
    }
    float4 acc = {0.f, 0.f, 0.f, 0.f};
#pragma unroll
    for (int i = 0; i < 4; ++i) {
      float4 v = *(const float4*)&opart[((long)(bh * 4 + i) * 256 + row) * 64 + dh4];
      acc.x += v.x * wt[i]; acc.y += v.y * wt[i];
      acc.z += v.z * wt[i]; acc.w += v.w * wt[i];
    }
    float invL = 1.f / L;
    float vv[4] = {acc.x * invL, acc.y * invL, acc.z * invL, acc.w * invL};
#pragma unroll
    for (int e = 0; e < 4; ++e) {
      int dh = dh4 + e;
      long idx = (long)bh * 16384 + (long)dh * 256 + row;
      u16 h = f2b(vv[e]);
      T1thi[idx] = h;
      T1tlo[idx] = f2b(vv[e] - b2f(h));
    }
  }
}

// ---------------- MFMA NN GEMM (pinv chain); NP=1 plain bf16, NP=3 split ----
template <int NP>
__global__ __launch_bounds__(256) void k_nn_mfma(
    const u16* __restrict__ Ahi, const u16* __restrict__ Alo,
    const u16* __restrict__ Bthi, const u16* __restrict__ Btlo,
    u16* __restrict__ CNhi, u16* __restrict__ CNlo,
    u16* __restrict__ CThi, u16* __restrict__ CTlo,
    int Nc, float sab, float sa, float cdiag) {
  const int bz = blockIdx.z;
  const long offA = (long)bz << 16;
  const long offB = (long)bz * ((long)Nc << 8);
  const int m0 = blockIdx.y << 6, n0 = blockIdx.x << 6;
  const int t = threadIdx.x, lane = t & 63, w = t >> 6;
  const int wm = (w >> 1) << 5, wn = (w & 1) << 5;
  const int fr = lane & 15, g = lane >> 4;
  __shared__ u16 lds[16384];
  u16* LAh = lds;
  u16* LAl = lds + 4096;
  u16* LBh = lds + 8192;
  u16* LBl = lds + 12288;
  f32x4 acc[2][2] = {};
  const int srow8 = lane >> 3, cs = lane & 7;
  for (int k0 = 0; k0 < 256; k0 += 64) {
    __syncthreads();
#pragma unroll
    for (int j = 0; j < 2; ++j) {
      int slab = w * 2 + j;
      int row = slab * 8 + srow8;
      long asrc = offA + (long)(m0 + row) * 256 + k0 + ((cs ^ (row & 7)) << 3);
      long bsrc = offB + (long)(n0 + row) * 256 + k0 + ((cs ^ (row & 7)) << 3);
      GLL(Ahi + asrc, LAh + slab * 512);
      GLL(Bthi + bsrc, LBh + slab * 512);
      if (NP == 3) {
        GLL(Alo + asrc, LAl + slab * 512);
        GLL(Btlo + bsrc, LBl + slab * 512);
      }
    }
    __syncthreads();
#pragma unroll
    for (int ks = 0; ks < 2; ++ks) {
      const int ra0 = wm + fr, ra1 = wm + 16 + fr;
      const int rb0 = wn + fr, rb1 = wn + 16 + fr;
#define RD(base, row) \
  (*(const bf16x8s*)((const char*)(base) + (row) * 128 + (((ks * 4 + g) ^ ((row) & 7)) << 4)))
      bf16x8s ah0 = RD(LAh, ra0), ah1 = RD(LAh, ra1);
      bf16x8s bh0 = RD(LBh, rb0), bh1 = RD(LBh, rb1);
      acc[0][0] = MFMA(ah0, bh0, acc[0][0], 0, 0, 0);
      acc[0][1] = MFMA(ah0, bh1, acc[0][1], 0, 0, 0);
      acc[1][0] = MFMA(ah1, bh0, acc[1][0], 0, 0, 0);
      acc[1][1] = MFMA(ah1, bh1, acc[1][1], 0, 0, 0);
      if (NP == 3) {
        bf16x8s al0 = RD(LAl, ra0), al1 = RD(LAl, ra1);
        bf16x8s bl0 = RD(LBl, rb0), bl1 = RD(LBl, rb1);
        acc[0][0] = MFMA(ah0, bl0, acc[0][0], 0, 0, 0);
        acc[0][0] = MFMA(al0, bh0, acc[0][0], 0, 0, 0);
        acc[0][1] = MFMA(ah0, bl1, acc[0][1], 0, 0, 0);
        acc[0][1] = MFMA(al0, bh1, acc[0][1], 0, 0, 0);
        acc[1][0] = MFMA(ah1, bl0, acc[1][0], 0, 0, 0);
        acc[1][0] = MFMA(al1, bh0, acc[1][0], 0, 0, 0);
        acc[1][1] = MFMA(ah1, bl1, acc[1][1], 0, 0, 0);
        acc[1][1] = MFMA(al1, bh1, acc[1][1], 0, 0, 0);
      }
#undef RD
    }
  }
  const int crow = g << 2;
  const long offC = (long)bz * ((long)Nc << 8);
#pragma unroll
  for (int i = 0; i < 2; ++i)
#pragma unroll
    for (int j = 0; j < 2; ++j)
#pragma unroll
      for (int r = 0; r < 4; ++r) {
        int row = m0 + wm + i * 16 + crow + r;
        int col = n0 + wn + j * 16 + fr;
        float v = sab * acc[i][j][r];
        if (sa != 0.f) {
          long ai = offA + ((long)row << 8) + col;
          v += sa * (b2f(Ahi[ai]) + b2f(Alo[ai]));
        }
        if (row == col) v += cdiag;
        if (CNhi) {
          long ci = offC + (long)row * Nc + col;
          u16 h = f2b(v);
          if (CNlo) { CNhi[ci] = h; CNlo[ci] = f2b(v - b2f(h)); }
          else CNhi[ci] = h;
        }
        if (CThi) {
          long ti = offC + ((long)col << 8) + row;
          u16 h = f2b(v);
          CThi[ti] = h;
          if (CTlo) CTlo[ti] = f2b(v - b2f(h));
        }
      }
}

// ---------------- pinv operand prep (z0 only; aN written by k_sim2) ---------
__global__ __launch_bounds__(256) void k_prep_pinv(
    const float* __restrict__ attn2, const unsigned* __restrict__ cmax,
    u16* __restrict__ zNhi, u16* __restrict__ zNlo,
    u16* __restrict__ zThi, u16* __restrict__ zTlo) {
  const int bz = blockIdx.z, i0 = blockIdx.y << 6, j0 = blockIdx.x << 6;
  const float s = 1.f / __uint_as_float(*cmax);
  const float* base = attn2 + ((long)bz << 16);
  __shared__ float mt[64][65];
  const int r = threadIdx.x >> 2, cb = (threadIdx.x & 3) << 4;
#pragma unroll
  for (int c4 = 0; c4 < 16; c4 += 4) {
    float4 v = *(const float4*)&base[(long)(j0 + r) * 256 + i0 + cb + c4];
    mt[r][cb + c4] = v.x; mt[r][cb + c4 + 1] = v.y;
    mt[r][cb + c4 + 2] = v.z; mt[r][cb + c4 + 3] = v.w;
  }
  __syncthreads();
  const int i = i0 + r;
#pragma unroll
  for (int c4 = 0; c4 < 16; c4 += 4) {
    float4 v = *(const float4*)&base[(long)i * 256 + j0 + cb + c4];
    float vv[4] = {v.x, v.y, v.z, v.w};
#pragma unroll
    for (int e = 0; e < 4; ++e) {
      int j = j0 + cb + c4 + e;
      long idx = ((long)bz << 16) + ((long)i << 8) + j;
      float zt = vv[e] * s;
      u16 zh = f2b(zt);
      zThi[idx] = zh; zTlo[idx] = f2b(zt - b2f(zh));
      float zn = mt[cb + c4 + e][r] * s;
      u16 nh = f2b(zn);
      zNhi[idx] = nh; zNlo[idx] = f2b(zn - b2f(nh));
    }
  }
}

// ---------------- fused sim1: O = softmax(q @ k_land^T) @ T2 ----------------
__global__ __launch_bounds__(256) void k_fused_attn1(const u16* __restrict__ q,
                                                     const u16* __restrict__ klb,
                                                     const u16* __restrict__ t2t,
                                                     u16* __restrict__ O) {
  const int bh = blockIdx.y, n0 = blockIdx.x << 6;
  const int bb = bh >> 3, hh = bh & 7;
  const int t = threadIdx.x, lane = t & 63, w = t >> 6;
  const int fr = lane & 15, g = lane >> 4;
  __shared__ char lds[65536];
  {
    const u16* ks = klb + (long)bh * 16384;
    const u16* ts = t2t + (long)bh * 16384;
    int srow8 = lane >> 3, cs7 = lane & 7;
    int srow2 = lane >> 5, seg32 = lane & 31;
#pragma unroll
    for (int i = 0; i < 8; ++i) {
      int slab = w * 8 + i;
      int krow = slab * 8 + srow8;
      GLL(ks + krow * 64 + ((cs7 ^ (krow & 7)) << 3), lds + slab * 1024);
      int trow = slab * 2 + srow2;
      GLL(ts + trow * 256 + ((seg32 ^ (trow & 7)) << 3), lds + 32768 + slab * 1024);
    }
  }
  __syncthreads();
  const u16* qrow = q + ((long)bh * 8192 + n0 + (w << 4) + fr) * 64;
  bf16x8s qa0 = *(const bf16x8s*)(qrow + g * 8);
  bf16x8s qa1 = *(const bf16x8s*)(qrow + 32 + g * 8);
  f32x4 s[16];
#pragma unroll
  for (int c = 0; c < 16; ++c) {
    int j = (c << 4) + fr;
    bf16x8s b0 = *(const bf16x8s*)(lds + j * 128 + ((g ^ (j & 7)) << 4));
    bf16x8s b1 = *(const bf16x8s*)(lds + j * 128 + (((4 + g) ^ (j & 7)) << 4));
    f32x4 zz = {};
    zz = MFMA(qa0, b0, zz, 0, 0, 0);
    zz = MFMA(qa1, b1, zz, 0, 0, 0);
    s[c] = zz;
  }
  float li[4];
#pragma unroll
  for (int r = 0; r < 4; ++r) {
    float m = s[0][r];
#pragma unroll
    for (int c = 1; c < 16; ++c) m = fmaxf(m, s[c][r]);
    m = fmaxf(m, __shfl_xor(m, 1, 64));
    m = fmaxf(m, __shfl_xor(m, 2, 64));
    m = fmaxf(m, __shfl_xor(m, 4, 64));
    m = fmaxf(m, __shfl_xor(m, 8, 64));
    float l = 0.f;
#pragma unroll
    for (int c = 0; c < 16; ++c) {
      float e = __expf(s[c][r] - m);
      s[c][r] = e;
      l += e;
    }
    l += __shfl_xor(l, 1, 64);
    l += __shfl_xor(l, 2, 64);
    l += __shfl_xor(l, 4, 64);
    l += __shfl_xor(l, 8, 64);
    li[r] = 1.f / l;
  }
  __syncthreads();  // all waves done reading k_land; reuse region as P[64][256]
#pragma unroll
  for (int c = 0; c < 16; ++c)
#pragma unroll
    for (int r = 0; r < 4; ++r) {
      int row = (w << 4) + (g << 2) + r;
      int byin = (c << 5) + (fr << 1);
      *(u16*)(lds + row * 512 + (byin ^ ((row & 7) << 4))) = f2b(s[c][r]);
    }
  asm volatile("s_waitcnt lgkmcnt(0)" ::: "memory");
  __builtin_amdgcn_sched_barrier(0);
  f32x4 o4[4] = {};
#pragma unroll
  for (int ss = 0; ss < 8; ++ss) {
    int prow = (w << 4) + fr;
    bf16x8s ap = *(const bf16x8s*)(lds + prow * 512 +
                                   (((ss * 64) + (g << 4)) ^ ((prow & 7) << 4)));
#pragma unroll
    for (int d = 0; d < 4; ++d) {
      int dh = (d << 4) + fr;
      bf16x8s bv = *(const bf16x8s*)(lds + 32768 + dh * 512 +
                                     (((ss * 4 + g) ^ (dh & 7)) << 4));
      o4[d] = MFMA(ap, bv, o4[d], 0, 0, 0);
    }
  }
  u16* ob = O + (((long)bb * 8192 + n0 + (w << 4)) << 9) + (hh << 6);
#pragma unroll
  for (int d = 0; d < 4; ++d)
#pragma unroll
    for (int r = 0; r < 4; ++r) {
      int row = (g << 2) + r;
      int col = (d << 4) + fr;
      ob[((long)row << 9) + col] = f2b(o4[d][r] * li[r]);
    }
}

// ---------------- host ----------------
extern "C" void kernel_launch(void* const* d_in, const int* in_sizes, int n_in,
                              void* d_out, int out_size, void* d_ws, size_t ws_size,
                              hipStream_t stream) {
  const float* x = (const float*)d_in[0];
  const float* z = (const float*)d_in[1];
  const float* Wq = (const float*)d_in[2];
  const float* Wkv = (const float*)d_in[3];
  const float* Wo = (const float*)d_in[4];
  const float* bo = (const float*)d_in[5];
  float* out = (float*)d_out;

  char* base = (char*)d_ws;
  size_t off = 0;
  auto alloc = [&](size_t bytes) -> void* {
    void* r = base + off;
    off = (off + bytes + 255) & ~(size_t)255;
    return r;
  };
  u16* qb = (u16*)alloc(33554432);
  u16* kb = (u16*)alloc(16777216);
  u16* vtb = (u16*)alloc(16777216);
  u16* PS = (u16*)alloc(67108864);    // T1 partials, then pinv state (16 x 4MB)
  float* attn2 = (float*)alloc(8388608);
  u16* xb = (u16*)alloc(33554432);    // dead after qproj -> Ob
  u16* zb = (u16*)alloc(16777216);    // dead after kvproj -> attn2 split aN
  u16* wqt = (u16*)alloc(524288);
  u16* wkvt = (u16*)alloc(1048576);
  u16* wot = (u16*)alloc(524288);
  u16* qlh = (u16*)alloc(1048576);
  u16* qll = (u16*)alloc(1048576);
  u16* klh = (u16*)alloc(1048576);
  u16* kll = (u16*)alloc(1048576);
  u16* T1t = (u16*)alloc(2097152);
  u16* T2t = (u16*)alloc(1048576);    // T2^T [bh][64 dh][256 m]
  unsigned* cmax = (unsigned*)alloc(256);
  const long MC = 2097152;
  u16* P = PS;
  u16 *ztA_Nhi = P,          *ztA_Nlo = P + MC,      *ztA_Thi = P + 2 * MC,  *ztA_Tlo = P + 3 * MC;
  u16 *ztB_Nhi = P + 4 * MC,  *ztB_Nlo = P + 5 * MC,  *ztB_Thi = P + 6 * MC,  *ztB_Tlo = P + 7 * MC;
  u16 *az_Nhi = P + 8 * MC,   *az_Nlo = P + 9 * MC,   *az_Thi = P + 10 * MC,  *az_Tlo = P + 11 * MC;
  u16 *taThi = P + 12 * MC,   *taTlo = P + 13 * MC;
  u16 *tcThi = P + 14 * MC,   *tcTlo = P + 15 * MC;
  u16 *aNhi = zb, *aNlo = zb + MC;
  // T1 partials alias PS (consumed by merge before prep overwrites PS)
  float* opart = (float*)PS;                 // 32*4*256*64 fp32 = 8.4MB
  float* pm_ = opart + 2097152;              // 128KB
  float* pl_ = pm_ + 32768;                  // 128KB
  u16* T1thi = T1t;
  u16* T1tlo = T1t + 524288;
  u16* Ob = xb;

  hipMemsetAsync(cmax, 0, 4, stream);
  k_f2b<<<16384, 256, 0, stream>>>(x, xb, 4194304);
  k_f2b<<<8192, 256, 0, stream>>>(z, zb, 2097152);
  k_wt<<<1024, 256, 0, stream>>>(Wq, wqt, 512);
  k_wt<<<2048, 256, 0, stream>>>(Wkv, wkvt, 1024);
  k_wt<<<1024, 256, 0, stream>>>(Wo, wot, 512);

  k_gemm128<0><<<dim3(4, 256), 256, 0, stream>>>(xb, wqt, qb, nullptr, nullptr,
                                                 nullptr, 512);
  k_gemm128<1><<<dim3(8, 128), 256, 0, stream>>>(zb, wkvt, kb, vtb, nullptr,
                                                 nullptr, 512);
  k_landmark<<<2048, 256, 0, stream>>>(qb, qlh, qll, 8192, 32, 1.f / 32.f);
  k_landmark<<<2048, 256, 0, stream>>>(kb, klh, kll, 4096, 16, 1.f / 16.f);

  // sim2 via split-bf16 MFMA (writes attn2 fp32 + aN split into dead zb)
  k_sim2<<<dim3(4, 32), 256, 0, stream>>>(qlh, qll, klh, kll, attn2, aNhi, aNlo);
  k_colmax<<<32, 256, 0, stream>>>(attn2, cmax);

  // T1 = softmax(q_land @ k^T) @ v : split-KV partials + merge
  k_t1part<<<512, 256, 0, stream>>>(qlh, kb, vtb, opart, pm_, pl_);
  k_t1merge<<<dim3(4, 32), 256, 0, stream>>>(opart, pm_, pl_, T1thi, T1tlo);

  // pinv prep (zN/zT into PS; PS partials consumed by merge above)
  k_prep_pinv<<<dim3(4, 4, 32), 256, 0, stream>>>(attn2, cmax, ztA_Nhi, ztA_Nlo,
                                                  ztA_Thi, ztA_Tlo);

  dim3 g256(4, 4, 32);
  u16 *cN0 = ztA_Nhi, *cN1 = ztA_Nlo, *cT0 = ztA_Thi, *cT1 = ztA_Tlo;
  u16 *nN0 = ztB_Nhi, *nN1 = ztB_Nlo, *nT0 = ztB_Thi, *nT1 = ztB_Tlo;
  for (int it = 0; it < 6; ++it) {
    bool last = (it == 5);
    // Newton-Schulz self-corrects: iters 0-2 plain bf16 (NP=1), 3-5 split (NP=3)
    if (it < 3) {
      k_nn_mfma<1><<<g256, 256, 0, stream>>>(aNhi, aNlo, cT0, cT1, az_Nhi, az_Nlo,
                                             az_Thi, az_Tlo, 256, 1.f, 0.f, 0.f);
      k_nn_mfma<1><<<g256, 256, 0, stream>>>(az_Nhi, az_Nlo, az_Thi, az_Tlo, nullptr,
                                             nullptr, taThi, taTlo, 256, 1.f, -7.f, 15.f);
      k_nn_mfma<1><<<g256, 256, 0, stream>>>(az_Nhi, az_Nlo, taThi, taTlo, nullptr,
                                             nullptr, tcThi, tcTlo, 256, -1.f, 0.f, 13.f);
      k_nn_mfma<1><<<g256, 256, 0, stream>>>(cN0, cN1, tcThi, tcTlo, nN0, nN1,
                                             nT0, nT1, 256, 0.25f, 0.f, 0.f);
    } else {
      k_nn_mfma<3><<<g256, 256, 0, stream>>>(aNhi, aNlo, cT0, cT1, az_Nhi, az_Nlo,
                                             az_Thi, az_Tlo, 256, 1.f, 0.f, 0.f);
      k_nn_mfma<3><<<g256, 256, 0, stream>>>(az_Nhi, az_Nlo, az_Thi, az_Tlo, nullptr,
                                             nullptr, taThi, taTlo, 256, 1.f, -7.f, 15.f);
      k_nn_mfma<3><<<g256, 256, 0, stream>>>(az_Nhi, az_Nlo, taThi, taTlo, nullptr,
                                             nullptr, tcThi, tcTlo, 256, -1.f, 0.f, 13.f);
      k_nn_mfma<3><<<g256, 256, 0, stream>>>(cN0, cN1, tcThi, tcTlo, nN0, nN1,
                                             last ? nullptr : nT0, last ? nullptr : nT1,
                                             256, 0.25f, 0.f, 0.f);
    }
    u16* t0;
    t0 = cN0; cN0 = nN0; nN0 = t0;  t0 = cN1; cN1 = nN1; nN1 = t0;
    t0 = cT0; cT0 = nT0; nT0 = t0;  t0 = cT1; cT1 = nT1; nT1 = t0;
  }
  // T2^T = (pinv @ T1)^T, plain bf16, [bh][64 dh][256 m] via CT store
  k_nn_mfma<3><<<dim3(1, 4, 32), 256, 0, stream>>>(cN0, cN1, T1thi, T1tlo, nullptr,
                                                   nullptr, T2t, nullptr, 64,
                                                   1.f, 0.f, 0.f);

  k_fused_attn1<<<dim3(128, 32), 256, 0, stream>>>(qb, klh, T2t, Ob);
  k_gemm128<2><<<dim3(4, 256), 256, 0, stream>>>(Ob, wot, out, nullptr, x, bo, 512);
}